// Round 1
// baseline (6627.382 us; speedup 1.0000x reference)
//
#include <hip/hip_runtime.h>

#define QLEN 10000
#define TLEN 3000
#define EMB 768
#define HNEED 3
#define NQ (QLEN * HNEED)
#define EG 100000
#define EI 100000
#define DKH 192
#define NHEADS 4

namespace {

constexpr float SCALE = 0.07216878364870322f; // 1/sqrt(192)
constexpr int BM = 64, BN = 64, BK = 16;

// ---------------------------------------------------------------- GEMM (f32)
// C = A @ B (+bias). EPI 0: plain row-major C.
// EPI 1: question-encoder epilogue: out[(n/768)*QLEN + m][n%768] = v + q_emb[m][n%768]
// EPI 2: ques output epilogue: out[(m%QLEN)*3 + m/QLEN][n] = v
template <int EPI>
__global__ __launch_bounds__(256) void gemm_f32(
    const float* __restrict__ A, int lda, long long sAz,
    const float* __restrict__ B, int ldb, long long sBz,
    float* __restrict__ C, int ldc, long long sCz,
    const float* __restrict__ bias, const float* __restrict__ extra,
    int M, int N, int K)
{
  __shared__ __align__(16) float As[BK][BM + 4];
  __shared__ __align__(16) float Bs[BK][BN + 4];
  const int z = blockIdx.z;
  A += z * sAz;
  B += z * sBz;
  C += z * sCz;
  const int bm = blockIdx.y * BM, bn = blockIdx.x * BN;
  const int tid = threadIdx.x;
  const int tx = tid & 15, ty = tid >> 4;
  const int ar = tid >> 4, ac = tid & 15;   // A loader: 16 rows x 16 k per pass
  const int br = tid >> 6, bc = tid & 63;   // B loader: 4 k-rows x 64 n per pass
  float acc[4][4] = {};
  for (int k0 = 0; k0 < K; k0 += BK) {
#pragma unroll
    for (int i = 0; i < 4; ++i) {
      int m = bm + ar + i * 16;
      As[ac][ar + i * 16] = (m < M) ? A[(long long)m * lda + k0 + ac] : 0.f;
    }
#pragma unroll
    for (int i = 0; i < 4; ++i) {
      int n = bn + bc;
      Bs[br + i * 4][bc] = (n < N) ? B[(long long)(k0 + br + i * 4) * ldb + n] : 0.f;
    }
    __syncthreads();
#pragma unroll
    for (int kk = 0; kk < BK; ++kk) {
      float4 a4 = *reinterpret_cast<const float4*>(&As[kk][ty * 4]);
      float4 b4 = *reinterpret_cast<const float4*>(&Bs[kk][tx * 4]);
      float a[4] = {a4.x, a4.y, a4.z, a4.w};
      float b[4] = {b4.x, b4.y, b4.z, b4.w};
#pragma unroll
      for (int i = 0; i < 4; ++i)
#pragma unroll
        for (int j = 0; j < 4; ++j) acc[i][j] = fmaf(a[i], b[j], acc[i][j]);
    }
    __syncthreads();
  }
#pragma unroll
  for (int i = 0; i < 4; ++i) {
    int m = bm + ty * 4 + i;
    if (m >= M) continue;
#pragma unroll
    for (int j = 0; j < 4; ++j) {
      int n = bn + tx * 4 + j;
      if (n >= N) continue;
      float v = acc[i][j] + (bias ? bias[n] : 0.f);
      if (EPI == 0) {
        C[(long long)m * ldc + n] = v;
      } else if (EPI == 1) {
        int h = n / EMB, c = n - h * EMB;
        C[((long long)h * QLEN + m) * EMB + c] = v + extra[(long long)m * EMB + c];
      } else {
        int i2 = m % QLEN, h = m / QLEN;
        C[((long long)i2 * HNEED + h) * EMB + n] = v;
      }
    }
  }
}

// --------------------------------------------- fused assign-softmax + centers
// per row: logits = row @ Wc + bc (10); softmax; row += assign @ centers
__global__ __launch_bounds__(256) void assign_center_kernel(
    float* __restrict__ qh, const float* __restrict__ Wc,
    const float* __restrict__ bc, const float* __restrict__ centers)
{
  const int row = blockIdx.x;
  const int tid = threadIdx.x;
  __shared__ float red[4][10];
  __shared__ float assign_s[10];
  float part[10] = {};
  for (int d = tid; d < EMB; d += 256) {
    float v = qh[(long long)row * EMB + d];
#pragma unroll
    for (int j = 0; j < 10; ++j) part[j] += v * Wc[d * 10 + j];
  }
#pragma unroll
  for (int j = 0; j < 10; ++j)
#pragma unroll
    for (int off = 32; off; off >>= 1) part[j] += __shfl_down(part[j], off);
  const int wave = tid >> 6, lane = tid & 63;
  if (lane == 0)
    for (int j = 0; j < 10; ++j) red[wave][j] = part[j];
  __syncthreads();
  if (tid == 0) {
    float lg[10], m = -1e30f, s = 0.f;
    for (int j = 0; j < 10; ++j) {
      lg[j] = red[0][j] + red[1][j] + red[2][j] + red[3][j] + bc[j];
      m = fmaxf(m, lg[j]);
    }
    for (int j = 0; j < 10; ++j) {
      float e = expf(lg[j] - m);
      assign_s[j] = e;
      s += e;
    }
    float inv = 1.f / s;
    for (int j = 0; j < 10; ++j) assign_s[j] *= inv;
  }
  __syncthreads();
  for (int c = tid; c < EMB; c += 256) {
    float a = 0.f;
#pragma unroll
    for (int j = 0; j < 10; ++j) a += assign_s[j] * centers[j * EMB + c];
    qh[(long long)row * EMB + c] += a;
  }
}

// ------------------------------------------------------------- edge machinery
__global__ void build_give_edges(const int* __restrict__ gs, const int* __restrict__ gd,
                                 int* __restrict__ osrc, int* __restrict__ odst)
{
  int e = blockIdx.x * 256 + threadIdx.x;
  if (e >= EG * HNEED) return;
  int b = e % EG, cp = e / EG;
  osrc[e] = gs[b];
  odst[e] = gd[b] + cp * QLEN;
}

__global__ __launch_bounds__(256) void edge_score(
    const float* __restrict__ q, const float* __restrict__ k,
    const int* __restrict__ src, const int* __restrict__ dst,
    const float* __restrict__ rpri, float* __restrict__ score, int E)
{
  int wid = (blockIdx.x * 256 + threadIdx.x) >> 6;
  int lane = threadIdx.x & 63;
  if (wid >= E) return;
  int s = src[wid], d = dst[wid];
  const float* qr = q + (long long)d * EMB;
  const float* kr = k + (long long)s * EMB;
#pragma unroll
  for (int h = 0; h < NHEADS; ++h) {
    float acc = qr[h * DKH + lane] * kr[h * DKH + lane] +
                qr[h * DKH + 64 + lane] * kr[h * DKH + 64 + lane] +
                qr[h * DKH + 128 + lane] * kr[h * DKH + 128 + lane];
#pragma unroll
    for (int off = 32; off; off >>= 1) acc += __shfl_down(acc, off);
    if (lane == 0) score[(long long)wid * 4 + h] = acc * rpri[h] * SCALE;
  }
}

__device__ inline unsigned fmap(float f) {
  int b = __float_as_int(f);
  return (b < 0) ? ~(unsigned)b : ((unsigned)b | 0x80000000u);
}
__device__ inline float funmap(unsigned u) {
  return (u & 0x80000000u) ? __int_as_float((int)(u & 0x7FFFFFFFu))
                           : __int_as_float(~(int)u);
}

__global__ void seg_max_kernel(const float* __restrict__ score, const int* __restrict__ dst,
                               unsigned* __restrict__ segmax, int E)
{
  int idx = blockIdx.x * 256 + threadIdx.x;
  if (idx >= E * 4) return;
  int e = idx >> 2, h = idx & 3;
  atomicMax(&segmax[dst[e] * 4 + h], fmap(score[idx]));
}

__global__ void exp_sum_kernel(float* __restrict__ score, const int* __restrict__ dst,
                               const unsigned* __restrict__ segmax,
                               float* __restrict__ segsum, int E)
{
  int idx = blockIdx.x * 256 + threadIdx.x;
  if (idx >= E * 4) return;
  int e = idx >> 2, h = idx & 3;
  float m = funmap(segmax[dst[e] * 4 + h]);
  float v = expf(score[idx] - m);
  score[idx] = v;
  atomicAdd(&segsum[dst[e] * 4 + h], v);
}

__global__ __launch_bounds__(256) void scatter_kernel(
    const float* __restrict__ escore, const float* __restrict__ segsum,
    const int* __restrict__ src, const int* __restrict__ dst,
    const float* __restrict__ v, float* __restrict__ out, float coef, int E)
{
  int wid = (blockIdx.x * 256 + threadIdx.x) >> 6;
  int lane = threadIdx.x & 63;
  if (wid >= E) return;
  int s = src[wid], d = dst[wid];
  const float* vr = v + (long long)s * EMB;
  float* orow = out + (long long)d * EMB;
#pragma unroll
  for (int h = 0; h < NHEADS; ++h) {
    float a = escore[(long long)wid * 4 + h] / segsum[d * 4 + h] * coef;
    atomicAdd(&orow[h * DKH + lane], a * vr[h * DKH + lane]);
    atomicAdd(&orow[h * DKH + 64 + lane], a * vr[h * DKH + 64 + lane]);
    atomicAdd(&orow[h * DKH + 128 + lane], a * vr[h * DKH + 128 + lane]);
  }
}

}  // namespace

extern "C" void kernel_launch(void* const* d_in, const int* in_sizes, int n_in,
                              void* d_out, int out_size, void* d_ws, size_t ws_size,
                              hipStream_t stream)
{
  const float* q_emb   = (const float*)d_in[0];
  const float* t_emb   = (const float*)d_in[1];
  const int*   give_src = (const int*)d_in[2];
  const int*   give_dst = (const int*)d_in[3];
  const int*   i1_src  = (const int*)d_in[4];
  const int*   i1_dst  = (const int*)d_in[5];
  const int*   i2_src  = (const int*)d_in[6];
  const int*   i2_dst  = (const int*)d_in[7];
  const float* Wq_enc  = (const float*)d_in[8];
  const float* bq_enc  = (const float*)d_in[9];
  const float* Wc      = (const float*)d_in[10];
  const float* bc      = (const float*)d_in[11];
  const float* centers = (const float*)d_in[12];
  const float* kW      = (const float*)d_in[13];
  const float* kb      = (const float*)d_in[14];
  const float* qW      = (const float*)d_in[15];
  const float* qb      = (const float*)d_in[16];
  const float* vW      = (const float*)d_in[17];
  const float* vb      = (const float*)d_in[18];
  const float* rel_att = (const float*)d_in[19];
  const float* rel_msg = (const float*)d_in[20];
  const float* rel_pri = (const float*)d_in[21];
  const float* Wout    = (const float*)d_in[22];
  const float* bout    = (const float*)d_in[23];
  float* out = (float*)d_out;

  // workspace carve-up
  float* p = (float*)d_ws;
  auto take = [&](size_t n) { float* r = p; p += n; return r; };
  float* h_q    = take((size_t)NQ * EMB);      // 23.04M
  float* h_tag  = take((size_t)TLEN * EMB);    // 2.304M
  float* k_tag  = take((size_t)TLEN * EMB);
  float* v_tag  = take((size_t)TLEN * EMB);
  float* q_tag  = take((size_t)TLEN * EMB);
  float* k_rel  = take((size_t)TLEN * EMB);
  float* v_rel  = take((size_t)TLEN * EMB);
  float* escore = take((size_t)EG * HNEED * 4);  // 1.2M (largest relation)
  unsigned* seg_max = (unsigned*)take((size_t)NQ * 4);
  float* seg_sum = take((size_t)NQ * 4);
  int* gsrc = (int*)take(EG * HNEED);
  int* gdst = (int*)take(EG * HNEED);
  float* q_que;
  size_t used = (size_t)((char*)p - (char*)d_ws);
  if (used + (size_t)NQ * EMB * sizeof(float) <= ws_size) {
    q_que = take((size_t)NQ * EMB);
  } else {
    q_que = out;  // d_out as scratch: fully overwritten by final GEMMs
  }

  auto gemm = [&](int EPI, const float* A, int lda, long long sAz,
                  const float* B, int ldb, long long sBz,
                  float* C, int ldc, long long sCz,
                  const float* bias, const float* extra,
                  int M, int N, int K, int batch) {
    dim3 grid((N + BN - 1) / BN, (M + BM - 1) / BM, batch);
    if (EPI == 0)
      gemm_f32<0><<<grid, 256, 0, stream>>>(A, lda, sAz, B, ldb, sBz, C, ldc, sCz, bias, extra, M, N, K);
    else if (EPI == 1)
      gemm_f32<1><<<grid, 256, 0, stream>>>(A, lda, sAz, B, ldb, sBz, C, ldc, sCz, bias, extra, M, N, K);
    else
      gemm_f32<2><<<grid, 256, 0, stream>>>(A, lda, sAz, B, ldb, sBz, C, ldc, sCz, bias, extra, M, N, K);
  };

  // give edges (head-replicated)
  build_give_edges<<<(EG * HNEED + 255) / 256, 256, 0, stream>>>(give_src, give_dst, gsrc, gdst);

  // q encoder: q_h = split-heads(q_emb @ Wq_enc + b) + tile(q_emb)
  gemm(1, q_emb, EMB, 0, Wq_enc, EMB * HNEED, 0, h_q, EMB, 0, bq_enc, q_emb,
       QLEN, EMB * HNEED, EMB, 1);
  // q_h += softmax(q_h @ Wc + bc) @ centers
  assign_center_kernel<<<NQ, 256, 0, stream>>>(h_q, Wc, bc, centers);
  // h_tag = t_emb
  hipMemcpyAsync(h_tag, t_emb, (size_t)TLEN * EMB * sizeof(float),
                 hipMemcpyDeviceToDevice, stream);

  auto run_rel = [&](const float* qbuf, const int* esrc, const int* edst, int E,
                     int n_dst, const float* ratt, const float* rmsg,
                     const float* rpri_p, float coef, float* outbuf) {
    // per-head relation K/V transforms (batched over 4 heads)
    gemm(0, k_tag, EMB, DKH, ratt, DKH, (long long)DKH * DKH, k_rel, EMB, DKH,
         nullptr, nullptr, TLEN, DKH, DKH, NHEADS);
    gemm(0, v_tag, EMB, DKH, rmsg, DKH, (long long)DKH * DKH, v_rel, EMB, DKH,
         nullptr, nullptr, TLEN, DKH, DKH, NHEADS);
    edge_score<<<((size_t)E * 64 + 255) / 256, 256, 0, stream>>>(qbuf, k_rel, esrc, edst, rpri_p, escore, E);
    hipMemsetAsync(seg_max, 0, (size_t)n_dst * 4 * sizeof(unsigned), stream);
    hipMemsetAsync(seg_sum, 0, (size_t)n_dst * 4 * sizeof(float), stream);
    seg_max_kernel<<<(E * 4 + 255) / 256, 256, 0, stream>>>(escore, edst, seg_max, E);
    exp_sum_kernel<<<(E * 4 + 255) / 256, 256, 0, stream>>>(escore, edst, seg_max, seg_sum, E);
    scatter_kernel<<<((size_t)E * 64 + 255) / 256, 256, 0, stream>>>(escore, seg_sum, esrc, edst, v_rel, outbuf, coef, E);
  };

  for (int l = 0; l < 2; ++l) {
    const long long WS = (long long)EMB * EMB;  // 589824
    gemm(0, h_tag, EMB, 0, kW + (l * 2 + 0) * WS, EMB, 0, k_tag, EMB, 0,
         kb + (l * 2 + 0) * EMB, nullptr, TLEN, EMB, EMB, 1);
    gemm(0, h_tag, EMB, 0, vW + (l * 2 + 0) * WS, EMB, 0, v_tag, EMB, 0,
         vb + (l * 2 + 0) * EMB, nullptr, TLEN, EMB, EMB, 1);
    gemm(0, h_tag, EMB, 0, qW + (l * 2 + 0) * WS, EMB, 0, q_tag, EMB, 0,
         qb + (l * 2 + 0) * EMB, nullptr, TLEN, EMB, EMB, 1);
    gemm(0, h_q, EMB, 0, qW + (l * 2 + 1) * WS, EMB, 0, q_que, EMB, 0,
         qb + (l * 2 + 1) * EMB, nullptr, NQ, EMB, EMB, 1);

    const long long RS = (long long)NHEADS * DKH * DKH;  // 147456
    // relation 0: tag -> question (give), residual-accumulate into h_q
    run_rel(q_que, gsrc, gdst, EG * HNEED, NQ,
            rel_att + (l * 3 + 0) * RS, rel_msg + (l * 3 + 0) * RS,
            rel_pri + (l * 3 + 0) * NHEADS, 1.0f, h_q);
    // relations 1,2: tag -> tag (inter), mean over the two -> 0.5 each into h_tag
    run_rel(q_tag, i1_src, i1_dst, EI, TLEN,
            rel_att + (l * 3 + 1) * RS, rel_msg + (l * 3 + 1) * RS,
            rel_pri + (l * 3 + 1) * NHEADS, 0.5f, h_tag);
    run_rel(q_tag, i2_src, i2_dst, EI, TLEN,
            rel_att + (l * 3 + 2) * RS, rel_msg + (l * 3 + 2) * RS,
            rel_pri + (l * 3 + 2) * NHEADS, 0.5f, h_tag);
  }

  // outputs
  gemm(2, h_q, EMB, 0, Wout, EMB, 0, out, EMB, 0, bout, nullptr, NQ, EMB, EMB, 1);
  gemm(0, h_tag, EMB, 0, Wout, EMB, 0, out + (size_t)NQ * EMB, EMB, 0, bout,
       nullptr, TLEN, EMB, EMB, 1);
}

// Round 2
// 4279.568 us; speedup vs baseline: 1.5486x; 1.5486x over previous
//
#include <hip/hip_runtime.h>

#define QLEN 10000
#define TLEN 3000
#define EMB 768
#define HNEED 3
#define NQ (QLEN * HNEED)
#define EG 100000
#define EI 100000
#define DKH 192
#define NHEADS 4

namespace {

constexpr float SCALE = 0.07216878364870322f; // 1/sqrt(192)
constexpr int BM = 64, BN = 64, BK = 16;

// ---------------------------------------------------------------- GEMM (f32)
// C = A @ B (+bias). EPI 0: plain row-major C.
// EPI 1: question-encoder epilogue: out[(n/768)*QLEN + m][n%768] = v + q_emb[m][n%768]
// EPI 2: ques output epilogue: out[(m%QLEN)*3 + m/QLEN][n] = v
template <int EPI>
__global__ __launch_bounds__(256) void gemm_f32(
    const float* __restrict__ A, int lda, long long sAz,
    const float* __restrict__ B, int ldb, long long sBz,
    float* __restrict__ C, int ldc, long long sCz,
    const float* __restrict__ bias, const float* __restrict__ extra,
    int M, int N, int K)
{
  __shared__ __align__(16) float As[BK][BM + 4];
  __shared__ __align__(16) float Bs[BK][BN + 4];
  const int z = blockIdx.z;
  A += z * sAz;
  B += z * sBz;
  C += z * sCz;
  const int bm = blockIdx.y * BM, bn = blockIdx.x * BN;
  const int tid = threadIdx.x;
  const int tx = tid & 15, ty = tid >> 4;
  const int ar = tid >> 4, ac = tid & 15;   // A loader: 16 rows x 16 k per pass
  const int br = tid >> 6, bc = tid & 63;   // B loader: 4 k-rows x 64 n per pass
  float acc[4][4] = {};
  for (int k0 = 0; k0 < K; k0 += BK) {
#pragma unroll
    for (int i = 0; i < 4; ++i) {
      int m = bm + ar + i * 16;
      As[ac][ar + i * 16] = (m < M) ? A[(long long)m * lda + k0 + ac] : 0.f;
    }
#pragma unroll
    for (int i = 0; i < 4; ++i) {
      int n = bn + bc;
      Bs[br + i * 4][bc] = (n < N) ? B[(long long)(k0 + br + i * 4) * ldb + n] : 0.f;
    }
    __syncthreads();
#pragma unroll
    for (int kk = 0; kk < BK; ++kk) {
      float4 a4 = *reinterpret_cast<const float4*>(&As[kk][ty * 4]);
      float4 b4 = *reinterpret_cast<const float4*>(&Bs[kk][tx * 4]);
      float a[4] = {a4.x, a4.y, a4.z, a4.w};
      float b[4] = {b4.x, b4.y, b4.z, b4.w};
#pragma unroll
      for (int i = 0; i < 4; ++i)
#pragma unroll
        for (int j = 0; j < 4; ++j) acc[i][j] = fmaf(a[i], b[j], acc[i][j]);
    }
    __syncthreads();
  }
#pragma unroll
  for (int i = 0; i < 4; ++i) {
    int m = bm + ty * 4 + i;
    if (m >= M) continue;
#pragma unroll
    for (int j = 0; j < 4; ++j) {
      int n = bn + tx * 4 + j;
      if (n >= N) continue;
      float v = acc[i][j] + (bias ? bias[n] : 0.f);
      if (EPI == 0) {
        C[(long long)m * ldc + n] = v;
      } else if (EPI == 1) {
        int h = n / EMB, c = n - h * EMB;
        C[((long long)h * QLEN + m) * EMB + c] = v + extra[(long long)m * EMB + c];
      } else {
        int i2 = m % QLEN, h = m / QLEN;
        C[((long long)i2 * HNEED + h) * EMB + n] = v;
      }
    }
  }
}

// --------------------------------------------- fused assign-softmax + centers
__global__ __launch_bounds__(256) void assign_center_kernel(
    float* __restrict__ qh, const float* __restrict__ Wc,
    const float* __restrict__ bc, const float* __restrict__ centers)
{
  const int row = blockIdx.x;
  const int tid = threadIdx.x;
  __shared__ float red[4][10];
  __shared__ float assign_s[10];
  float part[10] = {};
  for (int d = tid; d < EMB; d += 256) {
    float v = qh[(long long)row * EMB + d];
#pragma unroll
    for (int j = 0; j < 10; ++j) part[j] += v * Wc[d * 10 + j];
  }
#pragma unroll
  for (int j = 0; j < 10; ++j)
#pragma unroll
    for (int off = 32; off; off >>= 1) part[j] += __shfl_down(part[j], off);
  const int wave = tid >> 6, lane = tid & 63;
  if (lane == 0)
    for (int j = 0; j < 10; ++j) red[wave][j] = part[j];
  __syncthreads();
  if (tid == 0) {
    float lg[10], m = -1e30f, s = 0.f;
    for (int j = 0; j < 10; ++j) {
      lg[j] = red[0][j] + red[1][j] + red[2][j] + red[3][j] + bc[j];
      m = fmaxf(m, lg[j]);
    }
    for (int j = 0; j < 10; ++j) {
      float e = expf(lg[j] - m);
      assign_s[j] = e;
      s += e;
    }
    float inv = 1.f / s;
    for (int j = 0; j < 10; ++j) assign_s[j] *= inv;
  }
  __syncthreads();
  for (int c = tid; c < EMB; c += 256) {
    float a = 0.f;
#pragma unroll
    for (int j = 0; j < 10; ++j) a += assign_s[j] * centers[j * EMB + c];
    qh[(long long)row * EMB + c] += a;
  }
}

// ------------------------------------------------------------- CSR build
__global__ void hist_kernel(const int* __restrict__ dst, int* __restrict__ cnt, int E)
{
  int e = blockIdx.x * 256 + threadIdx.x;
  if (e < E) atomicAdd(&cnt[dst[e]], 1);
}

__global__ __launch_bounds__(1024) void scan_fill_kernel(
    const int* __restrict__ cnt, int* __restrict__ rowptr, int* __restrict__ cur, int n)
{
  __shared__ int buf[1024];
  const int tid = threadIdx.x;
  const int chunk = (n + 1023) >> 10;
  const int base = tid * chunk;
  int s = 0;
  for (int i = 0; i < chunk; ++i) {
    int idx = base + i;
    if (idx < n) s += cnt[idx];
  }
  buf[tid] = s;
  __syncthreads();
  for (int off = 1; off < 1024; off <<= 1) {
    int v = (tid >= off) ? buf[tid - off] : 0;
    __syncthreads();
    buf[tid] += v;
    __syncthreads();
  }
  int run = (tid == 0) ? 0 : buf[tid - 1];
  for (int i = 0; i < chunk; ++i) {
    int idx = base + i;
    if (idx < n) {
      rowptr[idx] = run;
      cur[idx] = run;
      run += cnt[idx];
    }
  }
  if (tid == 1023) rowptr[n] = buf[1023];
}

__global__ void fill_kernel(const int* __restrict__ src, const int* __restrict__ dst,
                            int* __restrict__ cur, int* __restrict__ adj, int E)
{
  int e = blockIdx.x * 256 + threadIdx.x;
  if (e < E) {
    int p = atomicAdd(&cur[dst[e]], 1);
    adj[p] = src[e];
  }
}

// --------------------------------------- fused gather attention (online softmax)
// one wave per (copy, dst-node, head); CSR shared across copies (dst offset cp*n_dst)
template <int NCOPY>
__global__ __launch_bounds__(256) void gather_attn(
    const float* __restrict__ q, const float* __restrict__ k,
    const float* __restrict__ v, const int* __restrict__ rowptr,
    const int* __restrict__ adj, const float* __restrict__ rpri,
    float coef, float* __restrict__ out, int n_dst)
{
  const int w = (blockIdx.x * 256 + threadIdx.x) >> 6;
  const int lane = threadIdx.x & 63;
  if (w >= n_dst * NCOPY * NHEADS) return;
  const int h = w & 3;
  const int t = w >> 2;
  const int d = t % n_dst;
  const int cp = t / n_dst;
  const int rs = rowptr[d], re = rowptr[d + 1];
  if (rs == re) return;  // no in-edges: output keeps residual
  const long long row = (long long)(cp * n_dst + d) * EMB + h * DKH;
  const float* qr = q + row;
  const float q0 = qr[lane], q1 = qr[64 + lane], q2 = qr[128 + lane];
  const float pri = rpri[h] * SCALE;
  float m = -1e30f, s = 0.f, a0 = 0.f, a1 = 0.f, a2 = 0.f;
  for (int i = rs; i < re; ++i) {
    const int sn = adj[i];
    const float* kr = k + (long long)sn * EMB + h * DKH;
    float dot = q0 * kr[lane] + q1 * kr[64 + lane] + q2 * kr[128 + lane];
#pragma unroll
    for (int off = 32; off; off >>= 1) dot += __shfl_xor(dot, off);
    const float score = dot * pri;
    const float nm = fmaxf(m, score);
    const float f = __expf(m - nm);
    const float e = __expf(score - nm);
    s = s * f + e;
    const float* vr = v + (long long)sn * EMB + h * DKH;
    a0 = a0 * f + e * vr[lane];
    a1 = a1 * f + e * vr[64 + lane];
    a2 = a2 * f + e * vr[128 + lane];
    m = nm;
  }
  const float inv = coef / s;
  float* orow = out + row;
  orow[lane] += a0 * inv;
  orow[64 + lane] += a1 * inv;
  orow[128 + lane] += a2 * inv;
}

}  // namespace

extern "C" void kernel_launch(void* const* d_in, const int* in_sizes, int n_in,
                              void* d_out, int out_size, void* d_ws, size_t ws_size,
                              hipStream_t stream)
{
  const float* q_emb   = (const float*)d_in[0];
  const float* t_emb   = (const float*)d_in[1];
  const int*   give_src = (const int*)d_in[2];
  const int*   give_dst = (const int*)d_in[3];
  const int*   i1_src  = (const int*)d_in[4];
  const int*   i1_dst  = (const int*)d_in[5];
  const int*   i2_src  = (const int*)d_in[6];
  const int*   i2_dst  = (const int*)d_in[7];
  const float* Wq_enc  = (const float*)d_in[8];
  const float* bq_enc  = (const float*)d_in[9];
  const float* Wc      = (const float*)d_in[10];
  const float* bc      = (const float*)d_in[11];
  const float* centers = (const float*)d_in[12];
  const float* kW      = (const float*)d_in[13];
  const float* kb      = (const float*)d_in[14];
  const float* qW      = (const float*)d_in[15];
  const float* qb      = (const float*)d_in[16];
  const float* vW      = (const float*)d_in[17];
  const float* vb      = (const float*)d_in[18];
  const float* rel_att = (const float*)d_in[19];
  const float* rel_msg = (const float*)d_in[20];
  const float* rel_pri = (const float*)d_in[21];
  const float* Wout    = (const float*)d_in[22];
  const float* bout    = (const float*)d_in[23];
  float* out = (float*)d_out;

  // workspace carve-up
  float* p = (float*)d_ws;
  auto take = [&](size_t n) { float* r = p; p += n; return r; };
  float* h_q    = take((size_t)NQ * EMB);
  float* h_tag  = take((size_t)TLEN * EMB);
  float* k_tag  = take((size_t)TLEN * EMB);
  float* v_tag  = take((size_t)TLEN * EMB);
  float* q_tag  = take((size_t)TLEN * EMB);
  float* k_rel  = take((size_t)TLEN * EMB);
  float* v_rel  = take((size_t)TLEN * EMB);
  // CSR (built once per launch; graphs are static)
  int* rp_g  = (int*)take(QLEN + 1);
  int* rp_1  = (int*)take(TLEN + 1);
  int* rp_2  = (int*)take(TLEN + 1);
  int* cur_g = (int*)take(QLEN);
  int* cur_1 = (int*)take(TLEN);
  int* cur_2 = (int*)take(TLEN);
  int* adj_g = (int*)take(EG);
  int* adj_1 = (int*)take(EI);
  int* adj_2 = (int*)take(EI);
  int* cnt   = (int*)take(QLEN);
  float* q_que;
  size_t used = (size_t)((char*)p - (char*)d_ws);
  if (used + (size_t)NQ * EMB * sizeof(float) <= ws_size) {
    q_que = take((size_t)NQ * EMB);
  } else {
    q_que = out;  // d_out as scratch: fully overwritten by final GEMMs
  }

  auto gemm = [&](int EPI, const float* A, int lda, long long sAz,
                  const float* B, int ldb, long long sBz,
                  float* C, int ldc, long long sCz,
                  const float* bias, const float* extra,
                  int M, int N, int K, int batch) {
    dim3 grid((N + BN - 1) / BN, (M + BM - 1) / BM, batch);
    if (EPI == 0)
      gemm_f32<0><<<grid, 256, 0, stream>>>(A, lda, sAz, B, ldb, sBz, C, ldc, sCz, bias, extra, M, N, K);
    else if (EPI == 1)
      gemm_f32<1><<<grid, 256, 0, stream>>>(A, lda, sAz, B, ldb, sBz, C, ldc, sCz, bias, extra, M, N, K);
    else
      gemm_f32<2><<<grid, 256, 0, stream>>>(A, lda, sAz, B, ldb, sBz, C, ldc, sCz, bias, extra, M, N, K);
  };

  // ---- CSR builds (static graphs, base give graph shared by 3 copies)
  auto build_csr = [&](const int* src, const int* dst, int E, int n,
                       int* rp, int* cu, int* adj) {
    hipMemsetAsync(cnt, 0, (size_t)n * sizeof(int), stream);
    hist_kernel<<<(E + 255) / 256, 256, 0, stream>>>(dst, cnt, E);
    scan_fill_kernel<<<1, 1024, 0, stream>>>(cnt, rp, cu, n);
    fill_kernel<<<(E + 255) / 256, 256, 0, stream>>>(src, dst, cu, adj, E);
  };
  build_csr(give_src, give_dst, EG, QLEN, rp_g, cur_g, adj_g);
  build_csr(i1_src, i1_dst, EI, TLEN, rp_1, cur_1, adj_1);
  build_csr(i2_src, i2_dst, EI, TLEN, rp_2, cur_2, adj_2);

  // q encoder: q_h = split-heads(q_emb @ Wq_enc + b) + tile(q_emb)
  gemm(1, q_emb, EMB, 0, Wq_enc, EMB * HNEED, 0, h_q, EMB, 0, bq_enc, q_emb,
       QLEN, EMB * HNEED, EMB, 1);
  // q_h += softmax(q_h @ Wc + bc) @ centers
  assign_center_kernel<<<NQ, 256, 0, stream>>>(h_q, Wc, bc, centers);
  // h_tag = t_emb
  hipMemcpyAsync(h_tag, t_emb, (size_t)TLEN * EMB * sizeof(float),
                 hipMemcpyDeviceToDevice, stream);

  auto run_rel = [&](const float* qbuf, const int* rp, const int* adj, int ncopy,
                     int n_dst, const float* ratt, const float* rmsg,
                     const float* rpri_p, float coef, float* outbuf) {
    gemm(0, k_tag, EMB, DKH, ratt, DKH, (long long)DKH * DKH, k_rel, EMB, DKH,
         nullptr, nullptr, TLEN, DKH, DKH, NHEADS);
    gemm(0, v_tag, EMB, DKH, rmsg, DKH, (long long)DKH * DKH, v_rel, EMB, DKH,
         nullptr, nullptr, TLEN, DKH, DKH, NHEADS);
    int waves = n_dst * ncopy * NHEADS;
    int blocks = (waves * 64 + 255) / 256;
    if (ncopy == 3)
      gather_attn<3><<<blocks, 256, 0, stream>>>(qbuf, k_rel, v_rel, rp, adj,
                                                 rpri_p, coef, outbuf, n_dst);
    else
      gather_attn<1><<<blocks, 256, 0, stream>>>(qbuf, k_rel, v_rel, rp, adj,
                                                 rpri_p, coef, outbuf, n_dst);
  };

  for (int l = 0; l < 2; ++l) {
    const long long WS = (long long)EMB * EMB;
    gemm(0, h_tag, EMB, 0, kW + (l * 2 + 0) * WS, EMB, 0, k_tag, EMB, 0,
         kb + (l * 2 + 0) * EMB, nullptr, TLEN, EMB, EMB, 1);
    gemm(0, h_tag, EMB, 0, vW + (l * 2 + 0) * WS, EMB, 0, v_tag, EMB, 0,
         vb + (l * 2 + 0) * EMB, nullptr, TLEN, EMB, EMB, 1);
    gemm(0, h_tag, EMB, 0, qW + (l * 2 + 0) * WS, EMB, 0, q_tag, EMB, 0,
         qb + (l * 2 + 0) * EMB, nullptr, TLEN, EMB, EMB, 1);
    gemm(0, h_q, EMB, 0, qW + (l * 2 + 1) * WS, EMB, 0, q_que, EMB, 0,
         qb + (l * 2 + 1) * EMB, nullptr, NQ, EMB, EMB, 1);

    const long long RS = (long long)NHEADS * DKH * DKH;
    // relation 0: tag -> question (give, 3 head-copies), residual into h_q
    run_rel(q_que, rp_g, adj_g, HNEED, QLEN,
            rel_att + (l * 3 + 0) * RS, rel_msg + (l * 3 + 0) * RS,
            rel_pri + (l * 3 + 0) * NHEADS, 1.0f, h_q);
    // relations 1,2: tag -> tag, mean -> 0.5 each into h_tag
    run_rel(q_tag, rp_1, adj_1, 1, TLEN,
            rel_att + (l * 3 + 1) * RS, rel_msg + (l * 3 + 1) * RS,
            rel_pri + (l * 3 + 1) * NHEADS, 0.5f, h_tag);
    run_rel(q_tag, rp_2, adj_2, 1, TLEN,
            rel_att + (l * 3 + 2) * RS, rel_msg + (l * 3 + 2) * RS,
            rel_pri + (l * 3 + 2) * NHEADS, 0.5f, h_tag);
  }

  // outputs
  gemm(2, h_q, EMB, 0, Wout, EMB, 0, out, EMB, 0, bout, nullptr, NQ, EMB, EMB, 1);
  gemm(0, h_tag, EMB, 0, Wout, EMB, 0, out + (size_t)NQ * EMB, EMB, 0, bout,
       nullptr, TLEN, EMB, EMB, 1);
}

// Round 3
// 1900.616 us; speedup vs baseline: 3.4870x; 2.2517x over previous
//
#include <hip/hip_runtime.h>

#define QLEN 10000
#define TLEN 3000
#define EMB 768
#define HNEED 3
#define NQ (QLEN * HNEED)
#define EG 100000
#define EI 100000
#define DKH 192
#define NHEADS 4

namespace {

typedef unsigned short u16;
typedef __attribute__((ext_vector_type(8))) short bf16x8;  // if compile error: try __bf16
typedef __attribute__((ext_vector_type(4))) float f32x4;

constexpr float SCALE = 0.07216878364870322f; // 1/sqrt(192)

__device__ inline u16 f2bf(float f) {
  unsigned u = __float_as_uint(f);
  unsigned r = (u + 0x7FFFu + ((u >> 16) & 1u)) >> 16;  // RNE
  return (u16)r;
}

__device__ inline void gload_lds16(const u16* g, u16* s) {
  __builtin_amdgcn_global_load_lds(
      (const __attribute__((address_space(1))) unsigned*)g,
      (__attribute__((address_space(3))) unsigned*)s, 16, 0, 0);
}

// ------------------------------------------------------------ bf16 MFMA GEMM
// A [M][K] bf16 row-major, Bt [N][K] bf16 row-major (B transposed).
// 128x128 tile, BK=32, 4 waves each computing 64x64 via 4x4 mfma 16x16x32.
// EPI 0: C[m][n]  (OUTBF: bf16 or f32)
// EPI 1: encoder: C[(n/768)*QLEN + m][n%768] = v + extra[m][n%768]   (f32)
// EPI 2: ques out: C[(m%QLEN)*3 + m/QLEN][n] = v                     (f32)
template <int EPI, int OUTBF>
__global__ __launch_bounds__(256) void gemm_bf16(
    const u16* __restrict__ A, int lda, long long sAz,
    const u16* __restrict__ Bt, int ldb, long long sBz,
    void* __restrict__ Cv, int ldc, long long sCz,
    const float* __restrict__ bias, const float* __restrict__ extra,
    int M, int N, int K)
{
  __shared__ __align__(16) u16 As[128 * 32];
  __shared__ __align__(16) u16 Bs[128 * 32];
  const int z = blockIdx.z;
  A += z * sAz;
  Bt += z * sBz;
  float* Cf = (float*)Cv + z * sCz;
  u16* Ch = (u16*)Cv + z * sCz;
  const int bm = blockIdx.y * 128, bn = blockIdx.x * 128;
  const int tid = threadIdx.x;
  const int w = tid >> 6, l = tid & 63;
  const int wr = w >> 1, wc = w & 1;
  const int l16 = l & 15, lk = l >> 4;
  const int srow = tid >> 2;
  const int scol = (tid & 3) * 8;

  int r0 = bm + srow;      if (r0 > M - 1) r0 = M - 1;
  int r1 = bm + srow + 64; if (r1 > M - 1) r1 = M - 1;
  int c0 = bn + srow;      if (c0 > N - 1) c0 = N - 1;
  int c1 = bn + srow + 64; if (c1 > N - 1) c1 = N - 1;
  const u16* pa0 = A + (long long)r0 * lda + scol;
  const u16* pa1 = A + (long long)r1 * lda + scol;
  const u16* pb0 = Bt + (long long)c0 * ldb + scol;
  const u16* pb1 = Bt + (long long)c1 * ldb + scol;
  u16* dA0 = As + w * 512;
  u16* dA1 = As + w * 512 + 2048;
  u16* dB0 = Bs + w * 512;
  u16* dB1 = Bs + w * 512 + 2048;

  f32x4 acc[4][4] = {};

  for (int k0 = 0; k0 < K; k0 += 32) {
    gload_lds16(pa0 + k0, dA0);
    gload_lds16(pa1 + k0, dA1);
    gload_lds16(pb0 + k0, dB0);
    gload_lds16(pb1 + k0, dB1);
    __syncthreads();
    bf16x8 af[4], bf[4];
#pragma unroll
    for (int m = 0; m < 4; ++m)
      af[m] = *(const bf16x8*)&As[(wr * 64 + m * 16 + l16) * 32 + lk * 8];
#pragma unroll
    for (int n = 0; n < 4; ++n)
      bf[n] = *(const bf16x8*)&Bs[(wc * 64 + n * 16 + l16) * 32 + lk * 8];
#pragma unroll
    for (int m = 0; m < 4; ++m)
#pragma unroll
      for (int n = 0; n < 4; ++n)
        acc[m][n] = __builtin_amdgcn_mfma_f32_16x16x32_bf16(af[m], bf[n], acc[m][n], 0, 0, 0);
    __syncthreads();
  }

#pragma unroll
  for (int m = 0; m < 4; ++m) {
#pragma unroll
    for (int j = 0; j < 4; ++j) {
      int grow = bm + wr * 64 + m * 16 + lk * 4 + j;
      if (grow >= M) continue;
#pragma unroll
      for (int n = 0; n < 4; ++n) {
        int gcol = bn + wc * 64 + n * 16 + l16;
        if (gcol >= N) continue;
        float val = acc[m][n][j] + (bias ? bias[gcol] : 0.f);
        if (EPI == 0) {
          if (OUTBF)
            Ch[(long long)grow * ldc + gcol] = f2bf(val);
          else
            Cf[(long long)grow * ldc + gcol] = val;
        } else if (EPI == 1) {
          int h = gcol / EMB, c = gcol - h * EMB;
          Cf[((long long)h * QLEN + grow) * EMB + c] = val + extra[(long long)grow * EMB + c];
        } else {
          int i2 = grow % QLEN, h = grow / QLEN;
          Cf[((long long)i2 * HNEED + h) * EMB + gcol] = val;
        }
      }
    }
  }
}

// ------------------------------------------------------ conversion / transpose
__global__ void f2bf_kernel(const float* __restrict__ in, u16* __restrict__ out, long long n)
{
  long long i = ((long long)blockIdx.x * 256 + threadIdx.x) * 4;
  if (i >= n) return;
  float4 v = *(const float4*)(in + i);
  ushort4 o;
  o.x = f2bf(v.x); o.y = f2bf(v.y); o.z = f2bf(v.z); o.w = f2bf(v.w);
  *(ushort4*)(out + i) = o;
}

// out[z][c][r] = bf16(in[z][r][c])
__global__ __launch_bounds__(256) void transpose_bf(
    const float* __restrict__ in, u16* __restrict__ out, int R, int C)
{
  __shared__ float t[32][33];
  const long long zoff = (long long)blockIdx.z * R * C;
  in += zoff;
  out += zoff;
  const int c0 = blockIdx.x * 32, r0 = blockIdx.y * 32;
  const int tx = threadIdx.x & 31, ty = threadIdx.x >> 5;  // 32 x 8
  for (int i = 0; i < 32; i += 8) {
    int r = r0 + ty + i, c = c0 + tx;
    t[ty + i][tx] = (r < R && c < C) ? in[(long long)r * C + c] : 0.f;
  }
  __syncthreads();
  for (int i = 0; i < 32; i += 8) {
    int c = c0 + ty + i, r = r0 + tx;
    if (c < C && r < R) out[(long long)c * R + r] = f2bf(t[tx][ty + i]);
  }
}

// --------------------------------------------- fused assign-softmax + centers
__global__ __launch_bounds__(256) void assign_center_kernel(
    float* __restrict__ qh, const float* __restrict__ Wc,
    const float* __restrict__ bc, const float* __restrict__ centers)
{
  const int row = blockIdx.x;
  const int tid = threadIdx.x;
  __shared__ float red[4][10];
  __shared__ float assign_s[10];
  float part[10] = {};
  for (int d = tid; d < EMB; d += 256) {
    float v = qh[(long long)row * EMB + d];
#pragma unroll
    for (int j = 0; j < 10; ++j) part[j] += v * Wc[d * 10 + j];
  }
#pragma unroll
  for (int j = 0; j < 10; ++j)
#pragma unroll
    for (int off = 32; off; off >>= 1) part[j] += __shfl_down(part[j], off);
  const int wave = tid >> 6, lane = tid & 63;
  if (lane == 0)
    for (int j = 0; j < 10; ++j) red[wave][j] = part[j];
  __syncthreads();
  if (tid == 0) {
    float lg[10], m = -1e30f, s = 0.f;
    for (int j = 0; j < 10; ++j) {
      lg[j] = red[0][j] + red[1][j] + red[2][j] + red[3][j] + bc[j];
      m = fmaxf(m, lg[j]);
    }
    for (int j = 0; j < 10; ++j) {
      float e = expf(lg[j] - m);
      assign_s[j] = e;
      s += e;
    }
    float inv = 1.f / s;
    for (int j = 0; j < 10; ++j) assign_s[j] *= inv;
  }
  __syncthreads();
  for (int c = tid; c < EMB; c += 256) {
    float a = 0.f;
#pragma unroll
    for (int j = 0; j < 10; ++j) a += assign_s[j] * centers[j * EMB + c];
    qh[(long long)row * EMB + c] += a;
  }
}

// ------------------------------------------------------------- CSR build
__global__ void hist_kernel(const int* __restrict__ dst, int* __restrict__ cnt, int E)
{
  int e = blockIdx.x * 256 + threadIdx.x;
  if (e < E) atomicAdd(&cnt[dst[e]], 1);
}

__global__ __launch_bounds__(1024) void scan_fill_kernel(
    const int* __restrict__ cnt, int* __restrict__ rowptr, int* __restrict__ cur, int n)
{
  __shared__ int buf[1024];
  const int tid = threadIdx.x;
  const int chunk = (n + 1023) >> 10;
  const int base = tid * chunk;
  int s = 0;
  for (int i = 0; i < chunk; ++i) {
    int idx = base + i;
    if (idx < n) s += cnt[idx];
  }
  buf[tid] = s;
  __syncthreads();
  for (int off = 1; off < 1024; off <<= 1) {
    int v = (tid >= off) ? buf[tid - off] : 0;
    __syncthreads();
    buf[tid] += v;
    __syncthreads();
  }
  int run = (tid == 0) ? 0 : buf[tid - 1];
  for (int i = 0; i < chunk; ++i) {
    int idx = base + i;
    if (idx < n) {
      rowptr[idx] = run;
      cur[idx] = run;
      run += cnt[idx];
    }
  }
  if (tid == 1023) rowptr[n] = buf[1023];
}

__global__ void fill_kernel(const int* __restrict__ src, const int* __restrict__ dst,
                            int* __restrict__ cur, int* __restrict__ adj, int E)
{
  int e = blockIdx.x * 256 + threadIdx.x;
  if (e < E) {
    int p = atomicAdd(&cur[dst[e]], 1);
    adj[p] = src[e];
  }
}

// --------------------------------------- fused gather attention (online softmax)
template <int NCOPY>
__global__ __launch_bounds__(256) void gather_attn(
    const float* __restrict__ q, const float* __restrict__ k,
    const float* __restrict__ v, const int* __restrict__ rowptr,
    const int* __restrict__ adj, const float* __restrict__ rpri,
    float coef, float* __restrict__ out, int n_dst)
{
  const int w = (blockIdx.x * 256 + threadIdx.x) >> 6;
  const int lane = threadIdx.x & 63;
  if (w >= n_dst * NCOPY * NHEADS) return;
  const int h = w & 3;
  const int t = w >> 2;
  const int d = t % n_dst;
  const int cp = t / n_dst;
  const int rs = rowptr[d], re = rowptr[d + 1];
  if (rs == re) return;
  const long long row = (long long)(cp * n_dst + d) * EMB + h * DKH;
  const float* qr = q + row;
  const float q0 = qr[lane], q1 = qr[64 + lane], q2 = qr[128 + lane];
  const float pri = rpri[h] * SCALE;
  float m = -1e30f, s = 0.f, a0 = 0.f, a1 = 0.f, a2 = 0.f;
  for (int i = rs; i < re; ++i) {
    const int sn = adj[i];
    const float* kr = k + (long long)sn * EMB + h * DKH;
    float dot = q0 * kr[lane] + q1 * kr[64 + lane] + q2 * kr[128 + lane];
#pragma unroll
    for (int off = 32; off; off >>= 1) dot += __shfl_xor(dot, off);
    const float score = dot * pri;
    const float nm = fmaxf(m, score);
    const float f = __expf(m - nm);
    const float e = __expf(score - nm);
    s = s * f + e;
    const float* vr = v + (long long)sn * EMB + h * DKH;
    a0 = a0 * f + e * vr[lane];
    a1 = a1 * f + e * vr[64 + lane];
    a2 = a2 * f + e * vr[128 + lane];
    m = nm;
  }
  const float inv = coef / s;
  float* orow = out + row;
  orow[lane] += a0 * inv;
  orow[64 + lane] += a1 * inv;
  orow[128 + lane] += a2 * inv;
}

}  // namespace

extern "C" void kernel_launch(void* const* d_in, const int* in_sizes, int n_in,
                              void* d_out, int out_size, void* d_ws, size_t ws_size,
                              hipStream_t stream)
{
  const float* q_emb   = (const float*)d_in[0];
  const float* t_emb   = (const float*)d_in[1];
  const int*   i1_src  = (const int*)d_in[4];
  const int*   i1_dst  = (const int*)d_in[5];
  const int*   i2_src  = (const int*)d_in[6];
  const int*   i2_dst  = (const int*)d_in[7];
  const int*   give_src = (const int*)d_in[2];
  const int*   give_dst = (const int*)d_in[3];
  const float* Wq_enc  = (const float*)d_in[8];
  const float* bq_enc  = (const float*)d_in[9];
  const float* Wc      = (const float*)d_in[10];
  const float* bc      = (const float*)d_in[11];
  const float* centers = (const float*)d_in[12];
  const float* kW      = (const float*)d_in[13];
  const float* kb      = (const float*)d_in[14];
  const float* qW      = (const float*)d_in[15];
  const float* qb      = (const float*)d_in[16];
  const float* vW      = (const float*)d_in[17];
  const float* vb      = (const float*)d_in[18];
  const float* rel_att = (const float*)d_in[19];
  const float* rel_msg = (const float*)d_in[20];
  const float* rel_pri = (const float*)d_in[21];
  const float* Wout    = (const float*)d_in[22];
  const float* bout    = (const float*)d_in[23];
  float* out = (float*)d_out;

  // -------- workspace carve-up (f32-element units, int/bf16 cast as needed)
  float* p = (float*)d_ws;
  auto take = [&](size_t n) { float* r = p; p += ((n + 3) & ~(size_t)3); return r; };
  float* h_q   = take((size_t)NQ * EMB);
  float* h_tag = take((size_t)TLEN * EMB);
  float* q_tag = take((size_t)TLEN * EMB);
  float* k_rel = take((size_t)TLEN * EMB);
  float* v_rel = take((size_t)TLEN * EMB);
  u16* h_q_bf   = (u16*)take((size_t)NQ * EMB / 2);
  u16* h_tag_bf = (u16*)take((size_t)TLEN * EMB / 2);
  u16* k_tag_bf = (u16*)take((size_t)TLEN * EMB / 2);
  u16* v_tag_bf = (u16*)take((size_t)TLEN * EMB / 2);
  const long long WS = (long long)EMB * EMB;        // 589824
  const long long RS = (long long)DKH * DKH;        // 36864
  u16* WqT   = (u16*)take((size_t)EMB * EMB * HNEED / 2);
  u16* qWT   = (u16*)take((size_t)4 * WS / 2);
  u16* kWT   = (u16*)take((size_t)4 * WS / 2);
  u16* vWT   = (u16*)take((size_t)4 * WS / 2);
  u16* WoutT = (u16*)take((size_t)WS / 2);
  u16* rattT = (u16*)take((size_t)24 * RS / 2);
  u16* rmsgT = (u16*)take((size_t)24 * RS / 2);
  int* rp_g  = (int*)take(QLEN + 1);
  int* rp_1  = (int*)take(TLEN + 1);
  int* rp_2  = (int*)take(TLEN + 1);
  int* cur_g = (int*)take(QLEN);
  int* cur_1 = (int*)take(TLEN);
  int* cur_2 = (int*)take(TLEN);
  int* adj_g = (int*)take(EG);
  int* adj_1 = (int*)take(EI);
  int* adj_2 = (int*)take(EI);
  int* cnt   = (int*)take(QLEN);
  u16* q_emb_bf = h_q_bf;        // overlay: dead before h_q_bf first written
  float* q_que = out;            // d_out as scratch; fully overwritten at end

  auto gemmb = [&](int EPI, int OUTBF, const u16* A, int lda, long long sAz,
                   const u16* Bt, int ldb, long long sBz,
                   void* C, int ldc, long long sCz,
                   const float* bias, const float* extra,
                   int M, int N, int K, int batch) {
    dim3 grid((N + 127) / 128, (M + 127) / 128, batch);
    if (EPI == 0 && OUTBF == 0)
      gemm_bf16<0, 0><<<grid, 256, 0, stream>>>(A, lda, sAz, Bt, ldb, sBz, C, ldc, sCz, bias, extra, M, N, K);
    else if (EPI == 0 && OUTBF == 1)
      gemm_bf16<0, 1><<<grid, 256, 0, stream>>>(A, lda, sAz, Bt, ldb, sBz, C, ldc, sCz, bias, extra, M, N, K);
    else if (EPI == 1)
      gemm_bf16<1, 0><<<grid, 256, 0, stream>>>(A, lda, sAz, Bt, ldb, sBz, C, ldc, sCz, bias, extra, M, N, K);
    else
      gemm_bf16<2, 0><<<grid, 256, 0, stream>>>(A, lda, sAz, Bt, ldb, sBz, C, ldc, sCz, bias, extra, M, N, K);
  };
  auto f2bf_launch = [&](const float* in, u16* o, long long n) {
    f2bf_kernel<<<(unsigned)((n / 4 + 255) / 256), 256, 0, stream>>>(in, o, n);
  };

  // -------- CSR builds (static graphs)
  auto build_csr = [&](const int* src, const int* dst, int E, int n,
                       int* rp, int* cu, int* adj) {
    hipMemsetAsync(cnt, 0, (size_t)n * sizeof(int), stream);
    hist_kernel<<<(E + 255) / 256, 256, 0, stream>>>(dst, cnt, E);
    scan_fill_kernel<<<1, 1024, 0, stream>>>(cnt, rp, cu, n);
    fill_kernel<<<(E + 255) / 256, 256, 0, stream>>>(src, dst, cu, adj, E);
  };
  build_csr(give_src, give_dst, EG, QLEN, rp_g, cur_g, adj_g);
  build_csr(i1_src, i1_dst, EI, TLEN, rp_1, cur_1, adj_1);
  build_csr(i2_src, i2_dst, EI, TLEN, rp_2, cur_2, adj_2);

  // -------- one-time weight transposes (f32 [R][C] -> bf16 [C][R])
  transpose_bf<<<dim3(EMB * HNEED / 32, EMB / 32, 1), 256, 0, stream>>>(Wq_enc, WqT, EMB, EMB * HNEED);
  transpose_bf<<<dim3(EMB / 32, EMB / 32, 4), 256, 0, stream>>>(qW, qWT, EMB, EMB);
  transpose_bf<<<dim3(EMB / 32, EMB / 32, 4), 256, 0, stream>>>(kW, kWT, EMB, EMB);
  transpose_bf<<<dim3(EMB / 32, EMB / 32, 4), 256, 0, stream>>>(vW, vWT, EMB, EMB);
  transpose_bf<<<dim3(EMB / 32, EMB / 32, 1), 256, 0, stream>>>(Wout, WoutT, EMB, EMB);
  transpose_bf<<<dim3(DKH / 32, DKH / 32, 24), 256, 0, stream>>>(rel_att, rattT, DKH, DKH);
  transpose_bf<<<dim3(DKH / 32, DKH / 32, 24), 256, 0, stream>>>(rel_msg, rmsgT, DKH, DKH);

  // -------- question encoder
  f2bf_launch(q_emb, q_emb_bf, (long long)QLEN * EMB);
  gemmb(1, 0, q_emb_bf, EMB, 0, WqT, EMB, 0, h_q, EMB, 0, bq_enc, q_emb,
        QLEN, EMB * HNEED, EMB, 1);
  assign_center_kernel<<<NQ, 256, 0, stream>>>(h_q, Wc, bc, centers);
  hipMemcpyAsync(h_tag, t_emb, (size_t)TLEN * EMB * sizeof(float),
                 hipMemcpyDeviceToDevice, stream);

  auto run_rel = [&](const float* qbuf, const int* rp, const int* adj, int ncopy,
                     int n_dst, const u16* rattTp, const u16* rmsgTp,
                     const float* rpri_p, float coef, float* outbuf) {
    gemmb(0, 0, k_tag_bf, EMB, DKH, rattTp, DKH, RS, k_rel, EMB, DKH,
          nullptr, nullptr, TLEN, DKH, DKH, NHEADS);
    gemmb(0, 0, v_tag_bf, EMB, DKH, rmsgTp, DKH, RS, v_rel, EMB, DKH,
          nullptr, nullptr, TLEN, DKH, DKH, NHEADS);
    int waves = n_dst * ncopy * NHEADS;
    int blocks = (waves * 64 + 255) / 256;
    if (ncopy == 3)
      gather_attn<3><<<blocks, 256, 0, stream>>>(qbuf, k_rel, v_rel, rp, adj,
                                                 rpri_p, coef, outbuf, n_dst);
    else
      gather_attn<1><<<blocks, 256, 0, stream>>>(qbuf, k_rel, v_rel, rp, adj,
                                                 rpri_p, coef, outbuf, n_dst);
  };

  for (int l = 0; l < 2; ++l) {
    f2bf_launch(h_tag, h_tag_bf, (long long)TLEN * EMB);
    f2bf_launch(h_q, h_q_bf, (long long)NQ * EMB);
    gemmb(0, 1, h_tag_bf, EMB, 0, kWT + (l * 2 + 0) * WS, EMB, 0, k_tag_bf, EMB, 0,
          kb + (l * 2 + 0) * EMB, nullptr, TLEN, EMB, EMB, 1);
    gemmb(0, 1, h_tag_bf, EMB, 0, vWT + (l * 2 + 0) * WS, EMB, 0, v_tag_bf, EMB, 0,
          vb + (l * 2 + 0) * EMB, nullptr, TLEN, EMB, EMB, 1);
    gemmb(0, 0, h_tag_bf, EMB, 0, qWT + (l * 2 + 0) * WS, EMB, 0, q_tag, EMB, 0,
          qb + (l * 2 + 0) * EMB, nullptr, TLEN, EMB, EMB, 1);
    gemmb(0, 0, h_q_bf, EMB, 0, qWT + (l * 2 + 1) * WS, EMB, 0, q_que, EMB, 0,
          qb + (l * 2 + 1) * EMB, nullptr, NQ, EMB, EMB, 1);

    run_rel(q_que, rp_g, adj_g, HNEED, QLEN,
            rattT + (l * 3 + 0) * 4 * RS, rmsgT + (l * 3 + 0) * 4 * RS,
            rel_pri + (l * 3 + 0) * NHEADS, 1.0f, h_q);
    run_rel(q_tag, rp_1, adj_1, 1, TLEN,
            rattT + (l * 3 + 1) * 4 * RS, rmsgT + (l * 3 + 1) * 4 * RS,
            rel_pri + (l * 3 + 1) * NHEADS, 0.5f, h_tag);
    run_rel(q_tag, rp_2, adj_2, 1, TLEN,
            rattT + (l * 3 + 2) * 4 * RS, rmsgT + (l * 3 + 2) * 4 * RS,
            rel_pri + (l * 3 + 2) * NHEADS, 0.5f, h_tag);
  }

  // -------- outputs
  f2bf_launch(h_q, h_q_bf, (long long)NQ * EMB);
  f2bf_launch(h_tag, h_tag_bf, (long long)TLEN * EMB);
  gemmb(2, 0, h_q_bf, EMB, 0, WoutT, EMB, 0, out, EMB, 0, bout, nullptr,
        NQ, EMB, EMB, 1);
  gemmb(0, 0, h_tag_bf, EMB, 0, WoutT, EMB, 0, out + (size_t)NQ * EMB, EMB, 0,
        bout, nullptr, TLEN, EMB, EMB, 1);
}

// Round 4
// 1431.147 us; speedup vs baseline: 4.6308x; 1.3280x over previous
//
#include <hip/hip_runtime.h>

#define QLEN 10000
#define TLEN 3000
#define EMB 768
#define HNEED 3
#define NQ (QLEN * HNEED)
#define EG 100000
#define EI 100000
#define DKH 192
#define NHEADS 4

namespace {

typedef unsigned short u16;
typedef __attribute__((ext_vector_type(8))) short bf16x8;
typedef __attribute__((ext_vector_type(4))) float f32x4;

constexpr float SCALE = 0.07216878364870322f; // 1/sqrt(192)

__device__ inline u16 f2bf(float f) {
  unsigned u = __float_as_uint(f);
  unsigned r = (u + 0x7FFFu + ((u >> 16) & 1u)) >> 16;  // RNE
  return (u16)r;
}
__device__ inline float bf2f(u16 h) {
  return __uint_as_float((unsigned)h << 16);
}

__device__ inline void gload_lds16(const u16* g, u16* s) {
  __builtin_amdgcn_global_load_lds(
      (const __attribute__((address_space(1))) unsigned*)g,
      (__attribute__((address_space(3))) unsigned*)s, 16, 0, 0);
}

// ------------------------------------------------------------ bf16 MFMA GEMM
// A [M][K] bf16 row-major, Bt [N][K] bf16 row-major (B transposed).
// 128x128 tile, BK=32, 4 waves each computing 64x64 via 4x4 mfma 16x16x32.
// EPI 0: C[m][n]  (OUTBF: bf16 or f32)
// EPI 1: encoder: C[(n/768)*QLEN + m][n%768] = v + extra[m][n%768]   (f32)
// EPI 2: ques out: C[(m%QLEN)*3 + m/QLEN][n] = v                     (f32)
template <int EPI, int OUTBF>
__global__ __launch_bounds__(256) void gemm_bf16(
    const u16* __restrict__ A, int lda, long long sAz,
    const u16* __restrict__ Bt, int ldb, long long sBz,
    void* __restrict__ Cv, int ldc, long long sCz,
    const float* __restrict__ bias, const float* __restrict__ extra,
    int M, int N, int K)
{
  __shared__ __align__(16) u16 As[128 * 32];
  __shared__ __align__(16) u16 Bs[128 * 32];
  const int z = blockIdx.z;
  A += z * sAz;
  Bt += z * sBz;
  float* Cf = (float*)Cv + z * sCz;
  u16* Ch = (u16*)Cv + z * sCz;
  const int bm = blockIdx.y * 128, bn = blockIdx.x * 128;
  const int tid = threadIdx.x;
  const int w = tid >> 6, l = tid & 63;
  const int wr = w >> 1, wc = w & 1;
  const int l16 = l & 15, lk = l >> 4;
  const int srow = tid >> 2;
  const int scol = (tid & 3) * 8;

  int r0 = bm + srow;      if (r0 > M - 1) r0 = M - 1;
  int r1 = bm + srow + 64; if (r1 > M - 1) r1 = M - 1;
  int c0 = bn + srow;      if (c0 > N - 1) c0 = N - 1;
  int c1 = bn + srow + 64; if (c1 > N - 1) c1 = N - 1;
  const u16* pa0 = A + (long long)r0 * lda + scol;
  const u16* pa1 = A + (long long)r1 * lda + scol;
  const u16* pb0 = Bt + (long long)c0 * ldb + scol;
  const u16* pb1 = Bt + (long long)c1 * ldb + scol;
  u16* dA0 = As + w * 512;
  u16* dA1 = As + w * 512 + 2048;
  u16* dB0 = Bs + w * 512;
  u16* dB1 = Bs + w * 512 + 2048;

  f32x4 acc[4][4] = {};

  for (int k0 = 0; k0 < K; k0 += 32) {
    gload_lds16(pa0 + k0, dA0);
    gload_lds16(pa1 + k0, dA1);
    gload_lds16(pb0 + k0, dB0);
    gload_lds16(pb1 + k0, dB1);
    __syncthreads();
    bf16x8 af[4], bf[4];
#pragma unroll
    for (int m = 0; m < 4; ++m)
      af[m] = *(const bf16x8*)&As[(wr * 64 + m * 16 + l16) * 32 + lk * 8];
#pragma unroll
    for (int n = 0; n < 4; ++n)
      bf[n] = *(const bf16x8*)&Bs[(wc * 64 + n * 16 + l16) * 32 + lk * 8];
#pragma unroll
    for (int m = 0; m < 4; ++m)
#pragma unroll
      for (int n = 0; n < 4; ++n)
        acc[m][n] = __builtin_amdgcn_mfma_f32_16x16x32_bf16(af[m], bf[n], acc[m][n], 0, 0, 0);
    __syncthreads();
  }

#pragma unroll
  for (int m = 0; m < 4; ++m) {
#pragma unroll
    for (int j = 0; j < 4; ++j) {
      int grow = bm + wr * 64 + m * 16 + lk * 4 + j;
      if (grow >= M) continue;
#pragma unroll
      for (int n = 0; n < 4; ++n) {
        int gcol = bn + wc * 64 + n * 16 + l16;
        if (gcol >= N) continue;
        float val = acc[m][n][j] + (bias ? bias[gcol] : 0.f);
        if (EPI == 0) {
          if (OUTBF)
            Ch[(long long)grow * ldc + gcol] = f2bf(val);
          else
            Cf[(long long)grow * ldc + gcol] = val;
        } else if (EPI == 1) {
          int h = gcol / EMB, c = gcol - h * EMB;
          Cf[((long long)h * QLEN + grow) * EMB + c] = val + extra[(long long)grow * EMB + c];
        } else {
          int i2 = grow % QLEN, h = grow / QLEN;
          Cf[((long long)i2 * HNEED + h) * EMB + gcol] = val;
        }
      }
    }
  }
}

// ------------------------------------------------------ conversion / transpose
__global__ void f2bf_kernel(const float* __restrict__ in, u16* __restrict__ out, long long n)
{
  long long i = ((long long)blockIdx.x * 256 + threadIdx.x) * 4;
  if (i >= n) return;
  float4 v = *(const float4*)(in + i);
  ushort4 o;
  o.x = f2bf(v.x); o.y = f2bf(v.y); o.z = f2bf(v.z); o.w = f2bf(v.w);
  *(ushort4*)(out + i) = o;
}

// out[z][c][r] = bf16(in[z][r][c])
__global__ __launch_bounds__(256) void transpose_bf(
    const float* __restrict__ in, u16* __restrict__ out, int R, int C)
{
  __shared__ float t[32][33];
  const long long zoff = (long long)blockIdx.z * R * C;
  in += zoff;
  out += zoff;
  const int c0 = blockIdx.x * 32, r0 = blockIdx.y * 32;
  const int tx = threadIdx.x & 31, ty = threadIdx.x >> 5;  // 32 x 8
  for (int i = 0; i < 32; i += 8) {
    int r = r0 + ty + i, c = c0 + tx;
    t[ty + i][tx] = (r < R && c < C) ? in[(long long)r * C + c] : 0.f;
  }
  __syncthreads();
  for (int i = 0; i < 32; i += 8) {
    int c = c0 + ty + i, r = r0 + tx;
    if (c < C && r < R) out[(long long)c * R + r] = f2bf(t[tx][ty + i]);
  }
}

// --------------------------------------------- fused assign-softmax + centers
__global__ __launch_bounds__(256) void assign_center_kernel(
    float* __restrict__ qh, const float* __restrict__ Wc,
    const float* __restrict__ bc, const float* __restrict__ centers)
{
  const int row = blockIdx.x;
  const int tid = threadIdx.x;
  __shared__ float red[4][10];
  __shared__ float assign_s[10];
  float part[10] = {};
  for (int d = tid; d < EMB; d += 256) {
    float v = qh[(long long)row * EMB + d];
#pragma unroll
    for (int j = 0; j < 10; ++j) part[j] += v * Wc[d * 10 + j];
  }
#pragma unroll
  for (int j = 0; j < 10; ++j)
#pragma unroll
    for (int off = 32; off; off >>= 1) part[j] += __shfl_down(part[j], off);
  const int wave = tid >> 6, lane = tid & 63;
  if (lane == 0)
    for (int j = 0; j < 10; ++j) red[wave][j] = part[j];
  __syncthreads();
  if (tid == 0) {
    float lg[10], m = -1e30f, s = 0.f;
    for (int j = 0; j < 10; ++j) {
      lg[j] = red[0][j] + red[1][j] + red[2][j] + red[3][j] + bc[j];
      m = fmaxf(m, lg[j]);
    }
    for (int j = 0; j < 10; ++j) {
      float e = expf(lg[j] - m);
      assign_s[j] = e;
      s += e;
    }
    float inv = 1.f / s;
    for (int j = 0; j < 10; ++j) assign_s[j] *= inv;
  }
  __syncthreads();
  for (int c = tid; c < EMB; c += 256) {
    float a = 0.f;
#pragma unroll
    for (int j = 0; j < 10; ++j) a += assign_s[j] * centers[j * EMB + c];
    qh[(long long)row * EMB + c] += a;
  }
}

// ------------------------------------------------------------- CSR build
__global__ void hist_kernel(const int* __restrict__ dst, int* __restrict__ cnt, int E)
{
  int e = blockIdx.x * 256 + threadIdx.x;
  if (e < E) atomicAdd(&cnt[dst[e]], 1);
}

__global__ __launch_bounds__(1024) void scan_fill_kernel(
    const int* __restrict__ cnt, int* __restrict__ rowptr, int* __restrict__ cur, int n)
{
  __shared__ int buf[1024];
  const int tid = threadIdx.x;
  const int chunk = (n + 1023) >> 10;
  const int base = tid * chunk;
  int s = 0;
  for (int i = 0; i < chunk; ++i) {
    int idx = base + i;
    if (idx < n) s += cnt[idx];
  }
  buf[tid] = s;
  __syncthreads();
  for (int off = 1; off < 1024; off <<= 1) {
    int v = (tid >= off) ? buf[tid - off] : 0;
    __syncthreads();
    buf[tid] += v;
    __syncthreads();
  }
  int run = (tid == 0) ? 0 : buf[tid - 1];
  for (int i = 0; i < chunk; ++i) {
    int idx = base + i;
    if (idx < n) {
      rowptr[idx] = run;
      cur[idx] = run;
      run += cnt[idx];
    }
  }
  if (tid == 1023) rowptr[n] = buf[1023];
}

__global__ void fill_kernel(const int* __restrict__ src, const int* __restrict__ dst,
                            int* __restrict__ cur, int* __restrict__ adj, int E)
{
  int e = blockIdx.x * 256 + threadIdx.x;
  if (e < E) {
    int p = atomicAdd(&cur[dst[e]], 1);
    adj[p] = src[e];
  }
}

// ---------------------------- fused gather attention (online softmax, bf16 in)
// One wave per (dst, head). K/V rows loaded ONCE, reused by all NCOPY copies
// (give graph: 3 head-copies share adjacency; only q / output rows differ).
template <int NCOPY>
__global__ __launch_bounds__(256) void gather_attn(
    const u16* __restrict__ q, const u16* __restrict__ k,
    const u16* __restrict__ v, const int* __restrict__ rowptr,
    const int* __restrict__ adj, const float* __restrict__ rpri,
    float coef, float* __restrict__ out, int n_dst)
{
  const int w = (blockIdx.x * 256 + threadIdx.x) >> 6;
  const int lane = threadIdx.x & 63;
  if (w >= n_dst * NHEADS) return;
  const int h = w & 3;
  const int d = w >> 2;
  const int rs = rowptr[d], re = rowptr[d + 1];
  if (rs == re) return;  // no in-edges: rows keep residual
  float q0[NCOPY], q1[NCOPY], q2[NCOPY];
  float m[NCOPY], s[NCOPY], A0[NCOPY], A1[NCOPY], A2[NCOPY];
#pragma unroll
  for (int c = 0; c < NCOPY; ++c) {
    const u16* qr = q + (long long)(c * n_dst + d) * EMB + h * DKH;
    q0[c] = bf2f(qr[lane]);
    q1[c] = bf2f(qr[64 + lane]);
    q2[c] = bf2f(qr[128 + lane]);
    m[c] = -1e30f; s[c] = 0.f; A0[c] = 0.f; A1[c] = 0.f; A2[c] = 0.f;
  }
  const float pri = rpri[h] * SCALE;

  auto process = [&](float k0, float k1, float k2, float v0, float v1, float v2) {
#pragma unroll
    for (int c = 0; c < NCOPY; ++c) {
      float dot = q0[c] * k0 + q1[c] * k1 + q2[c] * k2;
#pragma unroll
      for (int off = 32; off; off >>= 1) dot += __shfl_xor(dot, off);
      const float score = dot * pri;
      const float nm = fmaxf(m[c], score);
      const float f = __expf(m[c] - nm);
      const float e = __expf(score - nm);
      s[c] = s[c] * f + e;
      A0[c] = A0[c] * f + e * v0;
      A1[c] = A1[c] * f + e * v1;
      A2[c] = A2[c] * f + e * v2;
      m[c] = nm;
    }
  };

  int i = rs;
  for (; i + 1 < re; i += 2) {
    const int s0 = adj[i], s1 = adj[i + 1];
    const u16* kr0 = k + (long long)s0 * EMB + h * DKH;
    const u16* vr0 = v + (long long)s0 * EMB + h * DKH;
    const u16* kr1 = k + (long long)s1 * EMB + h * DKH;
    const u16* vr1 = v + (long long)s1 * EMB + h * DKH;
    float ka = bf2f(kr0[lane]), kb = bf2f(kr0[64 + lane]), kc = bf2f(kr0[128 + lane]);
    float va = bf2f(vr0[lane]), vb = bf2f(vr0[64 + lane]), vc = bf2f(vr0[128 + lane]);
    float kd = bf2f(kr1[lane]), ke = bf2f(kr1[64 + lane]), kf = bf2f(kr1[128 + lane]);
    float vd = bf2f(vr1[lane]), ve = bf2f(vr1[64 + lane]), vf = bf2f(vr1[128 + lane]);
    process(ka, kb, kc, va, vb, vc);
    process(kd, ke, kf, vd, ve, vf);
  }
  if (i < re) {
    const int s0 = adj[i];
    const u16* kr0 = k + (long long)s0 * EMB + h * DKH;
    const u16* vr0 = v + (long long)s0 * EMB + h * DKH;
    process(bf2f(kr0[lane]), bf2f(kr0[64 + lane]), bf2f(kr0[128 + lane]),
            bf2f(vr0[lane]), bf2f(vr0[64 + lane]), bf2f(vr0[128 + lane]));
  }

#pragma unroll
  for (int c = 0; c < NCOPY; ++c) {
    const float inv = coef / s[c];
    float* orow = out + (long long)(c * n_dst + d) * EMB + h * DKH;
    orow[lane] += A0[c] * inv;
    orow[64 + lane] += A1[c] * inv;
    orow[128 + lane] += A2[c] * inv;
  }
}

}  // namespace

extern "C" void kernel_launch(void* const* d_in, const int* in_sizes, int n_in,
                              void* d_out, int out_size, void* d_ws, size_t ws_size,
                              hipStream_t stream)
{
  const float* q_emb   = (const float*)d_in[0];
  const float* t_emb   = (const float*)d_in[1];
  const int*   give_src = (const int*)d_in[2];
  const int*   give_dst = (const int*)d_in[3];
  const int*   i1_src  = (const int*)d_in[4];
  const int*   i1_dst  = (const int*)d_in[5];
  const int*   i2_src  = (const int*)d_in[6];
  const int*   i2_dst  = (const int*)d_in[7];
  const float* Wq_enc  = (const float*)d_in[8];
  const float* bq_enc  = (const float*)d_in[9];
  const float* Wc      = (const float*)d_in[10];
  const float* bc      = (const float*)d_in[11];
  const float* centers = (const float*)d_in[12];
  const float* kW      = (const float*)d_in[13];
  const float* kb      = (const float*)d_in[14];
  const float* qW      = (const float*)d_in[15];
  const float* qb      = (const float*)d_in[16];
  const float* vW      = (const float*)d_in[17];
  const float* vb      = (const float*)d_in[18];
  const float* rel_att = (const float*)d_in[19];
  const float* rel_msg = (const float*)d_in[20];
  const float* rel_pri = (const float*)d_in[21];
  const float* Wout    = (const float*)d_in[22];
  const float* bout    = (const float*)d_in[23];
  float* out = (float*)d_out;

  // -------- workspace carve-up
  float* p = (float*)d_ws;
  auto take = [&](size_t n) { float* r = p; p += ((n + 3) & ~(size_t)3); return r; };
  float* h_q   = take((size_t)NQ * EMB);
  float* h_tag = take((size_t)TLEN * EMB);
  u16* h_q_bf   = (u16*)take((size_t)NQ * EMB / 2);
  u16* h_tag_bf = (u16*)take((size_t)TLEN * EMB / 2);
  u16* k_tag_bf = (u16*)take((size_t)TLEN * EMB / 2);
  u16* v_tag_bf = (u16*)take((size_t)TLEN * EMB / 2);
  u16* q_tag_bf = (u16*)take((size_t)TLEN * EMB / 2);
  u16* k_rel    = (u16*)take((size_t)TLEN * EMB / 2);
  u16* v_rel    = (u16*)take((size_t)TLEN * EMB / 2);
  const long long WS = (long long)EMB * EMB;        // 589824
  const long long RS = (long long)DKH * DKH;        // 36864
  u16* WqT   = (u16*)take((size_t)EMB * EMB * HNEED / 2);
  u16* qWT   = (u16*)take((size_t)4 * WS / 2);
  u16* kWT   = (u16*)take((size_t)4 * WS / 2);
  u16* vWT   = (u16*)take((size_t)4 * WS / 2);
  u16* WoutT = (u16*)take((size_t)WS / 2);
  u16* rattT = (u16*)take((size_t)24 * RS / 2);
  u16* rmsgT = (u16*)take((size_t)24 * RS / 2);
  int* rp_g  = (int*)take(QLEN + 1);
  int* rp_1  = (int*)take(TLEN + 1);
  int* rp_2  = (int*)take(TLEN + 1);
  int* cur_g = (int*)take(QLEN);
  int* cur_1 = (int*)take(TLEN);
  int* cur_2 = (int*)take(TLEN);
  int* adj_g = (int*)take(EG);
  int* adj_1 = (int*)take(EI);
  int* adj_2 = (int*)take(EI);
  int* cnt   = (int*)take(QLEN);
  u16* q_emb_bf = h_q_bf;        // overlay: dead before h_q_bf first written
  u16* q_que = (u16*)out;        // d_out as scratch; fully overwritten at end

  auto gemmb = [&](int EPI, int OUTBF, const u16* A, int lda, long long sAz,
                   const u16* Bt, int ldb, long long sBz,
                   void* C, int ldc, long long sCz,
                   const float* bias, const float* extra,
                   int M, int N, int K, int batch) {
    dim3 grid((N + 127) / 128, (M + 127) / 128, batch);
    if (EPI == 0 && OUTBF == 0)
      gemm_bf16<0, 0><<<grid, 256, 0, stream>>>(A, lda, sAz, Bt, ldb, sBz, C, ldc, sCz, bias, extra, M, N, K);
    else if (EPI == 0 && OUTBF == 1)
      gemm_bf16<0, 1><<<grid, 256, 0, stream>>>(A, lda, sAz, Bt, ldb, sBz, C, ldc, sCz, bias, extra, M, N, K);
    else if (EPI == 1)
      gemm_bf16<1, 0><<<grid, 256, 0, stream>>>(A, lda, sAz, Bt, ldb, sBz, C, ldc, sCz, bias, extra, M, N, K);
    else
      gemm_bf16<2, 0><<<grid, 256, 0, stream>>>(A, lda, sAz, Bt, ldb, sBz, C, ldc, sCz, bias, extra, M, N, K);
  };
  auto f2bf_launch = [&](const float* in, u16* o, long long n) {
    f2bf_kernel<<<(unsigned)((n / 4 + 255) / 256), 256, 0, stream>>>(in, o, n);
  };

  // -------- CSR builds (static graphs)
  auto build_csr = [&](const int* src, const int* dst, int E, int n,
                       int* rp, int* cu, int* adj) {
    hipMemsetAsync(cnt, 0, (size_t)n * sizeof(int), stream);
    hist_kernel<<<(E + 255) / 256, 256, 0, stream>>>(dst, cnt, E);
    scan_fill_kernel<<<1, 1024, 0, stream>>>(cnt, rp, cu, n);
    fill_kernel<<<(E + 255) / 256, 256, 0, stream>>>(src, dst, cu, adj, E);
  };
  build_csr(give_src, give_dst, EG, QLEN, rp_g, cur_g, adj_g);
  build_csr(i1_src, i1_dst, EI, TLEN, rp_1, cur_1, adj_1);
  build_csr(i2_src, i2_dst, EI, TLEN, rp_2, cur_2, adj_2);

  // -------- one-time weight transposes (f32 [R][C] -> bf16 [C][R])
  transpose_bf<<<dim3(EMB * HNEED / 32, EMB / 32, 1), 256, 0, stream>>>(Wq_enc, WqT, EMB, EMB * HNEED);
  transpose_bf<<<dim3(EMB / 32, EMB / 32, 4), 256, 0, stream>>>(qW, qWT, EMB, EMB);
  transpose_bf<<<dim3(EMB / 32, EMB / 32, 4), 256, 0, stream>>>(kW, kWT, EMB, EMB);
  transpose_bf<<<dim3(EMB / 32, EMB / 32, 4), 256, 0, stream>>>(vW, vWT, EMB, EMB);
  transpose_bf<<<dim3(EMB / 32, EMB / 32, 1), 256, 0, stream>>>(Wout, WoutT, EMB, EMB);
  transpose_bf<<<dim3(DKH / 32, DKH / 32, 24), 256, 0, stream>>>(rel_att, rattT, DKH, DKH);
  transpose_bf<<<dim3(DKH / 32, DKH / 32, 24), 256, 0, stream>>>(rel_msg, rmsgT, DKH, DKH);

  // -------- question encoder
  f2bf_launch(q_emb, q_emb_bf, (long long)QLEN * EMB);
  gemmb(1, 0, q_emb_bf, EMB, 0, WqT, EMB, 0, h_q, EMB, 0, bq_enc, q_emb,
        QLEN, EMB * HNEED, EMB, 1);
  assign_center_kernel<<<NQ, 256, 0, stream>>>(h_q, Wc, bc, centers);
  hipMemcpyAsync(h_tag, t_emb, (size_t)TLEN * EMB * sizeof(float),
                 hipMemcpyDeviceToDevice, stream);

  auto run_rel = [&](const u16* qbuf, const int* rp, const int* adj, int ncopy,
                     int n_dst, const u16* rattTp, const u16* rmsgTp,
                     const float* rpri_p, float coef, float* outbuf) {
    gemmb(0, 1, k_tag_bf, EMB, DKH, rattTp, DKH, RS, k_rel, EMB, DKH,
          nullptr, nullptr, TLEN, DKH, DKH, NHEADS);
    gemmb(0, 1, v_tag_bf, EMB, DKH, rmsgTp, DKH, RS, v_rel, EMB, DKH,
          nullptr, nullptr, TLEN, DKH, DKH, NHEADS);
    int waves = n_dst * NHEADS;
    int blocks = (waves * 64 + 255) / 256;
    if (ncopy == 3)
      gather_attn<3><<<blocks, 256, 0, stream>>>(qbuf, k_rel, v_rel, rp, adj,
                                                 rpri_p, coef, outbuf, n_dst);
    else
      gather_attn<1><<<blocks, 256, 0, stream>>>(qbuf, k_rel, v_rel, rp, adj,
                                                 rpri_p, coef, outbuf, n_dst);
  };

  for (int l = 0; l < 2; ++l) {
    f2bf_launch(h_tag, h_tag_bf, (long long)TLEN * EMB);
    f2bf_launch(h_q, h_q_bf, (long long)NQ * EMB);
    gemmb(0, 1, h_tag_bf, EMB, 0, kWT + (l * 2 + 0) * WS, EMB, 0, k_tag_bf, EMB, 0,
          kb + (l * 2 + 0) * EMB, nullptr, TLEN, EMB, EMB, 1);
    gemmb(0, 1, h_tag_bf, EMB, 0, vWT + (l * 2 + 0) * WS, EMB, 0, v_tag_bf, EMB, 0,
          vb + (l * 2 + 0) * EMB, nullptr, TLEN, EMB, EMB, 1);
    gemmb(0, 1, h_tag_bf, EMB, 0, qWT + (l * 2 + 0) * WS, EMB, 0, q_tag_bf, EMB, 0,
          qb + (l * 2 + 0) * EMB, nullptr, TLEN, EMB, EMB, 1);
    gemmb(0, 1, h_q_bf, EMB, 0, qWT + (l * 2 + 1) * WS, EMB, 0, q_que, EMB, 0,
          qb + (l * 2 + 1) * EMB, nullptr, NQ, EMB, EMB, 1);

    run_rel(q_que, rp_g, adj_g, HNEED, QLEN,
            rattT + (l * 3 + 0) * 4 * RS, rmsgT + (l * 3 + 0) * 4 * RS,
            rel_pri + (l * 3 + 0) * NHEADS, 1.0f, h_q);
    run_rel(q_tag_bf, rp_1, adj_1, 1, TLEN,
            rattT + (l * 3 + 1) * 4 * RS, rmsgT + (l * 3 + 1) * 4 * RS,
            rel_pri + (l * 3 + 1) * NHEADS, 0.5f, h_tag);
    run_rel(q_tag_bf, rp_2, adj_2, 1, TLEN,
            rattT + (l * 3 + 2) * 4 * RS, rmsgT + (l * 3 + 2) * 4 * RS,
            rel_pri + (l * 3 + 2) * NHEADS, 0.5f, h_tag);
  }

  // -------- outputs
  f2bf_launch(h_q, h_q_bf, (long long)NQ * EMB);
  f2bf_launch(h_tag, h_tag_bf, (long long)TLEN * EMB);
  gemmb(2, 0, h_q_bf, EMB, 0, WoutT, EMB, 0, out, EMB, 0, bout, nullptr,
        NQ, EMB, EMB, 1);
  gemmb(0, 0, h_tag_bf, EMB, 0, WoutT, EMB, 0, out + (size_t)NQ * EMB, EMB, 0,
        bout, nullptr, TLEN, EMB, EMB, 1);
}

// Round 5
// 1123.649 us; speedup vs baseline: 5.8981x; 1.2737x over previous
//
#include <hip/hip_runtime.h>

#define QLEN 10000
#define TLEN 3000
#define EMB 768
#define HNEED 3
#define NQ (QLEN * HNEED)
#define EG 100000
#define EI 100000
#define DKH 192
#define NHEADS 4

namespace {

typedef unsigned short u16;
typedef __attribute__((ext_vector_type(8))) short bf16x8;
typedef __attribute__((ext_vector_type(4))) float f32x4;

constexpr float SCALE = 0.07216878364870322f; // 1/sqrt(192)

__device__ inline u16 f2bf(float f) {
  unsigned u = __float_as_uint(f);
  unsigned r = (u + 0x7FFFu + ((u >> 16) & 1u)) >> 16;  // RNE
  return (u16)r;
}
__device__ inline float bf2f(u16 h) {
  return __uint_as_float((unsigned)h << 16);
}

__device__ inline void gload_lds16(const u16* g, u16* s) {
  __builtin_amdgcn_global_load_lds(
      (const __attribute__((address_space(1))) unsigned*)g,
      (__attribute__((address_space(3))) unsigned*)s, 16, 0, 0);
}

// ------------------------------------------------------------ bf16 MFMA GEMM
// A [M][K] bf16 row-major, Bt [N][K] bf16 row-major (B transposed).
// 128x128 tile, BK=32, 4 waves each computing 64x64 via 4x4 mfma 16x16x32.
// EPI 0: C[m][n]  (OUTBF: bf16 or f32)
// EPI 1: encoder: C[(n/768)*QLEN + m][n%768] = v + extra[m][n%768]   (f32)
// EPI 2: ques out: C[(m%QLEN)*3 + m/QLEN][n] = v                     (f32)
template <int EPI, int OUTBF>
__global__ __launch_bounds__(256) void gemm_bf16(
    const u16* __restrict__ A, int lda, long long sAz,
    const u16* __restrict__ Bt, int ldb, long long sBz,
    void* __restrict__ Cv, int ldc, long long sCz,
    const float* __restrict__ bias, const float* __restrict__ extra,
    int M, int N, int K)
{
  __shared__ __align__(16) u16 As[128 * 32];
  __shared__ __align__(16) u16 Bs[128 * 32];
  const int z = blockIdx.z;
  A += z * sAz;
  Bt += z * sBz;
  float* Cf = (float*)Cv + z * sCz;
  u16* Ch = (u16*)Cv + z * sCz;
  const int bm = blockIdx.y * 128, bn = blockIdx.x * 128;
  const int tid = threadIdx.x;
  const int w = tid >> 6, l = tid & 63;
  const int wr = w >> 1, wc = w & 1;
  const int l16 = l & 15, lk = l >> 4;
  const int srow = tid >> 2;
  const int scol = (tid & 3) * 8;

  int r0 = bm + srow;      if (r0 > M - 1) r0 = M - 1;
  int r1 = bm + srow + 64; if (r1 > M - 1) r1 = M - 1;
  int c0 = bn + srow;      if (c0 > N - 1) c0 = N - 1;
  int c1 = bn + srow + 64; if (c1 > N - 1) c1 = N - 1;
  const u16* pa0 = A + (long long)r0 * lda + scol;
  const u16* pa1 = A + (long long)r1 * lda + scol;
  const u16* pb0 = Bt + (long long)c0 * ldb + scol;
  const u16* pb1 = Bt + (long long)c1 * ldb + scol;
  u16* dA0 = As + w * 512;
  u16* dA1 = As + w * 512 + 2048;
  u16* dB0 = Bs + w * 512;
  u16* dB1 = Bs + w * 512 + 2048;

  f32x4 acc[4][4] = {};

  for (int k0 = 0; k0 < K; k0 += 32) {
    gload_lds16(pa0 + k0, dA0);
    gload_lds16(pa1 + k0, dA1);
    gload_lds16(pb0 + k0, dB0);
    gload_lds16(pb1 + k0, dB1);
    __syncthreads();
    bf16x8 af[4], bf[4];
#pragma unroll
    for (int m = 0; m < 4; ++m)
      af[m] = *(const bf16x8*)&As[(wr * 64 + m * 16 + l16) * 32 + lk * 8];
#pragma unroll
    for (int n = 0; n < 4; ++n)
      bf[n] = *(const bf16x8*)&Bs[(wc * 64 + n * 16 + l16) * 32 + lk * 8];
#pragma unroll
    for (int m = 0; m < 4; ++m)
#pragma unroll
      for (int n = 0; n < 4; ++n)
        acc[m][n] = __builtin_amdgcn_mfma_f32_16x16x32_bf16(af[m], bf[n], acc[m][n], 0, 0, 0);
    __syncthreads();
  }

#pragma unroll
  for (int m = 0; m < 4; ++m) {
#pragma unroll
    for (int j = 0; j < 4; ++j) {
      int grow = bm + wr * 64 + m * 16 + lk * 4 + j;
      if (grow >= M) continue;
#pragma unroll
      for (int n = 0; n < 4; ++n) {
        int gcol = bn + wc * 64 + n * 16 + l16;
        if (gcol >= N) continue;
        float val = acc[m][n][j] + (bias ? bias[gcol] : 0.f);
        if (EPI == 0) {
          if (OUTBF)
            Ch[(long long)grow * ldc + gcol] = f2bf(val);
          else
            Cf[(long long)grow * ldc + gcol] = val;
        } else if (EPI == 1) {
          int h = gcol / EMB, c = gcol - h * EMB;
          Cf[((long long)h * QLEN + grow) * EMB + c] = val + extra[(long long)grow * EMB + c];
        } else {
          int i2 = grow % QLEN, h = grow / QLEN;
          Cf[((long long)i2 * HNEED + h) * EMB + gcol] = val;
        }
      }
    }
  }
}

// ------------------------------------------------------ conversion / transpose
__global__ void f2bf_kernel(const float* __restrict__ in, u16* __restrict__ out, long long n)
{
  long long i = ((long long)blockIdx.x * 256 + threadIdx.x) * 4;
  if (i >= n) return;
  float4 v = *(const float4*)(in + i);
  ushort4 o;
  o.x = f2bf(v.x); o.y = f2bf(v.y); o.z = f2bf(v.z); o.w = f2bf(v.w);
  *(ushort4*)(out + i) = o;
}

__global__ void copy_cast_kernel(const float* __restrict__ in, float* __restrict__ of,
                                 u16* __restrict__ ob, long long n)
{
  long long i = ((long long)blockIdx.x * 256 + threadIdx.x) * 4;
  if (i >= n) return;
  float4 v = *(const float4*)(in + i);
  *(float4*)(of + i) = v;
  ushort4 o;
  o.x = f2bf(v.x); o.y = f2bf(v.y); o.z = f2bf(v.z); o.w = f2bf(v.w);
  *(ushort4*)(ob + i) = o;
}

// out z-slot = (z/G)*OG + z%G ; out[slot][c][r] = bf16(in[z][r][c])
__global__ __launch_bounds__(256) void transpose_bf(
    const float* __restrict__ in, u16* __restrict__ out, int R, int C, int G, int OG)
{
  __shared__ float t[32][33];
  const int z = blockIdx.z;
  in += (long long)z * R * C;
  out += (long long)((z / G) * OG + (z % G)) * R * C;
  const int c0 = blockIdx.x * 32, r0 = blockIdx.y * 32;
  const int tx = threadIdx.x & 31, ty = threadIdx.x >> 5;  // 32 x 8
  for (int i = 0; i < 32; i += 8) {
    int r = r0 + ty + i, c = c0 + tx;
    t[ty + i][tx] = (r < R && c < C) ? in[(long long)r * C + c] : 0.f;
  }
  __syncthreads();
  for (int i = 0; i < 32; i += 8) {
    int c = c0 + ty + i, r = r0 + tx;
    if (c < C && r < R) out[(long long)c * R + r] = f2bf(t[tx][ty + i]);
  }
}

// ---------------------------------------------------- small packing kernels
__global__ void pack_wct_kernel(const float* __restrict__ Wc, float* __restrict__ WcT)
{
  int idx = blockIdx.x * 256 + threadIdx.x;
  if (idx >= 7680) return;
  int j = idx / EMB, d = idx - j * EMB;
  WcT[idx] = Wc[d * 10 + j];
}

__global__ void pack_bias_kernel(const float* __restrict__ kb, const float* __restrict__ vb,
                                 const float* __restrict__ qb, float* __restrict__ o)
{
  int idx = blockIdx.x * 256 + threadIdx.x;
  if (idx >= 2 * 2304) return;
  int l = idx / 2304, c = idx - l * 2304;
  float v;
  if (c < 768) v = kb[(l * 2) * EMB + c];
  else if (c < 1536) v = vb[(l * 2) * EMB + c - 768];
  else v = qb[(l * 2) * EMB + c - 1536];
  o[idx] = v;
}

// --------------------------------------------- fused assign-softmax + centers
// 512 threads = 8 waves, one wave per row; Wc^T + centers staged in LDS.
// Writes f32 result AND bf16 mirror.
__global__ __launch_bounds__(512) void assign_center512(
    float* __restrict__ qh, u16* __restrict__ qh_bf,
    const float* __restrict__ WcT, const float* __restrict__ bc,
    const float* __restrict__ centers)
{
  __shared__ float wc_s[7680];
  __shared__ float cen_s[7680];
  const int tid = threadIdx.x;
  for (int i = tid; i < 7680; i += 512) {
    wc_s[i] = WcT[i];
    cen_s[i] = centers[i];
  }
  __syncthreads();
  const int wave = tid >> 6, lane = tid & 63;
  const int row = blockIdx.x * 8 + wave;   // NQ = 30000 = 3750*8 exact
  const long long base = (long long)row * EMB;
  float x[12];
#pragma unroll
  for (int i = 0; i < 12; ++i) x[i] = qh[base + lane + 64 * i];
  float part[10] = {};
#pragma unroll
  for (int i = 0; i < 12; ++i) {
    const float v = x[i];
    const int d = lane + 64 * i;
#pragma unroll
    for (int j = 0; j < 10; ++j) part[j] = fmaf(v, wc_s[j * EMB + d], part[j]);
  }
#pragma unroll
  for (int j = 0; j < 10; ++j)
#pragma unroll
    for (int off = 32; off; off >>= 1) part[j] += __shfl_xor(part[j], off);
  float mx = -1e30f;
#pragma unroll
  for (int j = 0; j < 10; ++j) { part[j] += bc[j]; mx = fmaxf(mx, part[j]); }
  float s = 0.f;
#pragma unroll
  for (int j = 0; j < 10; ++j) { part[j] = __expf(part[j] - mx); s += part[j]; }
  const float inv = 1.f / s;
#pragma unroll
  for (int i = 0; i < 12; ++i) {
    const int d = lane + 64 * i;
    float acc = 0.f;
#pragma unroll
    for (int j = 0; j < 10; ++j) acc = fmaf(part[j], cen_s[j * EMB + d], acc);
    const float val = x[i] + acc * inv;
    qh[base + d] = val;
    qh_bf[base + d] = f2bf(val);
  }
}

// ------------------------------------------------------------- CSR build
__global__ void hist_kernel(const int* __restrict__ dst, int* __restrict__ cnt, int E)
{
  int e = blockIdx.x * 256 + threadIdx.x;
  if (e < E) atomicAdd(&cnt[dst[e]], 1);
}

__global__ __launch_bounds__(1024) void scan_fill_kernel(
    const int* __restrict__ cnt, int* __restrict__ rowptr, int* __restrict__ cur, int n)
{
  __shared__ int buf[1024];
  const int tid = threadIdx.x;
  const int chunk = (n + 1023) >> 10;
  const int base = tid * chunk;
  int s = 0;
  for (int i = 0; i < chunk; ++i) {
    int idx = base + i;
    if (idx < n) s += cnt[idx];
  }
  buf[tid] = s;
  __syncthreads();
  for (int off = 1; off < 1024; off <<= 1) {
    int v = (tid >= off) ? buf[tid - off] : 0;
    __syncthreads();
    buf[tid] += v;
    __syncthreads();
  }
  int run = (tid == 0) ? 0 : buf[tid - 1];
  for (int i = 0; i < chunk; ++i) {
    int idx = base + i;
    if (idx < n) {
      rowptr[idx] = run;
      cur[idx] = run;
      run += cnt[idx];
    }
  }
  if (tid == 1023) rowptr[n] = buf[1023];
}

__global__ void fill_kernel(const int* __restrict__ src, const int* __restrict__ dst,
                            int* __restrict__ cur, int* __restrict__ adj, int E)
{
  int e = blockIdx.x * 256 + threadIdx.x;
  if (e < E) {
    int p = atomicAdd(&cur[dst[e]], 1);
    adj[p] = src[e];
  }
}

// ---------------------------- give gather (3 head-copies share K/V + adjacency)
// kv layout: row sn*1536, k at h*192, v at 768 + h*192 (bf16).
__global__ __launch_bounds__(256) void gather_give(
    const u16* __restrict__ q, const u16* __restrict__ kv,
    const int* __restrict__ rowptr, const int* __restrict__ adj,
    const float* __restrict__ rpri,
    float* __restrict__ out, u16* __restrict__ out_bf)
{
  const int w = (blockIdx.x * 256 + threadIdx.x) >> 6;
  const int lane = threadIdx.x & 63;
  if (w >= QLEN * NHEADS) return;
  const int h = w & 3;
  const int d = w >> 2;
  const int rs = rowptr[d], re = rowptr[d + 1];
  if (rs == re) return;  // no in-edges: rows keep residual (bf16 already current)
  float q0[3], q1[3], q2[3];
  float m[3], s[3], A0[3], A1[3], A2[3];
#pragma unroll
  for (int c = 0; c < 3; ++c) {
    const u16* qr = q + (long long)(c * QLEN + d) * EMB + h * DKH;
    q0[c] = bf2f(qr[lane]);
    q1[c] = bf2f(qr[64 + lane]);
    q2[c] = bf2f(qr[128 + lane]);
    m[c] = -1e30f; s[c] = 0.f; A0[c] = 0.f; A1[c] = 0.f; A2[c] = 0.f;
  }
  const float pri = rpri[h] * SCALE;

  auto process = [&](float k0, float k1, float k2, float v0, float v1, float v2) {
#pragma unroll
    for (int c = 0; c < 3; ++c) {
      float dot = q0[c] * k0 + q1[c] * k1 + q2[c] * k2;
#pragma unroll
      for (int off = 32; off; off >>= 1) dot += __shfl_xor(dot, off);
      const float score = dot * pri;
      const float nm = fmaxf(m[c], score);
      const float f = __expf(m[c] - nm);
      const float e = __expf(score - nm);
      s[c] = s[c] * f + e;
      A0[c] = A0[c] * f + e * v0;
      A1[c] = A1[c] * f + e * v1;
      A2[c] = A2[c] * f + e * v2;
      m[c] = nm;
    }
  };

  int i = rs;
  for (; i + 1 < re; i += 2) {
    const u16* kr0 = kv + (long long)adj[i] * 1536 + h * DKH;
    const u16* kr1 = kv + (long long)adj[i + 1] * 1536 + h * DKH;
    float ka = bf2f(kr0[lane]), kb = bf2f(kr0[64 + lane]), kc = bf2f(kr0[128 + lane]);
    float va = bf2f(kr0[768 + lane]), vb = bf2f(kr0[832 + lane]), vc = bf2f(kr0[896 + lane]);
    float kd = bf2f(kr1[lane]), ke = bf2f(kr1[64 + lane]), kf = bf2f(kr1[128 + lane]);
    float vd = bf2f(kr1[768 + lane]), ve = bf2f(kr1[832 + lane]), vf = bf2f(kr1[896 + lane]);
    process(ka, kb, kc, va, vb, vc);
    process(kd, ke, kf, vd, ve, vf);
  }
  if (i < re) {
    const u16* kr0 = kv + (long long)adj[i] * 1536 + h * DKH;
    process(bf2f(kr0[lane]), bf2f(kr0[64 + lane]), bf2f(kr0[128 + lane]),
            bf2f(kr0[768 + lane]), bf2f(kr0[832 + lane]), bf2f(kr0[896 + lane]));
  }

#pragma unroll
  for (int c = 0; c < 3; ++c) {
    const float inv = 1.f / s[c];
    float* orow = out + (long long)(c * QLEN + d) * EMB + h * DKH;
    u16* obf = out_bf + (long long)(c * QLEN + d) * EMB + h * DKH;
    float v0 = orow[lane] + A0[c] * inv;
    float v1 = orow[64 + lane] + A1[c] * inv;
    float v2 = orow[128 + lane] + A2[c] * inv;
    orow[lane] = v0; orow[64 + lane] = v1; orow[128 + lane] = v2;
    obf[lane] = f2bf(v0); obf[64 + lane] = f2bf(v1); obf[128 + lane] = f2bf(v2);
  }
}

// ------------------- merged inter gather: both tag->tag relations, single RMW
__global__ __launch_bounds__(256) void gather_inter(
    const u16* __restrict__ tag_kvq,   // q at col 1536
    const u16* __restrict__ kv1, const u16* __restrict__ kv2,
    const int* __restrict__ rp1, const int* __restrict__ adj1,
    const int* __restrict__ rp2, const int* __restrict__ adj2,
    const float* __restrict__ pri1, const float* __restrict__ pri2,
    float* __restrict__ out, u16* __restrict__ out_bf)
{
  const int w = (blockIdx.x * 256 + threadIdx.x) >> 6;
  const int lane = threadIdx.x & 63;
  if (w >= TLEN * NHEADS) return;
  const int h = w & 3;
  const int d = w >> 2;
  const int rs1 = rp1[d], re1 = rp1[d + 1];
  const int rs2 = rp2[d], re2 = rp2[d + 1];
  if (rs1 == re1 && rs2 == re2) return;
  const u16* qr = tag_kvq + (long long)d * 2304 + 1536 + h * DKH;
  const float q0 = bf2f(qr[lane]), q1 = bf2f(qr[64 + lane]), q2 = bf2f(qr[128 + lane]);
  float R0 = 0.f, R1 = 0.f, R2 = 0.f;
#pragma unroll
  for (int rel = 0; rel < 2; ++rel) {
    const u16* kv = rel ? kv2 : kv1;
    const int rs = rel ? rs2 : rs1, re = rel ? re2 : re1;
    const int* adj = rel ? adj2 : adj1;
    if (rs == re) continue;
    const float pri = (rel ? pri2[h] : pri1[h]) * SCALE;
    float m = -1e30f, s = 0.f, A0 = 0.f, A1 = 0.f, A2 = 0.f;
    auto process = [&](float k0, float k1, float k2, float v0, float v1, float v2) {
      float dot = q0 * k0 + q1 * k1 + q2 * k2;
#pragma unroll
      for (int off = 32; off; off >>= 1) dot += __shfl_xor(dot, off);
      const float score = dot * pri;
      const float nm = fmaxf(m, score);
      const float f = __expf(m - nm);
      const float e = __expf(score - nm);
      s = s * f + e;
      A0 = A0 * f + e * v0;
      A1 = A1 * f + e * v1;
      A2 = A2 * f + e * v2;
      m = nm;
    };
    int i = rs;
    for (; i + 1 < re; i += 2) {
      const u16* kr0 = kv + (long long)adj[i] * 1536 + h * DKH;
      const u16* kr1 = kv + (long long)adj[i + 1] * 1536 + h * DKH;
      float ka = bf2f(kr0[lane]), kb = bf2f(kr0[64 + lane]), kc = bf2f(kr0[128 + lane]);
      float va = bf2f(kr0[768 + lane]), vb = bf2f(kr0[832 + lane]), vc = bf2f(kr0[896 + lane]);
      float kd = bf2f(kr1[lane]), ke = bf2f(kr1[64 + lane]), kf = bf2f(kr1[128 + lane]);
      float vd = bf2f(kr1[768 + lane]), ve = bf2f(kr1[832 + lane]), vf = bf2f(kr1[896 + lane]);
      process(ka, kb, kc, va, vb, vc);
      process(kd, ke, kf, vd, ve, vf);
    }
    if (i < re) {
      const u16* kr0 = kv + (long long)adj[i] * 1536 + h * DKH;
      process(bf2f(kr0[lane]), bf2f(kr0[64 + lane]), bf2f(kr0[128 + lane]),
              bf2f(kr0[768 + lane]), bf2f(kr0[832 + lane]), bf2f(kr0[896 + lane]));
    }
    const float inv = 0.5f / s;
    R0 += A0 * inv; R1 += A1 * inv; R2 += A2 * inv;
  }
  float* orow = out + (long long)d * EMB + h * DKH;
  u16* obf = out_bf + (long long)d * EMB + h * DKH;
  float v0 = orow[lane] + R0;
  float v1 = orow[64 + lane] + R1;
  float v2 = orow[128 + lane] + R2;
  orow[lane] = v0; orow[64 + lane] = v1; orow[128 + lane] = v2;
  obf[lane] = f2bf(v0); obf[64 + lane] = f2bf(v1); obf[128 + lane] = f2bf(v2);
}

}  // namespace

extern "C" void kernel_launch(void* const* d_in, const int* in_sizes, int n_in,
                              void* d_out, int out_size, void* d_ws, size_t ws_size,
                              hipStream_t stream)
{
  const float* q_emb   = (const float*)d_in[0];
  const float* t_emb   = (const float*)d_in[1];
  const int*   give_src = (const int*)d_in[2];
  const int*   give_dst = (const int*)d_in[3];
  const int*   i1_src  = (const int*)d_in[4];
  const int*   i1_dst  = (const int*)d_in[5];
  const int*   i2_src  = (const int*)d_in[6];
  const int*   i2_dst  = (const int*)d_in[7];
  const float* Wq_enc  = (const float*)d_in[8];
  const float* bq_enc  = (const float*)d_in[9];
  const float* Wc      = (const float*)d_in[10];
  const float* bc      = (const float*)d_in[11];
  const float* centers = (const float*)d_in[12];
  const float* kW      = (const float*)d_in[13];
  const float* kb      = (const float*)d_in[14];
  const float* qW      = (const float*)d_in[15];
  const float* qb      = (const float*)d_in[16];
  const float* vW      = (const float*)d_in[17];
  const float* vb      = (const float*)d_in[18];
  const float* rel_att = (const float*)d_in[19];
  const float* rel_msg = (const float*)d_in[20];
  const float* rel_pri = (const float*)d_in[21];
  const float* Wout    = (const float*)d_in[22];
  const float* bout    = (const float*)d_in[23];
  float* out = (float*)d_out;

  const long long WS = (long long)EMB * EMB;   // 589824
  const long long RS = (long long)DKH * DKH;   // 36864

  // -------- workspace carve-up
  float* p = (float*)d_ws;
  auto take = [&](size_t n) { float* r = p; p += ((n + 3) & ~(size_t)3); return r; };
  float* h_q     = take((size_t)NQ * EMB);
  float* h_tag   = take((size_t)TLEN * EMB);
  u16* h_q_bf    = (u16*)take((size_t)NQ * EMB / 2);
  u16* h_tag_bf  = (u16*)take((size_t)TLEN * EMB / 2);
  u16* tag_kvq   = (u16*)take((size_t)TLEN * 2304 / 2);
  u16* kv_g      = (u16*)take((size_t)TLEN * 1536 / 2);
  u16* kv_1      = (u16*)take((size_t)TLEN * 1536 / 2);
  u16* kv_2      = (u16*)take((size_t)TLEN * 1536 / 2);
  u16* WqT   = (u16*)take((size_t)EMB * EMB * HNEED / 2);
  u16* qWT   = (u16*)take((size_t)4 * WS / 2);
  u16* Wtag  = (u16*)take((size_t)2 * 3 * WS / 2);   // [l][2304][768]
  u16* WoutT = (u16*)take((size_t)WS / 2);
  u16* relWT = (u16*)take((size_t)48 * RS / 2);      // [l*3+r][8][192][192] (k4,v4)
  float* WcT   = take(7680);
  float* b_kvq = take(2 * 2304);
  int* rp_g  = (int*)take(QLEN + 1);
  int* rp_1  = (int*)take(TLEN + 1);
  int* rp_2  = (int*)take(TLEN + 1);
  int* cur_g = (int*)take(QLEN);
  int* cur_1 = (int*)take(TLEN);
  int* cur_2 = (int*)take(TLEN);
  int* adj_g = (int*)take(EG);
  int* adj_1 = (int*)take(EI);
  int* adj_2 = (int*)take(EI);
  int* cnt   = (int*)take(QLEN);
  u16* q_emb_bf = h_q_bf;        // overlay: dead before h_q_bf first written
  u16* q_que = (u16*)out;        // d_out as scratch; fully overwritten at end

  auto gemmb = [&](int EPI, int OUTBF, const u16* A, int lda, long long sAz,
                   const u16* Bt, int ldb, long long sBz,
                   void* C, int ldc, long long sCz,
                   const float* bias, const float* extra,
                   int M, int N, int K, int batch) {
    dim3 grid((N + 127) / 128, (M + 127) / 128, batch);
    if (EPI == 0 && OUTBF == 0)
      gemm_bf16<0, 0><<<grid, 256, 0, stream>>>(A, lda, sAz, Bt, ldb, sBz, C, ldc, sCz, bias, extra, M, N, K);
    else if (EPI == 0 && OUTBF == 1)
      gemm_bf16<0, 1><<<grid, 256, 0, stream>>>(A, lda, sAz, Bt, ldb, sBz, C, ldc, sCz, bias, extra, M, N, K);
    else if (EPI == 1)
      gemm_bf16<1, 0><<<grid, 256, 0, stream>>>(A, lda, sAz, Bt, ldb, sBz, C, ldc, sCz, bias, extra, M, N, K);
    else
      gemm_bf16<2, 0><<<grid, 256, 0, stream>>>(A, lda, sAz, Bt, ldb, sBz, C, ldc, sCz, bias, extra, M, N, K);
  };

  // -------- CSR builds (static graphs)
  auto build_csr = [&](const int* src, const int* dst, int E, int n,
                       int* rp, int* cu, int* adj) {
    hipMemsetAsync(cnt, 0, (size_t)n * sizeof(int), stream);
    hist_kernel<<<(E + 255) / 256, 256, 0, stream>>>(dst, cnt, E);
    scan_fill_kernel<<<1, 1024, 0, stream>>>(cnt, rp, cu, n);
    fill_kernel<<<(E + 255) / 256, 256, 0, stream>>>(src, dst, cu, adj, E);
  };
  build_csr(give_src, give_dst, EG, QLEN, rp_g, cur_g, adj_g);
  build_csr(i1_src, i1_dst, EI, TLEN, rp_1, cur_1, adj_1);
  build_csr(i2_src, i2_dst, EI, TLEN, rp_2, cur_2, adj_2);

  // -------- one-time packs / transposes
  pack_wct_kernel<<<30, 256, 0, stream>>>(Wc, WcT);
  pack_bias_kernel<<<18, 256, 0, stream>>>(kb, vb, qb, b_kvq);
  transpose_bf<<<dim3(EMB * HNEED / 32, EMB / 32, 1), 256, 0, stream>>>(Wq_enc, WqT, EMB, EMB * HNEED, 1, 1);
  transpose_bf<<<dim3(EMB / 32, EMB / 32, 4), 256, 0, stream>>>(qW, qWT, EMB, EMB, 1, 1);
  // fused tag weight [l][2304][768]: rows 0-767 k, 768-1535 v, 1536-2303 q  (slot l*2+0 of each)
  for (int l = 0; l < 2; ++l) {
    transpose_bf<<<dim3(EMB / 32, EMB / 32, 1), 256, 0, stream>>>(kW + (l * 2) * WS, Wtag + (l * 3 + 0) * WS, EMB, EMB, 1, 1);
    transpose_bf<<<dim3(EMB / 32, EMB / 32, 1), 256, 0, stream>>>(vW + (l * 2) * WS, Wtag + (l * 3 + 1) * WS, EMB, EMB, 1, 1);
    transpose_bf<<<dim3(EMB / 32, EMB / 32, 1), 256, 0, stream>>>(qW + (l * 2) * WS, Wtag + (l * 3 + 2) * WS, EMB, EMB, 1, 1);
  }
  transpose_bf<<<dim3(EMB / 32, EMB / 32, 1), 256, 0, stream>>>(Wout, WoutT, EMB, EMB, 1, 1);
  // relWT: z = lr*4+h -> slot lr*8 + h (ratt) / lr*8 + 4 + h (rmsg)
  transpose_bf<<<dim3(DKH / 32, DKH / 32, 24), 256, 0, stream>>>(rel_att, relWT, DKH, DKH, 4, 8);
  transpose_bf<<<dim3(DKH / 32, DKH / 32, 24), 256, 0, stream>>>(rel_msg, relWT + 4 * RS, DKH, DKH, 4, 8);

  // -------- question encoder + clustering
  f2bf_kernel<<<(QLEN * EMB / 4 + 255) / 256, 256, 0, stream>>>(q_emb, q_emb_bf, (long long)QLEN * EMB);
  gemmb(1, 0, q_emb_bf, EMB, 0, WqT, EMB, 0, h_q, EMB, 0, bq_enc, q_emb,
        QLEN, EMB * HNEED, EMB, 1);
  assign_center512<<<NQ / 8, 512, 0, stream>>>(h_q, h_q_bf, WcT, bc, centers);
  copy_cast_kernel<<<(TLEN * EMB / 4 + 255) / 256, 256, 0, stream>>>(t_emb, h_tag, h_tag_bf, (long long)TLEN * EMB);

  for (int l = 0; l < 2; ++l) {
    // fused K|V|Q tag projection: [3000][2304] bf16
    gemmb(0, 1, h_tag_bf, EMB, 0, Wtag + (long long)l * 3 * WS, EMB, 0,
          tag_kvq, 2304, 0, b_kvq + l * 2304, nullptr, TLEN, 2304, EMB, 1);
    // question Q projection
    gemmb(0, 1, h_q_bf, EMB, 0, qWT + (l * 2 + 1) * WS, EMB, 0,
          q_que, EMB, 0, qb + (l * 2 + 1) * EMB, nullptr, NQ, EMB, EMB, 1);
    // relation K/V transforms, batched z=8 (4 k-heads then 4 v-heads)
    gemmb(0, 1, tag_kvq, 2304, 192, relWT + (long long)(l * 3 + 0) * 8 * RS, DKH, RS,
          kv_g, 1536, 192, nullptr, nullptr, TLEN, DKH, DKH, 8);
    gemmb(0, 1, tag_kvq, 2304, 192, relWT + (long long)(l * 3 + 1) * 8 * RS, DKH, RS,
          kv_1, 1536, 192, nullptr, nullptr, TLEN, DKH, DKH, 8);
    gemmb(0, 1, tag_kvq, 2304, 192, relWT + (long long)(l * 3 + 2) * 8 * RS, DKH, RS,
          kv_2, 1536, 192, nullptr, nullptr, TLEN, DKH, DKH, 8);
    // gathers (write f32 + bf16 mirrors)
    gather_give<<<QLEN * NHEADS / 4, 256, 0, stream>>>(
        q_que, kv_g, rp_g, adj_g, rel_pri + (l * 3 + 0) * NHEADS, h_q, h_q_bf);
    gather_inter<<<TLEN * NHEADS / 4, 256, 0, stream>>>(
        tag_kvq, kv_1, kv_2, rp_1, adj_1, rp_2, adj_2,
        rel_pri + (l * 3 + 1) * NHEADS, rel_pri + (l * 3 + 2) * NHEADS,
        h_tag, h_tag_bf);
  }

  // -------- outputs
  gemmb(2, 0, h_q_bf, EMB, 0, WoutT, EMB, 0, out, EMB, 0, bout, nullptr,
        NQ, EMB, EMB, 1);
  gemmb(0, 0, h_tag_bf, EMB, 0, WoutT, EMB, 0, out + (size_t)NQ * EMB, EMB, 0,
        bout, nullptr, TLEN, EMB, EMB, 1);
}

// Round 6
// 1075.065 us; speedup vs baseline: 6.1646x; 1.0452x over previous
//
#include <hip/hip_runtime.h>

#define QLEN 10000
#define TLEN 3000
#define EMB 768
#define HNEED 3
#define NQ (QLEN * HNEED)
#define EG 100000
#define EI 100000
#define DKH 192
#define NHEADS 4

namespace {

typedef unsigned short u16;
typedef __attribute__((ext_vector_type(8))) short bf16x8;
typedef __attribute__((ext_vector_type(4))) float f32x4;

constexpr float SCALE = 0.07216878364870322f; // 1/sqrt(192)

__device__ inline u16 f2bf(float f) {
  unsigned u = __float_as_uint(f);
  unsigned r = (u + 0x7FFFu + ((u >> 16) & 1u)) >> 16;  // RNE
  return (u16)r;
}
__device__ inline float bf2f(u16 h) {
  return __uint_as_float((unsigned)h << 16);
}

__device__ inline void gload_lds16(const u16* g, u16* s) {
  __builtin_amdgcn_global_load_lds(
      (const __attribute__((address_space(1))) unsigned*)g,
      (__attribute__((address_space(3))) unsigned*)s, 16, 0, 0);
}

// ------------------------------------------------------------ bf16 MFMA GEMM
// A [M][K] bf16 row-major, Bt [N][K] bf16 row-major (B transposed).
// 128x128 tile, BK=32, 4 waves each computing 64x64 via 4x4 mfma 16x16x32.
// LDS k-chunk swizzle: chunk' = chunk ^ ((row>>1)&3)  (pre-swizzled global
// source + matching XOR on ds_read; LDS itself stays linear for gload_lds).
// EPI 0: C[m][n]  (OUTBF: bf16 or f32)
// EPI 1: encoder: C_bf[(n/768)*QLEN + m][n%768] = bf16(v + extra[m][n%768])
// EPI 2: ques out: C[(m%QLEN)*3 + m/QLEN][n] = v                     (f32)
template <int EPI, int OUTBF>
__global__ __launch_bounds__(256) void gemm_bf16(
    const u16* __restrict__ A, int lda, long long sAz,
    const u16* __restrict__ Bt, int ldb, long long sBz,
    void* __restrict__ Cv, int ldc, long long sCz,
    const float* __restrict__ bias, const float* __restrict__ extra,
    int M, int N, int K)
{
  __shared__ __align__(16) u16 As[128 * 32];
  __shared__ __align__(16) u16 Bs[128 * 32];
  const int z = blockIdx.z;
  A += z * sAz;
  Bt += z * sBz;
  float* Cf = (float*)Cv + z * sCz;
  u16* Ch = (u16*)Cv + z * sCz;
  const int bm = blockIdx.y * 128, bn = blockIdx.x * 128;
  const int tid = threadIdx.x;
  const int w = tid >> 6, l = tid & 63;
  const int wr = w >> 1, wc = w & 1;
  const int l16 = l & 15, lk = l >> 4;
  const int srow = tid >> 2;
  // swizzled global k-chunk so that LDS[row][chunk] holds global chunk^f(row)
  const int scol = (((tid & 3) ^ ((srow >> 1) & 3))) * 8;
  const int rchunk = (lk ^ ((l16 >> 1) & 3));  // read-side inverse (same XOR)

  int r0 = bm + srow;      if (r0 > M - 1) r0 = M - 1;
  int r1 = bm + srow + 64; if (r1 > M - 1) r1 = M - 1;
  int c0 = bn + srow;      if (c0 > N - 1) c0 = N - 1;
  int c1 = bn + srow + 64; if (c1 > N - 1) c1 = N - 1;
  const u16* pa0 = A + (long long)r0 * lda + scol;
  const u16* pa1 = A + (long long)r1 * lda + scol;
  const u16* pb0 = Bt + (long long)c0 * ldb + scol;
  const u16* pb1 = Bt + (long long)c1 * ldb + scol;
  u16* dA0 = As + w * 512;
  u16* dA1 = As + w * 512 + 2048;
  u16* dB0 = Bs + w * 512;
  u16* dB1 = Bs + w * 512 + 2048;

  f32x4 acc[4][4] = {};

  for (int k0 = 0; k0 < K; k0 += 32) {
    gload_lds16(pa0 + k0, dA0);
    gload_lds16(pa1 + k0, dA1);
    gload_lds16(pb0 + k0, dB0);
    gload_lds16(pb1 + k0, dB1);
    __syncthreads();
    bf16x8 af[4], bf[4];
#pragma unroll
    for (int m = 0; m < 4; ++m)
      af[m] = *(const bf16x8*)&As[(wr * 64 + m * 16 + l16) * 32 + rchunk * 8];
#pragma unroll
    for (int n = 0; n < 4; ++n)
      bf[n] = *(const bf16x8*)&Bs[(wc * 64 + n * 16 + l16) * 32 + rchunk * 8];
#pragma unroll
    for (int m = 0; m < 4; ++m)
#pragma unroll
      for (int n = 0; n < 4; ++n)
        acc[m][n] = __builtin_amdgcn_mfma_f32_16x16x32_bf16(af[m], bf[n], acc[m][n], 0, 0, 0);
    __syncthreads();
  }

#pragma unroll
  for (int m = 0; m < 4; ++m) {
#pragma unroll
    for (int j = 0; j < 4; ++j) {
      int grow = bm + wr * 64 + m * 16 + lk * 4 + j;
      if (grow >= M) continue;
#pragma unroll
      for (int n = 0; n < 4; ++n) {
        int gcol = bn + wc * 64 + n * 16 + l16;
        if (gcol >= N) continue;
        float val = acc[m][n][j] + (bias ? bias[gcol] : 0.f);
        if (EPI == 0) {
          if (OUTBF)
            Ch[(long long)grow * ldc + gcol] = f2bf(val);
          else
            Cf[(long long)grow * ldc + gcol] = val;
        } else if (EPI == 1) {
          int h = gcol / EMB, c = gcol - h * EMB;
          Ch[((long long)h * QLEN + grow) * EMB + c] =
              f2bf(val + extra[(long long)grow * EMB + c]);
        } else {
          int i2 = grow % QLEN, h = grow / QLEN;
          Cf[((long long)i2 * HNEED + h) * EMB + gcol] = val;
        }
      }
    }
  }
}

// ------------------------------------------------------ conversion / transpose
__global__ void f2bf_kernel(const float* __restrict__ in, u16* __restrict__ out, long long n)
{
  long long i = ((long long)blockIdx.x * 256 + threadIdx.x) * 4;
  if (i >= n) return;
  float4 v = *(const float4*)(in + i);
  ushort4 o;
  o.x = f2bf(v.x); o.y = f2bf(v.y); o.z = f2bf(v.z); o.w = f2bf(v.w);
  *(ushort4*)(out + i) = o;
}

// out z-slot = (z/G)*OG + z%G ; out[slot][c][r] = bf16(in[z][r][c])
__global__ __launch_bounds__(256) void transpose_bf(
    const float* __restrict__ in, u16* __restrict__ out, int R, int C, int G, int OG)
{
  __shared__ float t[32][33];
  const int z = blockIdx.z;
  in += (long long)z * R * C;
  out += (long long)((z / G) * OG + (z % G)) * R * C;
  const int c0 = blockIdx.x * 32, r0 = blockIdx.y * 32;
  const int tx = threadIdx.x & 31, ty = threadIdx.x >> 5;  // 32 x 8
  for (int i = 0; i < 32; i += 8) {
    int r = r0 + ty + i, c = c0 + tx;
    t[ty + i][tx] = (r < R && c < C) ? in[(long long)r * C + c] : 0.f;
  }
  __syncthreads();
  for (int i = 0; i < 32; i += 8) {
    int c = c0 + ty + i, r = r0 + tx;
    if (c < C && r < R) out[(long long)c * R + r] = f2bf(t[tx][ty + i]);
  }
}

// ---------------------------------------------------- small packing kernels
__global__ void pack_wct_kernel(const float* __restrict__ Wc, float* __restrict__ WcT)
{
  int idx = blockIdx.x * 256 + threadIdx.x;
  if (idx >= 7680) return;
  int j = idx / EMB, d = idx - j * EMB;
  WcT[idx] = Wc[d * 10 + j];
}

__global__ void pack_bias_kernel(const float* __restrict__ kb, const float* __restrict__ vb,
                                 const float* __restrict__ qb, float* __restrict__ o)
{
  int idx = blockIdx.x * 256 + threadIdx.x;
  if (idx >= 2 * 2304) return;
  int l = idx / 2304, c = idx - l * 2304;
  float v;
  if (c < 768) v = kb[(l * 2) * EMB + c];
  else if (c < 1536) v = vb[(l * 2) * EMB + c - 768];
  else v = qb[(l * 2) * EMB + c - 1536];
  o[idx] = v;
}

// --------------------------------------------- fused assign-softmax + centers
// 512 threads = 8 waves, one wave per row; Wc^T + centers staged in LDS.
// bf16 in / bf16 out (h_q state is bf16-only).
__global__ __launch_bounds__(512) void assign_center512(
    u16* __restrict__ qh_bf,
    const float* __restrict__ WcT, const float* __restrict__ bc,
    const float* __restrict__ centers)
{
  __shared__ float wc_s[7680];
  __shared__ float cen_s[7680];
  const int tid = threadIdx.x;
  for (int i = tid; i < 7680; i += 512) {
    wc_s[i] = WcT[i];
    cen_s[i] = centers[i];
  }
  __syncthreads();
  const int wave = tid >> 6, lane = tid & 63;
  const int row = blockIdx.x * 8 + wave;   // NQ = 30000 = 3750*8 exact
  const long long base = (long long)row * EMB;
  float x[12];
#pragma unroll
  for (int i = 0; i < 12; ++i) x[i] = bf2f(qh_bf[base + lane + 64 * i]);
  float part[10] = {};
#pragma unroll
  for (int i = 0; i < 12; ++i) {
    const float v = x[i];
    const int d = lane + 64 * i;
#pragma unroll
    for (int j = 0; j < 10; ++j) part[j] = fmaf(v, wc_s[j * EMB + d], part[j]);
  }
#pragma unroll
  for (int j = 0; j < 10; ++j)
#pragma unroll
    for (int off = 32; off; off >>= 1) part[j] += __shfl_xor(part[j], off);
  float mx = -1e30f;
#pragma unroll
  for (int j = 0; j < 10; ++j) { part[j] += bc[j]; mx = fmaxf(mx, part[j]); }
  float s = 0.f;
#pragma unroll
  for (int j = 0; j < 10; ++j) { part[j] = __expf(part[j] - mx); s += part[j]; }
  const float inv = 1.f / s;
#pragma unroll
  for (int i = 0; i < 12; ++i) {
    const int d = lane + 64 * i;
    float acc = 0.f;
#pragma unroll
    for (int j = 0; j < 10; ++j) acc = fmaf(part[j], cen_s[j * EMB + d], acc);
    qh_bf[base + d] = f2bf(x[i] + acc * inv);
  }
}

// ------------------------------------------------------------- CSR build
__global__ void hist_kernel(const int* __restrict__ dst, int* __restrict__ cnt, int E)
{
  int e = blockIdx.x * 256 + threadIdx.x;
  if (e < E) atomicAdd(&cnt[dst[e]], 1);
}

__global__ __launch_bounds__(1024) void scan_fill_kernel(
    const int* __restrict__ cnt, int* __restrict__ rowptr, int* __restrict__ cur, int n)
{
  __shared__ int buf[1024];
  const int tid = threadIdx.x;
  const int chunk = (n + 1023) >> 10;
  const int base = tid * chunk;
  int s = 0;
  for (int i = 0; i < chunk; ++i) {
    int idx = base + i;
    if (idx < n) s += cnt[idx];
  }
  buf[tid] = s;
  __syncthreads();
  for (int off = 1; off < 1024; off <<= 1) {
    int v = (tid >= off) ? buf[tid - off] : 0;
    __syncthreads();
    buf[tid] += v;
    __syncthreads();
  }
  int run = (tid == 0) ? 0 : buf[tid - 1];
  for (int i = 0; i < chunk; ++i) {
    int idx = base + i;
    if (idx < n) {
      rowptr[idx] = run;
      cur[idx] = run;
      run += cnt[idx];
    }
  }
  if (tid == 1023) rowptr[n] = buf[1023];
}

__global__ void fill_kernel(const int* __restrict__ src, const int* __restrict__ dst,
                            int* __restrict__ cur, int* __restrict__ adj, int E)
{
  int e = blockIdx.x * 256 + threadIdx.x;
  if (e < E) {
    int p = atomicAdd(&cur[dst[e]], 1);
    adj[p] = src[e];
  }
}

// ---------------------------- give gather (3 head-copies share K/V + adjacency)
// kv layout: row sn*1536, k at h*192, v at 768 + h*192 (bf16).
// Scores are O(1) -> plain exp accumulation (no running-max) is exact enough.
// h_q state is bf16: single bf16 RMW per row segment.
__global__ __launch_bounds__(256) void gather_give(
    const u16* __restrict__ q, const u16* __restrict__ kv,
    const int* __restrict__ rowptr, const int* __restrict__ adj,
    const float* __restrict__ rpri, u16* __restrict__ hq_bf)
{
  const int w = (blockIdx.x * 256 + threadIdx.x) >> 6;
  const int lane = threadIdx.x & 63;
  if (w >= QLEN * NHEADS) return;
  const int h = w & 3;
  const int d = w >> 2;
  const int rs = rowptr[d], re = rowptr[d + 1];
  if (rs == re) return;  // no in-edges: rows keep residual
  const float pri = rpri[h] * SCALE;
  float q0[3], q1[3], q2[3];
  float s[3], A0[3], A1[3], A2[3];
#pragma unroll
  for (int c = 0; c < 3; ++c) {
    const u16* qr = q + (long long)(c * QLEN + d) * EMB + h * DKH;
    q0[c] = bf2f(qr[lane]) * pri;
    q1[c] = bf2f(qr[64 + lane]) * pri;
    q2[c] = bf2f(qr[128 + lane]) * pri;
    s[c] = 0.f; A0[c] = 0.f; A1[c] = 0.f; A2[c] = 0.f;
  }

  auto process = [&](float k0, float k1, float k2, float v0, float v1, float v2) {
#pragma unroll
    for (int c = 0; c < 3; ++c) {
      float dot = q0[c] * k0 + q1[c] * k1 + q2[c] * k2;
#pragma unroll
      for (int off = 32; off; off >>= 1) dot += __shfl_xor(dot, off);
      const float e = __expf(dot);
      s[c] += e;
      A0[c] = fmaf(e, v0, A0[c]);
      A1[c] = fmaf(e, v1, A1[c]);
      A2[c] = fmaf(e, v2, A2[c]);
    }
  };

  int i = rs;
  for (; i + 1 < re; i += 2) {
    const u16* kr0 = kv + (long long)adj[i] * 1536 + h * DKH;
    const u16* kr1 = kv + (long long)adj[i + 1] * 1536 + h * DKH;
    float ka = bf2f(kr0[lane]), kb = bf2f(kr0[64 + lane]), kc = bf2f(kr0[128 + lane]);
    float va = bf2f(kr0[768 + lane]), vb = bf2f(kr0[832 + lane]), vc = bf2f(kr0[896 + lane]);
    float kd = bf2f(kr1[lane]), ke = bf2f(kr1[64 + lane]), kf = bf2f(kr1[128 + lane]);
    float vd = bf2f(kr1[768 + lane]), ve = bf2f(kr1[832 + lane]), vf = bf2f(kr1[896 + lane]);
    process(ka, kb, kc, va, vb, vc);
    process(kd, ke, kf, vd, ve, vf);
  }
  if (i < re) {
    const u16* kr0 = kv + (long long)adj[i] * 1536 + h * DKH;
    process(bf2f(kr0[lane]), bf2f(kr0[64 + lane]), bf2f(kr0[128 + lane]),
            bf2f(kr0[768 + lane]), bf2f(kr0[832 + lane]), bf2f(kr0[896 + lane]));
  }

#pragma unroll
  for (int c = 0; c < 3; ++c) {
    const float inv = 1.f / s[c];
    u16* orow = hq_bf + (long long)(c * QLEN + d) * EMB + h * DKH;
    orow[lane]       = f2bf(bf2f(orow[lane])       + A0[c] * inv);
    orow[64 + lane]  = f2bf(bf2f(orow[64 + lane])  + A1[c] * inv);
    orow[128 + lane] = f2bf(bf2f(orow[128 + lane]) + A2[c] * inv);
  }
}

// ------------------- merged inter gather: both tag->tag relations, single RMW
__global__ __launch_bounds__(256) void gather_inter(
    const u16* __restrict__ tag_kvq,   // q at col 1536
    const u16* __restrict__ kv1, const u16* __restrict__ kv2,
    const int* __restrict__ rp1, const int* __restrict__ adj1,
    const int* __restrict__ rp2, const int* __restrict__ adj2,
    const float* __restrict__ pri1, const float* __restrict__ pri2,
    u16* __restrict__ htag_bf)
{
  const int w = (blockIdx.x * 256 + threadIdx.x) >> 6;
  const int lane = threadIdx.x & 63;
  if (w >= TLEN * NHEADS) return;
  const int h = w & 3;
  const int d = w >> 2;
  const int rs1 = rp1[d], re1 = rp1[d + 1];
  const int rs2 = rp2[d], re2 = rp2[d + 1];
  if (rs1 == re1 && rs2 == re2) return;
  const u16* qr = tag_kvq + (long long)d * 2304 + 1536 + h * DKH;
  const float q0 = bf2f(qr[lane]), q1 = bf2f(qr[64 + lane]), q2 = bf2f(qr[128 + lane]);
  float R0 = 0.f, R1 = 0.f, R2 = 0.f;
#pragma unroll
  for (int rel = 0; rel < 2; ++rel) {
    const u16* kv = rel ? kv2 : kv1;
    const int rs = rel ? rs2 : rs1, re = rel ? re2 : re1;
    const int* adj = rel ? adj2 : adj1;
    if (rs == re) continue;
    const float pri = (rel ? pri2[h] : pri1[h]) * SCALE;
    float s = 0.f, A0 = 0.f, A1 = 0.f, A2 = 0.f;
    auto process = [&](float k0, float k1, float k2, float v0, float v1, float v2) {
      float dot = q0 * k0 + q1 * k1 + q2 * k2;
#pragma unroll
      for (int off = 32; off; off >>= 1) dot += __shfl_xor(dot, off);
      const float e = __expf(dot * pri);
      s += e;
      A0 = fmaf(e, v0, A0);
      A1 = fmaf(e, v1, A1);
      A2 = fmaf(e, v2, A2);
    };
    int i = rs;
    for (; i + 1 < re; i += 2) {
      const u16* kr0 = kv + (long long)adj[i] * 1536 + h * DKH;
      const u16* kr1 = kv + (long long)adj[i + 1] * 1536 + h * DKH;
      float ka = bf2f(kr0[lane]), kb = bf2f(kr0[64 + lane]), kc = bf2f(kr0[128 + lane]);
      float va = bf2f(kr0[768 + lane]), vb = bf2f(kr0[832 + lane]), vc = bf2f(kr0[896 + lane]);
      float kd = bf2f(kr1[lane]), ke = bf2f(kr1[64 + lane]), kf = bf2f(kr1[128 + lane]);
      float vd = bf2f(kr1[768 + lane]), ve = bf2f(kr1[832 + lane]), vf = bf2f(kr1[896 + lane]);
      process(ka, kb, kc, va, vb, vc);
      process(kd, ke, kf, vd, ve, vf);
    }
    if (i < re) {
      const u16* kr0 = kv + (long long)adj[i] * 1536 + h * DKH;
      process(bf2f(kr0[lane]), bf2f(kr0[64 + lane]), bf2f(kr0[128 + lane]),
              bf2f(kr0[768 + lane]), bf2f(kr0[832 + lane]), bf2f(kr0[896 + lane]));
    }
    const float inv = 0.5f / s;
    R0 = fmaf(A0, inv, R0); R1 = fmaf(A1, inv, R1); R2 = fmaf(A2, inv, R2);
  }
  u16* orow = htag_bf + (long long)d * EMB + h * DKH;
  orow[lane]       = f2bf(bf2f(orow[lane])       + R0);
  orow[64 + lane]  = f2bf(bf2f(orow[64 + lane])  + R1);
  orow[128 + lane] = f2bf(bf2f(orow[128 + lane]) + R2);
}

}  // namespace

extern "C" void kernel_launch(void* const* d_in, const int* in_sizes, int n_in,
                              void* d_out, int out_size, void* d_ws, size_t ws_size,
                              hipStream_t stream)
{
  const float* q_emb   = (const float*)d_in[0];
  const float* t_emb   = (const float*)d_in[1];
  const int*   give_src = (const int*)d_in[2];
  const int*   give_dst = (const int*)d_in[3];
  const int*   i1_src  = (const int*)d_in[4];
  const int*   i1_dst  = (const int*)d_in[5];
  const int*   i2_src  = (const int*)d_in[6];
  const int*   i2_dst  = (const int*)d_in[7];
  const float* Wq_enc  = (const float*)d_in[8];
  const float* bq_enc  = (const float*)d_in[9];
  const float* Wc      = (const float*)d_in[10];
  const float* bc      = (const float*)d_in[11];
  const float* centers = (const float*)d_in[12];
  const float* kW      = (const float*)d_in[13];
  const float* kb      = (const float*)d_in[14];
  const float* qW      = (const float*)d_in[15];
  const float* qb      = (const float*)d_in[16];
  const float* vW      = (const float*)d_in[17];
  const float* vb      = (const float*)d_in[18];
  const float* rel_att = (const float*)d_in[19];
  const float* rel_msg = (const float*)d_in[20];
  const float* rel_pri = (const float*)d_in[21];
  const float* Wout    = (const float*)d_in[22];
  const float* bout    = (const float*)d_in[23];
  float* out = (float*)d_out;

  const long long WS = (long long)EMB * EMB;   // 589824
  const long long RS = (long long)DKH * DKH;   // 36864

  // -------- workspace carve-up (bf16-only node state)
  float* p = (float*)d_ws;
  auto take = [&](size_t n) { float* r = p; p += ((n + 3) & ~(size_t)3); return r; };
  u16* h_q_bf    = (u16*)take((size_t)NQ * EMB / 2);
  u16* h_tag_bf  = (u16*)take((size_t)TLEN * EMB / 2);
  u16* q_emb_bf  = (u16*)take((size_t)QLEN * EMB / 2);
  u16* tag_kvq   = (u16*)take((size_t)TLEN * 2304 / 2);
  u16* kv_g      = (u16*)take((size_t)TLEN * 1536 / 2);
  u16* kv_1      = (u16*)take((size_t)TLEN * 1536 / 2);
  u16* kv_2      = (u16*)take((size_t)TLEN * 1536 / 2);
  u16* WqT   = (u16*)take((size_t)EMB * EMB * HNEED / 2);
  u16* qWT   = (u16*)take((size_t)4 * WS / 2);
  u16* Wtag  = (u16*)take((size_t)2 * 3 * WS / 2);   // [l][2304][768]
  u16* WoutT = (u16*)take((size_t)WS / 2);
  u16* relWT = (u16*)take((size_t)48 * RS / 2);      // [l*3+r][8][192][192] (k4,v4)
  float* WcT   = take(7680);
  float* b_kvq = take(2 * 2304);
  int* rp_g  = (int*)take(QLEN + 1);
  int* rp_1  = (int*)take(TLEN + 1);
  int* rp_2  = (int*)take(TLEN + 1);
  int* cur_g = (int*)take(QLEN);
  int* cur_1 = (int*)take(TLEN);
  int* cur_2 = (int*)take(TLEN);
  int* adj_g = (int*)take(EG);
  int* adj_1 = (int*)take(EI);
  int* adj_2 = (int*)take(EI);
  int* cnt   = (int*)take(QLEN);
  u16* q_que = (u16*)out;        // d_out as scratch; fully overwritten at end

  auto gemmb = [&](int EPI, int OUTBF, const u16* A, int lda, long long sAz,
                   const u16* Bt, int ldb, long long sBz,
                   void* C, int ldc, long long sCz,
                   const float* bias, const float* extra,
                   int M, int N, int K, int batch) {
    dim3 grid((N + 127) / 128, (M + 127) / 128, batch);
    if (EPI == 0 && OUTBF == 0)
      gemm_bf16<0, 0><<<grid, 256, 0, stream>>>(A, lda, sAz, Bt, ldb, sBz, C, ldc, sCz, bias, extra, M, N, K);
    else if (EPI == 0 && OUTBF == 1)
      gemm_bf16<0, 1><<<grid, 256, 0, stream>>>(A, lda, sAz, Bt, ldb, sBz, C, ldc, sCz, bias, extra, M, N, K);
    else if (EPI == 1)
      gemm_bf16<1, 1><<<grid, 256, 0, stream>>>(A, lda, sAz, Bt, ldb, sBz, C, ldc, sCz, bias, extra, M, N, K);
    else
      gemm_bf16<2, 0><<<grid, 256, 0, stream>>>(A, lda, sAz, Bt, ldb, sBz, C, ldc, sCz, bias, extra, M, N, K);
  };

  // -------- CSR builds (static graphs)
  auto build_csr = [&](const int* src, const int* dst, int E, int n,
                       int* rp, int* cu, int* adj) {
    hipMemsetAsync(cnt, 0, (size_t)n * sizeof(int), stream);
    hist_kernel<<<(E + 255) / 256, 256, 0, stream>>>(dst, cnt, E);
    scan_fill_kernel<<<1, 1024, 0, stream>>>(cnt, rp, cu, n);
    fill_kernel<<<(E + 255) / 256, 256, 0, stream>>>(src, dst, cu, adj, E);
  };
  build_csr(give_src, give_dst, EG, QLEN, rp_g, cur_g, adj_g);
  build_csr(i1_src, i1_dst, EI, TLEN, rp_1, cur_1, adj_1);
  build_csr(i2_src, i2_dst, EI, TLEN, rp_2, cur_2, adj_2);

  // -------- one-time packs / transposes
  pack_wct_kernel<<<30, 256, 0, stream>>>(Wc, WcT);
  pack_bias_kernel<<<18, 256, 0, stream>>>(kb, vb, qb, b_kvq);
  transpose_bf<<<dim3(EMB * HNEED / 32, EMB / 32, 1), 256, 0, stream>>>(Wq_enc, WqT, EMB, EMB * HNEED, 1, 1);
  transpose_bf<<<dim3(EMB / 32, EMB / 32, 4), 256, 0, stream>>>(qW, qWT, EMB, EMB, 1, 1);
  // fused tag weight [l][2304][768]: rows 0-767 k, 768-1535 v, 1536-2303 q  (slot l*2+0 of each)
  for (int l = 0; l < 2; ++l) {
    transpose_bf<<<dim3(EMB / 32, EMB / 32, 1), 256, 0, stream>>>(kW + (l * 2) * WS, Wtag + (l * 3 + 0) * WS, EMB, EMB, 1, 1);
    transpose_bf<<<dim3(EMB / 32, EMB / 32, 1), 256, 0, stream>>>(vW + (l * 2) * WS, Wtag + (l * 3 + 1) * WS, EMB, EMB, 1, 1);
    transpose_bf<<<dim3(EMB / 32, EMB / 32, 1), 256, 0, stream>>>(qW + (l * 2) * WS, Wtag + (l * 3 + 2) * WS, EMB, EMB, 1, 1);
  }
  transpose_bf<<<dim3(EMB / 32, EMB / 32, 1), 256, 0, stream>>>(Wout, WoutT, EMB, EMB, 1, 1);
  // relWT: z = lr*4+h -> slot lr*8 + h (ratt) / lr*8 + 4 + h (rmsg)
  transpose_bf<<<dim3(DKH / 32, DKH / 32, 24), 256, 0, stream>>>(rel_att, relWT, DKH, DKH, 4, 8);
  transpose_bf<<<dim3(DKH / 32, DKH / 32, 24), 256, 0, stream>>>(rel_msg, relWT + 4 * RS, DKH, DKH, 4, 8);

  // -------- question encoder + clustering (h_q_bf = bf16 state)
  f2bf_kernel<<<(QLEN * EMB / 4 + 255) / 256, 256, 0, stream>>>(q_emb, q_emb_bf, (long long)QLEN * EMB);
  gemmb(1, 1, q_emb_bf, EMB, 0, WqT, EMB, 0, h_q_bf, EMB, 0, bq_enc, q_emb,
        QLEN, EMB * HNEED, EMB, 1);
  assign_center512<<<NQ / 8, 512, 0, stream>>>(h_q_bf, WcT, bc, centers);
  f2bf_kernel<<<(TLEN * EMB / 4 + 255) / 256, 256, 0, stream>>>(t_emb, h_tag_bf, (long long)TLEN * EMB);

  for (int l = 0; l < 2; ++l) {
    // fused K|V|Q tag projection: [3000][2304] bf16
    gemmb(0, 1, h_tag_bf, EMB, 0, Wtag + (long long)l * 3 * WS, EMB, 0,
          tag_kvq, 2304, 0, b_kvq + l * 2304, nullptr, TLEN, 2304, EMB, 1);
    // question Q projection
    gemmb(0, 1, h_q_bf, EMB, 0, qWT + (l * 2 + 1) * WS, EMB, 0,
          q_que, EMB, 0, qb + (l * 2 + 1) * EMB, nullptr, NQ, EMB, EMB, 1);
    // relation K/V transforms, batched z=8 (4 k-heads then 4 v-heads)
    gemmb(0, 1, tag_kvq, 2304, 192, relWT + (long long)(l * 3 + 0) * 8 * RS, DKH, RS,
          kv_g, 1536, 192, nullptr, nullptr, TLEN, DKH, DKH, 8);
    gemmb(0, 1, tag_kvq, 2304, 192, relWT + (long long)(l * 3 + 1) * 8 * RS, DKH, RS,
          kv_1, 1536, 192, nullptr, nullptr, TLEN, DKH, DKH, 8);
    gemmb(0, 1, tag_kvq, 2304, 192, relWT + (long long)(l * 3 + 2) * 8 * RS, DKH, RS,
          kv_2, 1536, 192, nullptr, nullptr, TLEN, DKH, DKH, 8);
    // gathers (bf16 RMW into node state)
    gather_give<<<QLEN * NHEADS / 4, 256, 0, stream>>>(
        q_que, kv_g, rp_g, adj_g, rel_pri + (l * 3 + 0) * NHEADS, h_q_bf);
    gather_inter<<<TLEN * NHEADS / 4, 256, 0, stream>>>(
        tag_kvq, kv_1, kv_2, rp_1, adj_1, rp_2, adj_2,
        rel_pri + (l * 3 + 1) * NHEADS, rel_pri + (l * 3 + 2) * NHEADS,
        h_tag_bf);
  }

  // -------- outputs
  gemmb(2, 0, h_q_bf, EMB, 0, WoutT, EMB, 0, out, EMB, 0, bout, nullptr,
        NQ, EMB, EMB, 1);
  gemmb(0, 0, h_tag_bf, EMB, 0, WoutT, EMB, 0, out + (size_t)NQ * EMB, EMB, 0,
        bout, nullptr, TLEN, EMB, EMB, 1);
}

// Round 7
// 987.755 us; speedup vs baseline: 6.7095x; 1.0884x over previous
//
#include <hip/hip_runtime.h>

#define QLEN 10000
#define TLEN 3000
#define EMB 768
#define HNEED 3
#define NQ (QLEN * HNEED)
#define EG 100000
#define EI 100000
#define DKH 192
#define NHEADS 4

namespace {

typedef unsigned short u16;
typedef __attribute__((ext_vector_type(8))) short bf16x8;
typedef __attribute__((ext_vector_type(4))) float f32x4;

constexpr float SCALE = 0.07216878364870322f; // 1/sqrt(192)

__device__ inline u16 f2bf(float f) {
  unsigned u = __float_as_uint(f);
  unsigned r = (u + 0x7FFFu + ((u >> 16) & 1u)) >> 16;  // RNE
  return (u16)r;
}
__device__ inline float bf2f(u16 h) {
  return __uint_as_float((unsigned)h << 16);
}

__device__ inline void gload_lds16(const u16* g, u16* s) {
  __builtin_amdgcn_global_load_lds(
      (const __attribute__((address_space(1))) unsigned*)g,
      (__attribute__((address_space(3))) unsigned*)s, 16, 0, 0);
}

// ------------------------------------------------------------ bf16 MFMA GEMM
// A [M][K] bf16 row-major, Bt [N][K] bf16 row-major (B transposed).
// 128x128 tile, BK=32, 4 waves x 4x4 mfma 16x16x32.
// 2-phase double-buffered LDS: stage(t+1) issued BEFORE compute(t); one
// barrier per iter (compiler drains vmcnt(0) at the barrier).
// XCD-chunked bijective blockIdx swizzle (m204) for A-panel L2 locality.
// LDS k-chunk swizzle: chunk' = chunk ^ ((row>>1)&3) (bank-conflict-free).
// relpack: z=24 batch for relation transforms; A by z%8, C by z/8 and z%8.
// EPI 0: C[m][n] (OUTBF: bf16 or f32)
// EPI 1: encoder: C_bf[(n/768)*QLEN + m][n%768] = bf16(v + extra[m][n%768])
// EPI 2: ques out: C[(m%QLEN)*3 + m/QLEN][n] = v (f32)
template <int EPI, int OUTBF>
__global__ __launch_bounds__(256) void gemm_bf16(
    const u16* __restrict__ A, int lda, long long sAz,
    const u16* __restrict__ Bt, int ldb, long long sBz,
    void* __restrict__ Cv, int ldc, long long sCz, long long sCz2, int relpack,
    const float* __restrict__ bias, const float* __restrict__ extra,
    int M, int N, int K)
{
  __shared__ __align__(16) u16 As[2][4096];
  __shared__ __align__(16) u16 Bs[2][4096];
  const int z = blockIdx.z;
  float* Cf = (float*)Cv;
  u16* Ch = (u16*)Cv;
  if (relpack) {
    const int zr = z >> 3, zh = z & 7;
    A += (long long)zh * sAz;
    Bt += (long long)z * sBz;
    Cf += (long long)zr * sCz2 + (long long)zh * sCz;
    Ch += (long long)zr * sCz2 + (long long)zh * sCz;
  } else {
    A += (long long)z * sAz;
    Bt += (long long)z * sBz;
    Cf += (long long)z * sCz;
    Ch += (long long)z * sCz;
  }
  // ---- XCD-chunked bijective remap (orig%8 = XCD under round-robin dispatch)
  const int gx = gridDim.x;
  const int nwg = gx * gridDim.y;
  const int orig = blockIdx.y * gx + blockIdx.x;
  const int qq = nwg >> 3, rr = nwg & 7;
  const int xc = orig & 7, ix = orig >> 3;
  const int swz = (xc < rr ? xc * (qq + 1) : rr * (qq + 1) + (xc - rr) * qq) + ix;
  const int by = swz / gx, bx = swz - by * gx;
  const int bm = by * 128, bn = bx * 128;

  const int tid = threadIdx.x;
  const int w = tid >> 6, l = tid & 63;
  const int wr = w >> 1, wc = w & 1;
  const int l16 = l & 15, lk = l >> 4;
  const int srow = tid >> 2;
  const int scol = (((tid & 3) ^ ((srow >> 1) & 3))) * 8;  // pre-swizzled k-chunk
  const int rchunk = (lk ^ ((l16 >> 1) & 3));              // read-side inverse

  int r0 = bm + srow;      if (r0 > M - 1) r0 = M - 1;
  int r1 = bm + srow + 64; if (r1 > M - 1) r1 = M - 1;
  int c0 = bn + srow;      if (c0 > N - 1) c0 = N - 1;
  int c1 = bn + srow + 64; if (c1 > N - 1) c1 = N - 1;
  const u16* pa0 = A + (long long)r0 * lda + scol;
  const u16* pa1 = A + (long long)r1 * lda + scol;
  const u16* pb0 = Bt + (long long)c0 * ldb + scol;
  const u16* pb1 = Bt + (long long)c1 * ldb + scol;

  f32x4 acc[4][4] = {};
  const int nt = K / 32;

  auto stage = [&](int buf, int k0) {
    gload_lds16(pa0 + k0, &As[buf][w * 512]);
    gload_lds16(pa1 + k0, &As[buf][w * 512 + 2048]);
    gload_lds16(pb0 + k0, &Bs[buf][w * 512]);
    gload_lds16(pb1 + k0, &Bs[buf][w * 512 + 2048]);
  };

  stage(0, 0);
  __syncthreads();
  int cur = 0;
  for (int t = 0; t < nt; ++t) {
    if (t + 1 < nt) stage(cur ^ 1, (t + 1) * 32);   // async prefetch next tile
    bf16x8 af[4], bf[4];
#pragma unroll
    for (int m = 0; m < 4; ++m)
      af[m] = *(const bf16x8*)&As[cur][(wr * 64 + m * 16 + l16) * 32 + rchunk * 8];
#pragma unroll
    for (int n = 0; n < 4; ++n)
      bf[n] = *(const bf16x8*)&Bs[cur][(wc * 64 + n * 16 + l16) * 32 + rchunk * 8];
#pragma unroll
    for (int m = 0; m < 4; ++m)
#pragma unroll
      for (int n = 0; n < 4; ++n)
        acc[m][n] = __builtin_amdgcn_mfma_f32_16x16x32_bf16(af[m], bf[n], acc[m][n], 0, 0, 0);
    __syncthreads();   // drains prefetch (vmcnt 0) + protects buffer swap
    cur ^= 1;
  }

#pragma unroll
  for (int m = 0; m < 4; ++m) {
#pragma unroll
    for (int j = 0; j < 4; ++j) {
      int grow = bm + wr * 64 + m * 16 + lk * 4 + j;
      if (grow >= M) continue;
#pragma unroll
      for (int n = 0; n < 4; ++n) {
        int gcol = bn + wc * 64 + n * 16 + l16;
        if (gcol >= N) continue;
        float val = acc[m][n][j] + (bias ? bias[gcol] : 0.f);
        if (EPI == 0) {
          if (OUTBF)
            Ch[(long long)grow * ldc + gcol] = f2bf(val);
          else
            Cf[(long long)grow * ldc + gcol] = val;
        } else if (EPI == 1) {
          int h = gcol / EMB, c = gcol - h * EMB;
          Ch[((long long)h * QLEN + grow) * EMB + c] =
              f2bf(val + extra[(long long)grow * EMB + c]);
        } else {
          int i2 = grow % QLEN, h = grow / QLEN;
          Cf[((long long)i2 * HNEED + h) * EMB + gcol] = val;
        }
      }
    }
  }
}

// ------------------------------------------------------ conversion / transpose
__global__ void f2bf_kernel(const float* __restrict__ in, u16* __restrict__ out, long long n)
{
  long long i = ((long long)blockIdx.x * 256 + threadIdx.x) * 4;
  if (i >= n) return;
  float4 v = *(const float4*)(in + i);
  ushort4 o;
  o.x = f2bf(v.x); o.y = f2bf(v.y); o.z = f2bf(v.z); o.w = f2bf(v.w);
  *(ushort4*)(out + i) = o;
}

// out z-slot = (z/G)*OG + z%G ; out[slot][c][r] = bf16(in[z][r][c])
__global__ __launch_bounds__(256) void transpose_bf(
    const float* __restrict__ in, u16* __restrict__ out, int R, int C, int G, int OG)
{
  __shared__ float t[32][33];
  const int z = blockIdx.z;
  in += (long long)z * R * C;
  out += (long long)((z / G) * OG + (z % G)) * R * C;
  const int c0 = blockIdx.x * 32, r0 = blockIdx.y * 32;
  const int tx = threadIdx.x & 31, ty = threadIdx.x >> 5;  // 32 x 8
  for (int i = 0; i < 32; i += 8) {
    int r = r0 + ty + i, c = c0 + tx;
    t[ty + i][tx] = (r < R && c < C) ? in[(long long)r * C + c] : 0.f;
  }
  __syncthreads();
  for (int i = 0; i < 32; i += 8) {
    int c = c0 + ty + i, r = r0 + tx;
    if (c < C && r < R) out[(long long)c * R + r] = f2bf(t[tx][ty + i]);
  }
}

// ---------------------------------------------------- small packing kernels
__global__ void pack_wct_kernel(const float* __restrict__ Wc, float* __restrict__ WcT)
{
  int idx = blockIdx.x * 256 + threadIdx.x;
  if (idx >= 7680) return;
  int j = idx / EMB, d = idx - j * EMB;
  WcT[idx] = Wc[d * 10 + j];
}

__global__ void pack_bias_kernel(const float* __restrict__ kb, const float* __restrict__ vb,
                                 const float* __restrict__ qb, float* __restrict__ o)
{
  int idx = blockIdx.x * 256 + threadIdx.x;
  if (idx >= 2 * 2304) return;
  int l = idx / 2304, c = idx - l * 2304;
  float v;
  if (c < 768) v = kb[(l * 2) * EMB + c];
  else if (c < 1536) v = vb[(l * 2) * EMB + c - 768];
  else v = qb[(l * 2) * EMB + c - 1536];
  o[idx] = v;
}

// --------------------------------------------- fused assign-softmax + centers
__global__ __launch_bounds__(512) void assign_center512(
    u16* __restrict__ qh_bf,
    const float* __restrict__ WcT, const float* __restrict__ bc,
    const float* __restrict__ centers)
{
  __shared__ float wc_s[7680];
  __shared__ float cen_s[7680];
  const int tid = threadIdx.x;
  for (int i = tid; i < 7680; i += 512) {
    wc_s[i] = WcT[i];
    cen_s[i] = centers[i];
  }
  __syncthreads();
  const int wave = tid >> 6, lane = tid & 63;
  const int row = blockIdx.x * 8 + wave;   // NQ = 30000 = 3750*8 exact
  const long long base = (long long)row * EMB;
  float x[12];
#pragma unroll
  for (int i = 0; i < 12; ++i) x[i] = bf2f(qh_bf[base + lane + 64 * i]);
  float part[10] = {};
#pragma unroll
  for (int i = 0; i < 12; ++i) {
    const float v = x[i];
    const int d = lane + 64 * i;
#pragma unroll
    for (int j = 0; j < 10; ++j) part[j] = fmaf(v, wc_s[j * EMB + d], part[j]);
  }
#pragma unroll
  for (int j = 0; j < 10; ++j)
#pragma unroll
    for (int off = 32; off; off >>= 1) part[j] += __shfl_xor(part[j], off);
  float mx = -1e30f;
#pragma unroll
  for (int j = 0; j < 10; ++j) { part[j] += bc[j]; mx = fmaxf(mx, part[j]); }
  float s = 0.f;
#pragma unroll
  for (int j = 0; j < 10; ++j) { part[j] = __expf(part[j] - mx); s += part[j]; }
  const float inv = 1.f / s;
#pragma unroll
  for (int i = 0; i < 12; ++i) {
    const int d = lane + 64 * i;
    float acc = 0.f;
#pragma unroll
    for (int j = 0; j < 10; ++j) acc = fmaf(part[j], cen_s[j * EMB + d], acc);
    qh_bf[base + d] = f2bf(x[i] + acc * inv);
  }
}

// ------------------------------------------------------------- CSR build
__global__ void hist_kernel(const int* __restrict__ dst, int* __restrict__ cnt, int E)
{
  int e = blockIdx.x * 256 + threadIdx.x;
  if (e < E) atomicAdd(&cnt[dst[e]], 1);
}

__global__ __launch_bounds__(1024) void scan_fill_kernel(
    const int* __restrict__ cnt, int* __restrict__ rowptr, int* __restrict__ cur, int n)
{
  __shared__ int buf[1024];
  const int tid = threadIdx.x;
  const int chunk = (n + 1023) >> 10;
  const int base = tid * chunk;
  int s = 0;
  for (int i = 0; i < chunk; ++i) {
    int idx = base + i;
    if (idx < n) s += cnt[idx];
  }
  buf[tid] = s;
  __syncthreads();
  for (int off = 1; off < 1024; off <<= 1) {
    int v = (tid >= off) ? buf[tid - off] : 0;
    __syncthreads();
    buf[tid] += v;
    __syncthreads();
  }
  int run = (tid == 0) ? 0 : buf[tid - 1];
  for (int i = 0; i < chunk; ++i) {
    int idx = base + i;
    if (idx < n) {
      rowptr[idx] = run;
      cur[idx] = run;
      run += cnt[idx];
    }
  }
  if (tid == 1023) rowptr[n] = buf[1023];
}

__global__ void fill_kernel(const int* __restrict__ src, const int* __restrict__ dst,
                            int* __restrict__ cur, int* __restrict__ adj, int E)
{
  int e = blockIdx.x * 256 + threadIdx.x;
  if (e < E) {
    int p = atomicAdd(&cur[dst[e]], 1);
    adj[p] = src[e];
  }
}

// ---------------------------- give gather (3 head-copies share K/V + adjacency)
__global__ __launch_bounds__(256) void gather_give(
    const u16* __restrict__ q, const u16* __restrict__ kv,
    const int* __restrict__ rowptr, const int* __restrict__ adj,
    const float* __restrict__ rpri, u16* __restrict__ hq_bf)
{
  const int w = (blockIdx.x * 256 + threadIdx.x) >> 6;
  const int lane = threadIdx.x & 63;
  if (w >= QLEN * NHEADS) return;
  const int h = w & 3;
  const int d = w >> 2;
  const int rs = rowptr[d], re = rowptr[d + 1];
  if (rs == re) return;  // no in-edges: rows keep residual
  const float pri = rpri[h] * SCALE;
  float q0[3], q1[3], q2[3];
  float s[3], A0[3], A1[3], A2[3];
#pragma unroll
  for (int c = 0; c < 3; ++c) {
    const u16* qr = q + (long long)(c * QLEN + d) * EMB + h * DKH;
    q0[c] = bf2f(qr[lane]) * pri;
    q1[c] = bf2f(qr[64 + lane]) * pri;
    q2[c] = bf2f(qr[128 + lane]) * pri;
    s[c] = 0.f; A0[c] = 0.f; A1[c] = 0.f; A2[c] = 0.f;
  }

  auto process = [&](float k0, float k1, float k2, float v0, float v1, float v2) {
#pragma unroll
    for (int c = 0; c < 3; ++c) {
      float dot = q0[c] * k0 + q1[c] * k1 + q2[c] * k2;
#pragma unroll
      for (int off = 32; off; off >>= 1) dot += __shfl_xor(dot, off);
      const float e = __expf(dot);
      s[c] += e;
      A0[c] = fmaf(e, v0, A0[c]);
      A1[c] = fmaf(e, v1, A1[c]);
      A2[c] = fmaf(e, v2, A2[c]);
    }
  };

  int i = rs;
  for (; i + 1 < re; i += 2) {
    const u16* kr0 = kv + (long long)adj[i] * 1536 + h * DKH;
    const u16* kr1 = kv + (long long)adj[i + 1] * 1536 + h * DKH;
    float ka = bf2f(kr0[lane]), kb = bf2f(kr0[64 + lane]), kc = bf2f(kr0[128 + lane]);
    float va = bf2f(kr0[768 + lane]), vb = bf2f(kr0[832 + lane]), vc = bf2f(kr0[896 + lane]);
    float kd = bf2f(kr1[lane]), ke = bf2f(kr1[64 + lane]), kf = bf2f(kr1[128 + lane]);
    float vd = bf2f(kr1[768 + lane]), ve = bf2f(kr1[832 + lane]), vf = bf2f(kr1[896 + lane]);
    process(ka, kb, kc, va, vb, vc);
    process(kd, ke, kf, vd, ve, vf);
  }
  if (i < re) {
    const u16* kr0 = kv + (long long)adj[i] * 1536 + h * DKH;
    process(bf2f(kr0[lane]), bf2f(kr0[64 + lane]), bf2f(kr0[128 + lane]),
            bf2f(kr0[768 + lane]), bf2f(kr0[832 + lane]), bf2f(kr0[896 + lane]));
  }

#pragma unroll
  for (int c = 0; c < 3; ++c) {
    const float inv = 1.f / s[c];
    u16* orow = hq_bf + (long long)(c * QLEN + d) * EMB + h * DKH;
    orow[lane]       = f2bf(bf2f(orow[lane])       + A0[c] * inv);
    orow[64 + lane]  = f2bf(bf2f(orow[64 + lane])  + A1[c] * inv);
    orow[128 + lane] = f2bf(bf2f(orow[128 + lane]) + A2[c] * inv);
  }
}

// ------------------- merged inter gather: both tag->tag relations, single RMW
__global__ __launch_bounds__(256) void gather_inter(
    const u16* __restrict__ tag_kvq,   // q at col 1536
    const u16* __restrict__ kv1, const u16* __restrict__ kv2,
    const int* __restrict__ rp1, const int* __restrict__ adj1,
    const int* __restrict__ rp2, const int* __restrict__ adj2,
    const float* __restrict__ pri1, const float* __restrict__ pri2,
    u16* __restrict__ htag_bf)
{
  const int w = (blockIdx.x * 256 + threadIdx.x) >> 6;
  const int lane = threadIdx.x & 63;
  if (w >= TLEN * NHEADS) return;
  const int h = w & 3;
  const int d = w >> 2;
  const int rs1 = rp1[d], re1 = rp1[d + 1];
  const int rs2 = rp2[d], re2 = rp2[d + 1];
  if (rs1 == re1 && rs2 == re2) return;
  const u16* qr = tag_kvq + (long long)d * 2304 + 1536 + h * DKH;
  const float q0 = bf2f(qr[lane]), q1 = bf2f(qr[64 + lane]), q2 = bf2f(qr[128 + lane]);
  float R0 = 0.f, R1 = 0.f, R2 = 0.f;
#pragma unroll
  for (int rel = 0; rel < 2; ++rel) {
    const u16* kv = rel ? kv2 : kv1;
    const int rs = rel ? rs2 : rs1, re = rel ? re2 : re1;
    const int* adj = rel ? adj2 : adj1;
    if (rs == re) continue;
    const float pri = (rel ? pri2[h] : pri1[h]) * SCALE;
    float s = 0.f, A0 = 0.f, A1 = 0.f, A2 = 0.f;
    auto process = [&](float k0, float k1, float k2, float v0, float v1, float v2) {
      float dot = q0 * k0 + q1 * k1 + q2 * k2;
#pragma unroll
      for (int off = 32; off; off >>= 1) dot += __shfl_xor(dot, off);
      const float e = __expf(dot * pri);
      s += e;
      A0 = fmaf(e, v0, A0);
      A1 = fmaf(e, v1, A1);
      A2 = fmaf(e, v2, A2);
    };
    int i = rs;
    for (; i + 1 < re; i += 2) {
      const u16* kr0 = kv + (long long)adj[i] * 1536 + h * DKH;
      const u16* kr1 = kv + (long long)adj[i + 1] * 1536 + h * DKH;
      float ka = bf2f(kr0[lane]), kb = bf2f(kr0[64 + lane]), kc = bf2f(kr0[128 + lane]);
      float va = bf2f(kr0[768 + lane]), vb = bf2f(kr0[832 + lane]), vc = bf2f(kr0[896 + lane]);
      float kd = bf2f(kr1[lane]), ke = bf2f(kr1[64 + lane]), kf = bf2f(kr1[128 + lane]);
      float vd = bf2f(kr1[768 + lane]), ve = bf2f(kr1[832 + lane]), vf = bf2f(kr1[896 + lane]);
      process(ka, kb, kc, va, vb, vc);
      process(kd, ke, kf, vd, ve, vf);
    }
    if (i < re) {
      const u16* kr0 = kv + (long long)adj[i] * 1536 + h * DKH;
      process(bf2f(kr0[lane]), bf2f(kr0[64 + lane]), bf2f(kr0[128 + lane]),
              bf2f(kr0[768 + lane]), bf2f(kr0[832 + lane]), bf2f(kr0[896 + lane]));
    }
    const float inv = 0.5f / s;
    R0 = fmaf(A0, inv, R0); R1 = fmaf(A1, inv, R1); R2 = fmaf(A2, inv, R2);
  }
  u16* orow = htag_bf + (long long)d * EMB + h * DKH;
  orow[lane]       = f2bf(bf2f(orow[lane])       + R0);
  orow[64 + lane]  = f2bf(bf2f(orow[64 + lane])  + R1);
  orow[128 + lane] = f2bf(bf2f(orow[128 + lane]) + R2);
}

}  // namespace

extern "C" void kernel_launch(void* const* d_in, const int* in_sizes, int n_in,
                              void* d_out, int out_size, void* d_ws, size_t ws_size,
                              hipStream_t stream)
{
  const float* q_emb   = (const float*)d_in[0];
  const float* t_emb   = (const float*)d_in[1];
  const int*   give_src = (const int*)d_in[2];
  const int*   give_dst = (const int*)d_in[3];
  const int*   i1_src  = (const int*)d_in[4];
  const int*   i1_dst  = (const int*)d_in[5];
  const int*   i2_src  = (const int*)d_in[6];
  const int*   i2_dst  = (const int*)d_in[7];
  const float* Wq_enc  = (const float*)d_in[8];
  const float* bq_enc  = (const float*)d_in[9];
  const float* Wc      = (const float*)d_in[10];
  const float* bc      = (const float*)d_in[11];
  const float* centers = (const float*)d_in[12];
  const float* kW      = (const float*)d_in[13];
  const float* kb      = (const float*)d_in[14];
  const float* qW      = (const float*)d_in[15];
  const float* qb      = (const float*)d_in[16];
  const float* vW      = (const float*)d_in[17];
  const float* vb      = (const float*)d_in[18];
  const float* rel_att = (const float*)d_in[19];
  const float* rel_msg = (const float*)d_in[20];
  const float* rel_pri = (const float*)d_in[21];
  const float* Wout    = (const float*)d_in[22];
  const float* bout    = (const float*)d_in[23];
  float* out = (float*)d_out;

  const long long WS = (long long)EMB * EMB;   // 589824
  const long long RS = (long long)DKH * DKH;   // 36864

  // -------- workspace carve-up (bf16-only node state)
  float* p = (float*)d_ws;
  auto take = [&](size_t n) { float* r = p; p += ((n + 3) & ~(size_t)3); return r; };
  u16* h_q_bf    = (u16*)take((size_t)NQ * EMB / 2);
  u16* h_tag_bf  = (u16*)take((size_t)TLEN * EMB / 2);
  u16* q_emb_bf  = (u16*)take((size_t)QLEN * EMB / 2);
  u16* tag_kvq   = (u16*)take((size_t)TLEN * 2304 / 2);
  u16* kv_g      = (u16*)take((size_t)TLEN * 1536 / 2);   // kv_g/1/2 contiguous
  u16* kv_1      = (u16*)take((size_t)TLEN * 1536 / 2);
  u16* kv_2      = (u16*)take((size_t)TLEN * 1536 / 2);
  u16* WqT   = (u16*)take((size_t)EMB * EMB * HNEED / 2);
  u16* qWT   = (u16*)take((size_t)4 * WS / 2);
  u16* Wtag  = (u16*)take((size_t)2 * 3 * WS / 2);   // [l][2304][768]
  u16* WoutT = (u16*)take((size_t)WS / 2);
  u16* relWT = (u16*)take((size_t)48 * RS / 2);      // [l*3+r][8][192][192] (k4,v4)
  float* WcT   = take(7680);
  float* b_kvq = take(2 * 2304);
  int* rp_g  = (int*)take(QLEN + 1);
  int* rp_1  = (int*)take(TLEN + 1);
  int* rp_2  = (int*)take(TLEN + 1);
  int* cur_g = (int*)take(QLEN);
  int* cur_1 = (int*)take(TLEN);
  int* cur_2 = (int*)take(TLEN);
  int* adj_g = (int*)take(EG);
  int* adj_1 = (int*)take(EI);
  int* adj_2 = (int*)take(EI);
  int* cnt   = (int*)take(QLEN);
  u16* q_que = (u16*)out;        // d_out as scratch; fully overwritten at end

  auto gemmb = [&](int EPI, int OUTBF, const u16* A, int lda, long long sAz,
                   const u16* Bt, int ldb, long long sBz,
                   void* C, int ldc, long long sCz, long long sCz2, int relpack,
                   const float* bias, const float* extra,
                   int M, int N, int K, int batch) {
    dim3 grid((N + 127) / 128, (M + 127) / 128, batch);
    if (EPI == 0 && OUTBF == 0)
      gemm_bf16<0, 0><<<grid, 256, 0, stream>>>(A, lda, sAz, Bt, ldb, sBz, C, ldc, sCz, sCz2, relpack, bias, extra, M, N, K);
    else if (EPI == 0 && OUTBF == 1)
      gemm_bf16<0, 1><<<grid, 256, 0, stream>>>(A, lda, sAz, Bt, ldb, sBz, C, ldc, sCz, sCz2, relpack, bias, extra, M, N, K);
    else if (EPI == 1)
      gemm_bf16<1, 1><<<grid, 256, 0, stream>>>(A, lda, sAz, Bt, ldb, sBz, C, ldc, sCz, sCz2, relpack, bias, extra, M, N, K);
    else
      gemm_bf16<2, 0><<<grid, 256, 0, stream>>>(A, lda, sAz, Bt, ldb, sBz, C, ldc, sCz, sCz2, relpack, bias, extra, M, N, K);
  };

  // -------- CSR builds (static graphs)
  auto build_csr = [&](const int* src, const int* dst, int E, int n,
                       int* rp, int* cu, int* adj) {
    hipMemsetAsync(cnt, 0, (size_t)n * sizeof(int), stream);
    hist_kernel<<<(E + 255) / 256, 256, 0, stream>>>(dst, cnt, E);
    scan_fill_kernel<<<1, 1024, 0, stream>>>(cnt, rp, cu, n);
    fill_kernel<<<(E + 255) / 256, 256, 0, stream>>>(src, dst, cu, adj, E);
  };
  build_csr(give_src, give_dst, EG, QLEN, rp_g, cur_g, adj_g);
  build_csr(i1_src, i1_dst, EI, TLEN, rp_1, cur_1, adj_1);
  build_csr(i2_src, i2_dst, EI, TLEN, rp_2, cur_2, adj_2);

  // -------- one-time packs / transposes
  pack_wct_kernel<<<30, 256, 0, stream>>>(Wc, WcT);
  pack_bias_kernel<<<18, 256, 0, stream>>>(kb, vb, qb, b_kvq);
  transpose_bf<<<dim3(EMB * HNEED / 32, EMB / 32, 1), 256, 0, stream>>>(Wq_enc, WqT, EMB, EMB * HNEED, 1, 1);
  transpose_bf<<<dim3(EMB / 32, EMB / 32, 4), 256, 0, stream>>>(qW, qWT, EMB, EMB, 1, 1);
  // fused tag weight [l][2304][768]: rows 0-767 k, 768-1535 v, 1536-2303 q
  for (int l = 0; l < 2; ++l) {
    transpose_bf<<<dim3(EMB / 32, EMB / 32, 1), 256, 0, stream>>>(kW + (l * 2) * WS, Wtag + (l * 3 + 0) * WS, EMB, EMB, 1, 1);
    transpose_bf<<<dim3(EMB / 32, EMB / 32, 1), 256, 0, stream>>>(vW + (l * 2) * WS, Wtag + (l * 3 + 1) * WS, EMB, EMB, 1, 1);
    transpose_bf<<<dim3(EMB / 32, EMB / 32, 1), 256, 0, stream>>>(qW + (l * 2) * WS, Wtag + (l * 3 + 2) * WS, EMB, EMB, 1, 1);
  }
  transpose_bf<<<dim3(EMB / 32, EMB / 32, 1), 256, 0, stream>>>(Wout, WoutT, EMB, EMB, 1, 1);
  // relWT: z = lr*4+h -> slot lr*8 + h (ratt) / lr*8 + 4 + h (rmsg)
  transpose_bf<<<dim3(DKH / 32, DKH / 32, 24), 256, 0, stream>>>(rel_att, relWT, DKH, DKH, 4, 8);
  transpose_bf<<<dim3(DKH / 32, DKH / 32, 24), 256, 0, stream>>>(rel_msg, relWT + 4 * RS, DKH, DKH, 4, 8);

  // -------- question encoder + clustering (h_q_bf = bf16 state)
  f2bf_kernel<<<(QLEN * EMB / 4 + 255) / 256, 256, 0, stream>>>(q_emb, q_emb_bf, (long long)QLEN * EMB);
  gemmb(1, 1, q_emb_bf, EMB, 0, WqT, EMB, 0, h_q_bf, EMB, 0, 0, 0, bq_enc, q_emb,
        QLEN, EMB * HNEED, EMB, 1);
  assign_center512<<<NQ / 8, 512, 0, stream>>>(h_q_bf, WcT, bc, centers);
  f2bf_kernel<<<(TLEN * EMB / 4 + 255) / 256, 256, 0, stream>>>(t_emb, h_tag_bf, (long long)TLEN * EMB);

  const long long KVZ = (long long)TLEN * 1536;   // elements per kv buffer (u16)
  for (int l = 0; l < 2; ++l) {
    // fused K|V|Q tag projection: [3000][2304] bf16
    gemmb(0, 1, h_tag_bf, EMB, 0, Wtag + (long long)l * 3 * WS, EMB, 0,
          tag_kvq, 2304, 0, 0, 0, b_kvq + l * 2304, nullptr, TLEN, 2304, EMB, 1);
    // question Q projection
    gemmb(0, 1, h_q_bf, EMB, 0, qWT + (l * 2 + 1) * WS, EMB, 0,
          q_que, EMB, 0, 0, 0, qb + (l * 2 + 1) * EMB, nullptr, NQ, EMB, EMB, 1);
    // all 3 relations' K/V transforms in one z=24 batch (relpack mode)
    gemmb(0, 1, tag_kvq, 2304, 192, relWT + (long long)(l * 3) * 8 * RS, DKH, RS,
          kv_g, 1536, 192, KVZ, 1, nullptr, nullptr, TLEN, DKH, DKH, 24);
    // gathers (bf16 RMW into node state)
    gather_give<<<QLEN * NHEADS / 4, 256, 0, stream>>>(
        q_que, kv_g, rp_g, adj_g, rel_pri + (l * 3 + 0) * NHEADS, h_q_bf);
    gather_inter<<<TLEN * NHEADS / 4, 256, 0, stream>>>(
        tag_kvq, kv_1, kv_2, rp_1, adj_1, rp_2, adj_2,
        rel_pri + (l * 3 + 1) * NHEADS, rel_pri + (l * 3 + 2) * NHEADS,
        h_tag_bf);
  }

  // -------- outputs
  gemmb(2, 0, h_q_bf, EMB, 0, WoutT, EMB, 0, out, EMB, 0, 0, 0, bout, nullptr,
        NQ, EMB, EMB, 1);
  gemmb(0, 0, h_tag_bf, EMB, 0, WoutT, EMB, 0, out + (size_t)NQ * EMB, EMB, 0, 0, 0,
        bout, nullptr, TLEN, EMB, EMB, 1);
}

// Round 8
// 882.000 us; speedup vs baseline: 7.5140x; 1.1199x over previous
//
#include <hip/hip_runtime.h>

#define QLEN 10000
#define TLEN 3000
#define EMB 768
#define HNEED 3
#define NQ (QLEN * HNEED)
#define EG 100000
#define EI 100000
#define DKH 192
#define NHEADS 4

namespace {

typedef unsigned short u16;
typedef unsigned char u8;
typedef unsigned int u32;
typedef __attribute__((ext_vector_type(8))) short bf16x8;
typedef __attribute__((ext_vector_type(4))) float f32x4;
typedef __attribute__((ext_vector_type(2))) float f32x2;

constexpr float SCALE = 0.07216878364870322f; // 1/sqrt(192)

__device__ inline u16 f2bf(float f) {
  unsigned u = __float_as_uint(f);
  unsigned r = (u + 0x7FFFu + ((u >> 16) & 1u)) >> 16;  // RNE
  return (u16)r;
}
__device__ inline float bf2f(u16 h) {
  return __uint_as_float((unsigned)h << 16);
}
__device__ inline u8 f2fp8(float f) {
  u32 pk = __builtin_amdgcn_cvt_pk_fp8_f32(f, f, 0, false);
  return (u8)(pk & 0xFF);
}
// decode 12 fp8 (3 dwords) -> 12 floats
__device__ inline void decode12(const u32* p, float* o) {
#pragma unroll
  for (int t = 0; t < 3; ++t) {
    u32 w = p[t];
    f32x2 lo = __builtin_amdgcn_cvt_pk_f32_fp8(w, false);
    f32x2 hi = __builtin_amdgcn_cvt_pk_f32_fp8(w, true);
    o[t * 4 + 0] = lo[0]; o[t * 4 + 1] = lo[1];
    o[t * 4 + 2] = hi[0]; o[t * 4 + 3] = hi[1];
  }
}
__device__ inline f32x2 bfx2(u32 w) {
  f32x2 r;
  r[0] = __uint_as_float(w << 16);
  r[1] = __uint_as_float(w & 0xFFFF0000u);
  return r;
}

__device__ inline void gload_lds16(const u16* g, u16* s) {
  __builtin_amdgcn_global_load_lds(
      (const __attribute__((address_space(1))) unsigned*)g,
      (__attribute__((address_space(3))) unsigned*)s, 16, 0, 0);
}

// ------------------------------------------------------------ bf16 MFMA GEMM
// A [M][K] bf16 row-major, Bt [N][K] bf16 row-major (B transposed).
// 128x128 tile, BK=32, 2-phase double-buffered LDS, XCD-chunked swizzle,
// LDS k-chunk swizzle. OUT: 0=f32, 1=bf16, 2=fp8.
// EPI 0: C[m][n]
// EPI 1: encoder: C_bf[(n/768)*QLEN + m][n%768] = bf16(v + extra[m][n%768])
// EPI 2: ques out: C[(m%QLEN)*3 + m/QLEN][n] = v (f32)
template <int EPI, int OUT>
__global__ __launch_bounds__(256) void gemm_bf16(
    const u16* __restrict__ A, int lda, long long sAz,
    const u16* __restrict__ Bt, int ldb, long long sBz,
    void* __restrict__ Cv, int ldc, long long sCz, long long sCz2, int relpack,
    const float* __restrict__ bias, const float* __restrict__ extra,
    int M, int N, int K)
{
  __shared__ __align__(16) u16 As[2][4096];
  __shared__ __align__(16) u16 Bs[2][4096];
  const int z = blockIdx.z;
  float* Cf = (float*)Cv;
  u16* Ch = (u16*)Cv;
  u8* C8 = (u8*)Cv;
  if (relpack) {
    const int zr = z >> 3, zh = z & 7;
    A += (long long)zh * sAz;
    Bt += (long long)z * sBz;
    const long long co = (long long)zr * sCz2 + (long long)zh * sCz;
    Cf += co; Ch += co; C8 += co;
  } else {
    A += (long long)z * sAz;
    Bt += (long long)z * sBz;
    Cf += (long long)z * sCz;
    Ch += (long long)z * sCz;
    C8 += (long long)z * sCz;
  }
  // XCD-chunked bijective remap
  const int gx = gridDim.x;
  const int nwg = gx * gridDim.y;
  const int orig = blockIdx.y * gx + blockIdx.x;
  const int qq = nwg >> 3, rr = nwg & 7;
  const int xc = orig & 7, ix = orig >> 3;
  const int swz = (xc < rr ? xc * (qq + 1) : rr * (qq + 1) + (xc - rr) * qq) + ix;
  const int by = swz / gx, bx = swz - by * gx;
  const int bm = by * 128, bn = bx * 128;

  const int tid = threadIdx.x;
  const int w = tid >> 6, l = tid & 63;
  const int wr = w >> 1, wc = w & 1;
  const int l16 = l & 15, lk = l >> 4;
  const int srow = tid >> 2;
  const int scol = (((tid & 3) ^ ((srow >> 1) & 3))) * 8;  // pre-swizzled k-chunk
  const int rchunk = (lk ^ ((l16 >> 1) & 3));              // read-side inverse

  int r0 = bm + srow;      if (r0 > M - 1) r0 = M - 1;
  int r1 = bm + srow + 64; if (r1 > M - 1) r1 = M - 1;
  int c0 = bn + srow;      if (c0 > N - 1) c0 = N - 1;
  int c1 = bn + srow + 64; if (c1 > N - 1) c1 = N - 1;
  const u16* pa0 = A + (long long)r0 * lda + scol;
  const u16* pa1 = A + (long long)r1 * lda + scol;
  const u16* pb0 = Bt + (long long)c0 * ldb + scol;
  const u16* pb1 = Bt + (long long)c1 * ldb + scol;

  f32x4 acc[4][4] = {};
  const int nt = K / 32;

  auto stage = [&](int buf, int k0) {
    gload_lds16(pa0 + k0, &As[buf][w * 512]);
    gload_lds16(pa1 + k0, &As[buf][w * 512 + 2048]);
    gload_lds16(pb0 + k0, &Bs[buf][w * 512]);
    gload_lds16(pb1 + k0, &Bs[buf][w * 512 + 2048]);
  };

  stage(0, 0);
  __syncthreads();
  int cur = 0;
  for (int t = 0; t < nt; ++t) {
    if (t + 1 < nt) stage(cur ^ 1, (t + 1) * 32);
    bf16x8 af[4], bf[4];
#pragma unroll
    for (int m = 0; m < 4; ++m)
      af[m] = *(const bf16x8*)&As[cur][(wr * 64 + m * 16 + l16) * 32 + rchunk * 8];
#pragma unroll
    for (int n = 0; n < 4; ++n)
      bf[n] = *(const bf16x8*)&Bs[cur][(wc * 64 + n * 16 + l16) * 32 + rchunk * 8];
#pragma unroll
    for (int m = 0; m < 4; ++m)
#pragma unroll
      for (int n = 0; n < 4; ++n)
        acc[m][n] = __builtin_amdgcn_mfma_f32_16x16x32_bf16(af[m], bf[n], acc[m][n], 0, 0, 0);
    __syncthreads();
    cur ^= 1;
  }

#pragma unroll
  for (int m = 0; m < 4; ++m) {
#pragma unroll
    for (int j = 0; j < 4; ++j) {
      int grow = bm + wr * 64 + m * 16 + lk * 4 + j;
      if (grow >= M) continue;
#pragma unroll
      for (int n = 0; n < 4; ++n) {
        int gcol = bn + wc * 64 + n * 16 + l16;
        if (gcol >= N) continue;
        float val = acc[m][n][j] + (bias ? bias[gcol] : 0.f);
        if (EPI == 0) {
          if (OUT == 0)
            Cf[(long long)grow * ldc + gcol] = val;
          else if (OUT == 1)
            Ch[(long long)grow * ldc + gcol] = f2bf(val);
          else
            C8[(long long)grow * ldc + gcol] = f2fp8(val);
        } else if (EPI == 1) {
          int h = gcol / EMB, c = gcol - h * EMB;
          Ch[((long long)h * QLEN + grow) * EMB + c] =
              f2bf(val + extra[(long long)grow * EMB + c]);
        } else {
          int i2 = grow % QLEN, h = grow / QLEN;
          Cf[((long long)i2 * HNEED + h) * EMB + gcol] = val;
        }
      }
    }
  }
}

// ------------------------------------------------------ conversion / transpose
__global__ void f2bf_kernel(const float* __restrict__ in, u16* __restrict__ out, long long n)
{
  long long i = ((long long)blockIdx.x * 256 + threadIdx.x) * 4;
  if (i >= n) return;
  float4 v = *(const float4*)(in + i);
  ushort4 o;
  o.x = f2bf(v.x); o.y = f2bf(v.y); o.z = f2bf(v.z); o.w = f2bf(v.w);
  *(ushort4*)(out + i) = o;
}

// out z-slot = (z/G)*OG + z%G ; out[slot][c][r] = bf16(in[z][r][c])
__global__ __launch_bounds__(256) void transpose_bf(
    const float* __restrict__ in, u16* __restrict__ out, int R, int C, int G, int OG)
{
  __shared__ float t[32][33];
  const int z = blockIdx.z;
  in += (long long)z * R * C;
  out += (long long)((z / G) * OG + (z % G)) * R * C;
  const int c0 = blockIdx.x * 32, r0 = blockIdx.y * 32;
  const int tx = threadIdx.x & 31, ty = threadIdx.x >> 5;  // 32 x 8
  for (int i = 0; i < 32; i += 8) {
    int r = r0 + ty + i, c = c0 + tx;
    t[ty + i][tx] = (r < R && c < C) ? in[(long long)r * C + c] : 0.f;
  }
  __syncthreads();
  for (int i = 0; i < 32; i += 8) {
    int c = c0 + ty + i, r = r0 + tx;
    if (c < C && r < R) out[(long long)c * R + r] = f2bf(t[tx][ty + i]);
  }
}

// ---------------------------------------------------- small packing kernels
__global__ void pack_wct_kernel(const float* __restrict__ Wc, float* __restrict__ WcT)
{
  int idx = blockIdx.x * 256 + threadIdx.x;
  if (idx >= 7680) return;
  int j = idx / EMB, d = idx - j * EMB;
  WcT[idx] = Wc[d * 10 + j];
}

__global__ void pack_bias_kernel(const float* __restrict__ kb, const float* __restrict__ vb,
                                 const float* __restrict__ qb, float* __restrict__ o)
{
  int idx = blockIdx.x * 256 + threadIdx.x;
  if (idx >= 2 * 2304) return;
  int l = idx / 2304, c = idx - l * 2304;
  float v;
  if (c < 768) v = kb[(l * 2) * EMB + c];
  else if (c < 1536) v = vb[(l * 2) * EMB + c - 768];
  else v = qb[(l * 2) * EMB + c - 1536];
  o[idx] = v;
}

// --------------------------------------------- fused assign-softmax + centers
__global__ __launch_bounds__(512) void assign_center512(
    u16* __restrict__ qh_bf,
    const float* __restrict__ WcT, const float* __restrict__ bc,
    const float* __restrict__ centers)
{
  __shared__ float wc_s[7680];
  __shared__ float cen_s[7680];
  const int tid = threadIdx.x;
  for (int i = tid; i < 7680; i += 512) {
    wc_s[i] = WcT[i];
    cen_s[i] = centers[i];
  }
  __syncthreads();
  const int wave = tid >> 6, lane = tid & 63;
  const int row = blockIdx.x * 8 + wave;   // NQ = 30000 = 3750*8 exact
  const long long base = (long long)row * EMB;
  float x[12];
#pragma unroll
  for (int i = 0; i < 12; ++i) x[i] = bf2f(qh_bf[base + lane + 64 * i]);
  float part[10] = {};
#pragma unroll
  for (int i = 0; i < 12; ++i) {
    const float v = x[i];
    const int d = lane + 64 * i;
#pragma unroll
    for (int j = 0; j < 10; ++j) part[j] = fmaf(v, wc_s[j * EMB + d], part[j]);
  }
#pragma unroll
  for (int j = 0; j < 10; ++j)
#pragma unroll
    for (int off = 32; off; off >>= 1) part[j] += __shfl_xor(part[j], off);
  float mx = -1e30f;
#pragma unroll
  for (int j = 0; j < 10; ++j) { part[j] += bc[j]; mx = fmaxf(mx, part[j]); }
  float s = 0.f;
#pragma unroll
  for (int j = 0; j < 10; ++j) { part[j] = __expf(part[j] - mx); s += part[j]; }
  const float inv = 1.f / s;
#pragma unroll
  for (int i = 0; i < 12; ++i) {
    const int d = lane + 64 * i;
    float acc = 0.f;
#pragma unroll
    for (int j = 0; j < 10; ++j) acc = fmaf(part[j], cen_s[j * EMB + d], acc);
    qh_bf[base + d] = f2bf(x[i] + acc * inv);
  }
}

// ------------------------------------------------------------- CSR build
__global__ void hist_kernel(const int* __restrict__ dst, int* __restrict__ cnt, int E)
{
  int e = blockIdx.x * 256 + threadIdx.x;
  if (e < E) atomicAdd(&cnt[dst[e]], 1);
}

__global__ __launch_bounds__(1024) void scan_fill_kernel(
    const int* __restrict__ cnt, int* __restrict__ rowptr, int* __restrict__ cur, int n)
{
  __shared__ int buf[1024];
  const int tid = threadIdx.x;
  const int chunk = (n + 1023) >> 10;
  const int base = tid * chunk;
  int s = 0;
  for (int i = 0; i < chunk; ++i) {
    int idx = base + i;
    if (idx < n) s += cnt[idx];
  }
  buf[tid] = s;
  __syncthreads();
  for (int off = 1; off < 1024; off <<= 1) {
    int v = (tid >= off) ? buf[tid - off] : 0;
    __syncthreads();
    buf[tid] += v;
    __syncthreads();
  }
  int run = (tid == 0) ? 0 : buf[tid - 1];
  for (int i = 0; i < chunk; ++i) {
    int idx = base + i;
    if (idx < n) {
      rowptr[idx] = run;
      cur[idx] = run;
      run += cnt[idx];
    }
  }
  if (tid == 1023) rowptr[n] = buf[1023];
}

__global__ void fill_kernel(const int* __restrict__ src, const int* __restrict__ dst,
                            int* __restrict__ cur, int* __restrict__ adj, int E)
{
  int e = blockIdx.x * 256 + threadIdx.x;
  if (e < E) {
    int p = atomicAdd(&cur[dst[e]], 1);
    adj[p] = src[e];
  }
}

// ------------- give gather: one wave per dst, all 4 heads, fp8 K/V/Q, 3 copies
// lane = h*16 + sub; lane owns elems [sub*12, sub*12+12) of head h's slice.
// kv row: 768 fp8 K | 768 fp8 V (1536 B).
__global__ __launch_bounds__(256) void gather_give(
    const u8* __restrict__ q, const u8* __restrict__ kv,
    const int* __restrict__ rowptr, const int* __restrict__ adj,
    const float* __restrict__ rpri, u16* __restrict__ hq_bf)
{
  const int d = (blockIdx.x * 256 + threadIdx.x) >> 6;
  const int lane = threadIdx.x & 63;
  if (d >= QLEN) return;
  const int rs = rowptr[d], re = rowptr[d + 1];
  if (rs == re) return;  // no in-edges: rows keep residual
  const int h = lane >> 4, sub = lane & 15;
  const int off = h * DKH + sub * 12;
  const float pri = rpri[h] * SCALE;

  float qv[3][12];
#pragma unroll
  for (int c = 0; c < 3; ++c)
    decode12((const u32*)(q + (size_t)(c * QLEN + d) * EMB + off), qv[c]);

  float S[3] = {0.f, 0.f, 0.f};
  float A[3][12] = {};

  auto edge = [&](int sn) {
    float kf[12], vf[12];
    decode12((const u32*)(kv + (size_t)sn * 1536 + off), kf);
    decode12((const u32*)(kv + (size_t)sn * 1536 + 768 + off), vf);
    float dt[3] = {0.f, 0.f, 0.f};
#pragma unroll
    for (int t = 0; t < 12; ++t) {
#pragma unroll
      for (int c = 0; c < 3; ++c) dt[c] = fmaf(qv[c][t], kf[t], dt[c]);
    }
#pragma unroll
    for (int c = 0; c < 3; ++c) {
#pragma unroll
      for (int o2 = 8; o2; o2 >>= 1) dt[c] += __shfl_xor(dt[c], o2);
      const float e = __expf(dt[c] * pri);
      S[c] += e;
#pragma unroll
      for (int t = 0; t < 12; ++t) A[c][t] = fmaf(e, vf[t], A[c][t]);
    }
  };
  int i = rs;
  for (; i + 1 < re; i += 2) { edge(adj[i]); edge(adj[i + 1]); }
  if (i < re) edge(adj[i]);

#pragma unroll
  for (int c = 0; c < 3; ++c) {
    const float inv = 1.f / S[c];
    u32* o = (u32*)(hq_bf + (size_t)(c * QLEN + d) * EMB + off);
#pragma unroll
    for (int t = 0; t < 6; ++t) {
      f32x2 r = bfx2(o[t]);
      r[0] += A[c][2 * t] * inv;
      r[1] += A[c][2 * t + 1] * inv;
      o[t] = (u32)f2bf(r[0]) | ((u32)f2bf(r[1]) << 16);
    }
  }
}

// ---- merged inter gather: one wave per dst, all 4 heads, both relations
__global__ __launch_bounds__(256) void gather_inter(
    const u16* __restrict__ tag_kvq,   // bf16, q at col 1536
    const u8* __restrict__ kv1, const u8* __restrict__ kv2,
    const int* __restrict__ rp1, const int* __restrict__ adj1,
    const int* __restrict__ rp2, const int* __restrict__ adj2,
    const float* __restrict__ pri1, const float* __restrict__ pri2,
    u16* __restrict__ htag_bf)
{
  const int d = (blockIdx.x * 256 + threadIdx.x) >> 6;
  const int lane = threadIdx.x & 63;
  if (d >= TLEN) return;
  const int rs1 = rp1[d], re1 = rp1[d + 1];
  const int rs2 = rp2[d], re2 = rp2[d + 1];
  if (rs1 == re1 && rs2 == re2) return;
  const int h = lane >> 4, sub = lane & 15;
  const int off = h * DKH + sub * 12;
  float qv[12];
  {
    const u32* qp = (const u32*)(tag_kvq + (size_t)d * 2304 + 1536 + off);
#pragma unroll
    for (int t = 0; t < 6; ++t) {
      f32x2 r = bfx2(qp[t]);
      qv[2 * t] = r[0]; qv[2 * t + 1] = r[1];
    }
  }
  float R[12] = {};
#pragma unroll
  for (int rel = 0; rel < 2; ++rel) {
    const u8* kv = rel ? kv2 : kv1;
    const int rs = rel ? rs2 : rs1, re = rel ? re2 : re1;
    const int* adj = rel ? adj2 : adj1;
    if (rs == re) continue;
    const float pri = (rel ? pri2[h] : pri1[h]) * SCALE;
    float S = 0.f, A[12] = {};
    auto edge = [&](int sn) {
      float kf[12], vf[12];
      decode12((const u32*)(kv + (size_t)sn * 1536 + off), kf);
      decode12((const u32*)(kv + (size_t)sn * 1536 + 768 + off), vf);
      float dt = 0.f;
#pragma unroll
      for (int t = 0; t < 12; ++t) dt = fmaf(qv[t], kf[t], dt);
#pragma unroll
      for (int o2 = 8; o2; o2 >>= 1) dt += __shfl_xor(dt, o2);
      const float e = __expf(dt * pri);
      S += e;
#pragma unroll
      for (int t = 0; t < 12; ++t) A[t] = fmaf(e, vf[t], A[t]);
    };
    int i = rs;
    for (; i + 1 < re; i += 2) { edge(adj[i]); edge(adj[i + 1]); }
    if (i < re) edge(adj[i]);
    const float inv = 0.5f / S;
#pragma unroll
    for (int t = 0; t < 12; ++t) R[t] = fmaf(A[t], inv, R[t]);
  }
  u32* o = (u32*)(htag_bf + (size_t)d * EMB + off);
#pragma unroll
  for (int t = 0; t < 6; ++t) {
    f32x2 r = bfx2(o[t]);
    r[0] += R[2 * t];
    r[1] += R[2 * t + 1];
    o[t] = (u32)f2bf(r[0]) | ((u32)f2bf(r[1]) << 16);
  }
}

}  // namespace

extern "C" void kernel_launch(void* const* d_in, const int* in_sizes, int n_in,
                              void* d_out, int out_size, void* d_ws, size_t ws_size,
                              hipStream_t stream)
{
  const float* q_emb   = (const float*)d_in[0];
  const float* t_emb   = (const float*)d_in[1];
  const int*   give_src = (const int*)d_in[2];
  const int*   give_dst = (const int*)d_in[3];
  const int*   i1_src  = (const int*)d_in[4];
  const int*   i1_dst  = (const int*)d_in[5];
  const int*   i2_src  = (const int*)d_in[6];
  const int*   i2_dst  = (const int*)d_in[7];
  const float* Wq_enc  = (const float*)d_in[8];
  const float* bq_enc  = (const float*)d_in[9];
  const float* Wc      = (const float*)d_in[10];
  const float* bc      = (const float*)d_in[11];
  const float* centers = (const float*)d_in[12];
  const float* kW      = (const float*)d_in[13];
  const float* kb      = (const float*)d_in[14];
  const float* qW      = (const float*)d_in[15];
  const float* qb      = (const float*)d_in[16];
  const float* vW      = (const float*)d_in[17];
  const float* vb      = (const float*)d_in[18];
  const float* rel_att = (const float*)d_in[19];
  const float* rel_msg = (const float*)d_in[20];
  const float* rel_pri = (const float*)d_in[21];
  const float* Wout    = (const float*)d_in[22];
  const float* bout    = (const float*)d_in[23];
  float* out = (float*)d_out;

  const long long WS = (long long)EMB * EMB;   // 589824
  const long long RS = (long long)DKH * DKH;   // 36864

  // -------- workspace carve-up (bf16 node state, fp8 gather operands)
  float* p = (float*)d_ws;
  auto take = [&](size_t n) { float* r = p; p += ((n + 3) & ~(size_t)3); return r; };
  u16* h_q_bf    = (u16*)take((size_t)NQ * EMB / 2);
  u16* h_tag_bf  = (u16*)take((size_t)TLEN * EMB / 2);
  u16* q_emb_bf  = (u16*)take((size_t)QLEN * EMB / 2);
  u16* tag_kvq   = (u16*)take((size_t)TLEN * 2304 / 2);
  u8* kv_all     = (u8*)take((size_t)3 * TLEN * 1536 / 4);  // fp8: 3 x 4.6MB
  u8* kv_g = kv_all;
  u8* kv_1 = kv_all + (size_t)TLEN * 1536;
  u8* kv_2 = kv_all + (size_t)2 * TLEN * 1536;
  u16* WqT   = (u16*)take((size_t)EMB * EMB * HNEED / 2);
  u16* qWT   = (u16*)take((size_t)4 * WS / 2);
  u16* Wtag  = (u16*)take((size_t)2 * 3 * WS / 2);   // [l][2304][768]
  u16* WoutT = (u16*)take((size_t)WS / 2);
  u16* relWT = (u16*)take((size_t)48 * RS / 2);      // [l*3+r][8][192][192]
  float* WcT   = take(7680);
  float* b_kvq = take(2 * 2304);
  int* rp_g  = (int*)take(QLEN + 1);
  int* rp_1  = (int*)take(TLEN + 1);
  int* rp_2  = (int*)take(TLEN + 1);
  int* cur_g = (int*)take(QLEN);
  int* cur_1 = (int*)take(TLEN);
  int* cur_2 = (int*)take(TLEN);
  int* adj_g = (int*)take(EG);
  int* adj_1 = (int*)take(EI);
  int* adj_2 = (int*)take(EI);
  int* cnt   = (int*)take(QLEN);
  u8* q_que = (u8*)out;          // d_out as scratch (fp8, 23MB); overwritten at end

  auto gemmb = [&](int EPI, int OUT, const u16* A, int lda, long long sAz,
                   const u16* Bt, int ldb, long long sBz,
                   void* C, int ldc, long long sCz, long long sCz2, int relpack,
                   const float* bias, const float* extra,
                   int M, int N, int K, int batch) {
    dim3 grid((N + 127) / 128, (M + 127) / 128, batch);
    if (EPI == 0 && OUT == 0)
      gemm_bf16<0, 0><<<grid, 256, 0, stream>>>(A, lda, sAz, Bt, ldb, sBz, C, ldc, sCz, sCz2, relpack, bias, extra, M, N, K);
    else if (EPI == 0 && OUT == 1)
      gemm_bf16<0, 1><<<grid, 256, 0, stream>>>(A, lda, sAz, Bt, ldb, sBz, C, ldc, sCz, sCz2, relpack, bias, extra, M, N, K);
    else if (EPI == 0 && OUT == 2)
      gemm_bf16<0, 2><<<grid, 256, 0, stream>>>(A, lda, sAz, Bt, ldb, sBz, C, ldc, sCz, sCz2, relpack, bias, extra, M, N, K);
    else if (EPI == 1)
      gemm_bf16<1, 1><<<grid, 256, 0, stream>>>(A, lda, sAz, Bt, ldb, sBz, C, ldc, sCz, sCz2, relpack, bias, extra, M, N, K);
    else
      gemm_bf16<2, 0><<<grid, 256, 0, stream>>>(A, lda, sAz, Bt, ldb, sBz, C, ldc, sCz, sCz2, relpack, bias, extra, M, N, K);
  };

  // -------- CSR builds (static graphs)
  auto build_csr = [&](const int* src, const int* dst, int E, int n,
                       int* rp, int* cu, int* adj) {
    hipMemsetAsync(cnt, 0, (size_t)n * sizeof(int), stream);
    hist_kernel<<<(E + 255) / 256, 256, 0, stream>>>(dst, cnt, E);
    scan_fill_kernel<<<1, 1024, 0, stream>>>(cnt, rp, cu, n);
    fill_kernel<<<(E + 255) / 256, 256, 0, stream>>>(src, dst, cu, adj, E);
  };
  build_csr(give_src, give_dst, EG, QLEN, rp_g, cur_g, adj_g);
  build_csr(i1_src, i1_dst, EI, TLEN, rp_1, cur_1, adj_1);
  build_csr(i2_src, i2_dst, EI, TLEN, rp_2, cur_2, adj_2);

  // -------- one-time packs / transposes
  pack_wct_kernel<<<30, 256, 0, stream>>>(Wc, WcT);
  pack_bias_kernel<<<18, 256, 0, stream>>>(kb, vb, qb, b_kvq);
  transpose_bf<<<dim3(EMB * HNEED / 32, EMB / 32, 1), 256, 0, stream>>>(Wq_enc, WqT, EMB, EMB * HNEED, 1, 1);
  transpose_bf<<<dim3(EMB / 32, EMB / 32, 4), 256, 0, stream>>>(qW, qWT, EMB, EMB, 1, 1);
  for (int l = 0; l < 2; ++l) {
    transpose_bf<<<dim3(EMB / 32, EMB / 32, 1), 256, 0, stream>>>(kW + (l * 2) * WS, Wtag + (l * 3 + 0) * WS, EMB, EMB, 1, 1);
    transpose_bf<<<dim3(EMB / 32, EMB / 32, 1), 256, 0, stream>>>(vW + (l * 2) * WS, Wtag + (l * 3 + 1) * WS, EMB, EMB, 1, 1);
    transpose_bf<<<dim3(EMB / 32, EMB / 32, 1), 256, 0, stream>>>(qW + (l * 2) * WS, Wtag + (l * 3 + 2) * WS, EMB, EMB, 1, 1);
  }
  transpose_bf<<<dim3(EMB / 32, EMB / 32, 1), 256, 0, stream>>>(Wout, WoutT, EMB, EMB, 1, 1);
  transpose_bf<<<dim3(DKH / 32, DKH / 32, 24), 256, 0, stream>>>(rel_att, relWT, DKH, DKH, 4, 8);
  transpose_bf<<<dim3(DKH / 32, DKH / 32, 24), 256, 0, stream>>>(rel_msg, relWT + 4 * RS, DKH, DKH, 4, 8);

  // -------- question encoder + clustering (bf16 state)
  f2bf_kernel<<<(QLEN * EMB / 4 + 255) / 256, 256, 0, stream>>>(q_emb, q_emb_bf, (long long)QLEN * EMB);
  gemmb(1, 1, q_emb_bf, EMB, 0, WqT, EMB, 0, h_q_bf, EMB, 0, 0, 0, bq_enc, q_emb,
        QLEN, EMB * HNEED, EMB, 1);
  assign_center512<<<NQ / 8, 512, 0, stream>>>(h_q_bf, WcT, bc, centers);
  f2bf_kernel<<<(TLEN * EMB / 4 + 255) / 256, 256, 0, stream>>>(t_emb, h_tag_bf, (long long)TLEN * EMB);

  const long long KVZ = (long long)TLEN * 1536;   // fp8 elements (bytes) per kv buffer
  for (int l = 0; l < 2; ++l) {
    // fused K|V|Q tag projection: [3000][2304] bf16
    gemmb(0, 1, h_tag_bf, EMB, 0, Wtag + (long long)l * 3 * WS, EMB, 0,
          tag_kvq, 2304, 0, 0, 0, b_kvq + l * 2304, nullptr, TLEN, 2304, EMB, 1);
    // question Q projection -> fp8
    gemmb(0, 2, h_q_bf, EMB, 0, qWT + (l * 2 + 1) * WS, EMB, 0,
          q_que, EMB, 0, 0, 0, qb + (l * 2 + 1) * EMB, nullptr, NQ, EMB, EMB, 1);
    // all 3 relations' K/V transforms in one z=24 batch -> fp8
    gemmb(0, 2, tag_kvq, 2304, 192, relWT + (long long)(l * 3) * 8 * RS, DKH, RS,
          kv_g, 1536, 192, KVZ, 1, nullptr, nullptr, TLEN, DKH, DKH, 24);
    // gathers (bf16 RMW into node state)
    gather_give<<<(QLEN * 64 + 255) / 256, 256, 0, stream>>>(
        q_que, kv_g, rp_g, adj_g, rel_pri + (l * 3 + 0) * NHEADS, h_q_bf);
    gather_inter<<<(TLEN * 64 + 255) / 256, 256, 0, stream>>>(
        tag_kvq, kv_1, kv_2, rp_1, adj_1, rp_2, adj_2,
        rel_pri + (l * 3 + 1) * NHEADS, rel_pri + (l * 3 + 2) * NHEADS,
        h_tag_bf);
  }

  // -------- outputs
  gemmb(2, 0, h_q_bf, EMB, 0, WoutT, EMB, 0, out, EMB, 0, 0, 0, bout, nullptr,
        NQ, EMB, EMB, 1);
  gemmb(0, 0, h_tag_bf, EMB, 0, WoutT, EMB, 0, out + (size_t)NQ * EMB, EMB, 0, 0, 0,
        bout, nullptr, TLEN, EMB, EMB, 1);
}

// Round 9
// 877.865 us; speedup vs baseline: 7.5494x; 1.0047x over previous
//
#include <hip/hip_runtime.h>

#define QLEN 10000
#define TLEN 3000
#define EMB 768
#define HNEED 3
#define NQ (QLEN * HNEED)
#define EG 100000
#define EI 100000
#define DKH 192
#define NHEADS 4

namespace {

typedef unsigned short u16;
typedef unsigned char u8;
typedef unsigned int u32;
typedef __attribute__((ext_vector_type(8))) short bf16x8;
typedef __attribute__((ext_vector_type(4))) float f32x4;
typedef __attribute__((ext_vector_type(2))) float f32x2;

constexpr float SCALE = 0.07216878364870322f; // 1/sqrt(192)

__device__ inline u16 f2bf(float f) {
  unsigned u = __float_as_uint(f);
  unsigned r = (u + 0x7FFFu + ((u >> 16) & 1u)) >> 16;  // RNE
  return (u16)r;
}
__device__ inline float bf2f(u16 h) {
  return __uint_as_float((unsigned)h << 16);
}
__device__ inline u8 f2fp8(float f) {
  u32 pk = __builtin_amdgcn_cvt_pk_fp8_f32(f, f, 0, false);
  return (u8)(pk & 0xFF);
}
// decode 12 fp8 (3 dwords) -> 12 floats
__device__ inline void decode12(const u32* p, float* o) {
#pragma unroll
  for (int t = 0; t < 3; ++t) {
    u32 w = p[t];
    f32x2 lo = __builtin_amdgcn_cvt_pk_f32_fp8(w, false);
    f32x2 hi = __builtin_amdgcn_cvt_pk_f32_fp8(w, true);
    o[t * 4 + 0] = lo[0]; o[t * 4 + 1] = lo[1];
    o[t * 4 + 2] = hi[0]; o[t * 4 + 3] = hi[1];
  }
}
__device__ inline f32x2 bfx2(u32 w) {
  f32x2 r;
  r[0] = __uint_as_float(w << 16);
  r[1] = __uint_as_float(w & 0xFFFF0000u);
  return r;
}

__device__ inline void gload_lds16(const u16* g, u16* s) {
  __builtin_amdgcn_global_load_lds(
      (const __attribute__((address_space(1))) unsigned*)g,
      (__attribute__((address_space(3))) unsigned*)s, 16, 0, 0);
}

// ------------------------------------------------------------ bf16 MFMA GEMM
// A [M][K] bf16 row-major, Bt [N][K] bf16 row-major (B transposed).
// 128x128 tile, BK=32, 3-stage pipelined LDS with COUNTED vmcnt across raw
// barriers (loads for tile t+1 stay in flight while computing tile t),
// XCD-chunked swizzle, LDS k-chunk swizzle, setprio around MFMA cluster.
// OUT: 0=f32, 1=bf16, 2=fp8.
// EPI 0: C[m][n]
// EPI 1: encoder: C_bf[(n/768)*QLEN + m][n%768] = bf16(v + bf2f(extra[m][n%768]))
// EPI 2: ques out: C[(m%QLEN)*3 + m/QLEN][n] = v (f32)
template <int EPI, int OUT>
__global__ __launch_bounds__(256) void gemm_bf16(
    const u16* __restrict__ A, int lda, long long sAz,
    const u16* __restrict__ Bt, int ldb, long long sBz,
    void* __restrict__ Cv, int ldc, long long sCz, long long sCz2, int relpack,
    const float* __restrict__ bias, const u16* __restrict__ extra,
    int M, int N, int K)
{
  __shared__ __align__(16) u16 As[3][4096];   // 24 KB
  __shared__ __align__(16) u16 Bs[3][4096];   // 24 KB
  const int z = blockIdx.z;
  float* Cf = (float*)Cv;
  u16* Ch = (u16*)Cv;
  u8* C8 = (u8*)Cv;
  if (relpack) {
    const int zr = z >> 3, zh = z & 7;
    A += (long long)zh * sAz;
    Bt += (long long)z * sBz;
    const long long co = (long long)zr * sCz2 + (long long)zh * sCz;
    Cf += co; Ch += co; C8 += co;
  } else {
    A += (long long)z * sAz;
    Bt += (long long)z * sBz;
    Cf += (long long)z * sCz;
    Ch += (long long)z * sCz;
    C8 += (long long)z * sCz;
  }
  // XCD-chunked bijective remap
  const int gx = gridDim.x;
  const int nwg = gx * gridDim.y;
  const int orig = blockIdx.y * gx + blockIdx.x;
  const int qq = nwg >> 3, rr = nwg & 7;
  const int xc = orig & 7, ix = orig >> 3;
  const int swz = (xc < rr ? xc * (qq + 1) : rr * (qq + 1) + (xc - rr) * qq) + ix;
  const int by = swz / gx, bx = swz - by * gx;
  const int bm = by * 128, bn = bx * 128;

  const int tid = threadIdx.x;
  const int w = tid >> 6, l = tid & 63;
  const int wr = w >> 1, wc = w & 1;
  const int l16 = l & 15, lk = l >> 4;
  const int srow = tid >> 2;
  const int scol = (((tid & 3) ^ ((srow >> 1) & 3))) * 8;  // pre-swizzled k-chunk
  const int rchunk = (lk ^ ((l16 >> 1) & 3));              // read-side inverse

  int r0 = bm + srow;      if (r0 > M - 1) r0 = M - 1;
  int r1 = bm + srow + 64; if (r1 > M - 1) r1 = M - 1;
  int c0 = bn + srow;      if (c0 > N - 1) c0 = N - 1;
  int c1 = bn + srow + 64; if (c1 > N - 1) c1 = N - 1;
  const u16* pa0 = A + (long long)r0 * lda + scol;
  const u16* pa1 = A + (long long)r1 * lda + scol;
  const u16* pb0 = Bt + (long long)c0 * ldb + scol;
  const u16* pb1 = Bt + (long long)c1 * ldb + scol;

  // per-lane fragment read offsets (within one buffer)
  int aoff[4], boff[4];
#pragma unroll
  for (int m = 0; m < 4; ++m) {
    aoff[m] = (wr * 64 + m * 16 + l16) * 32 + rchunk * 8;
    boff[m] = (wc * 64 + m * 16 + l16) * 32 + rchunk * 8;
  }

  f32x4 acc[4][4] = {};
  const int nt = K / 32;

  auto stage = [&](int buf, int k0) {
    gload_lds16(pa0 + k0, &As[buf][w * 512]);
    gload_lds16(pa1 + k0, &As[buf][w * 512 + 2048]);
    gload_lds16(pb0 + k0, &Bs[buf][w * 512]);
    gload_lds16(pb1 + k0, &Bs[buf][w * 512 + 2048]);
  };

  // prologue: tiles 0 and 1 in flight (4 loads each)
  stage(0, 0);
  stage(1, 32);
  int cur = 0, sb = 2;
  for (int t = 0; t < nt; ++t) {
    // wait for tile t's 4 loads; keep tile t+1's in flight (except last iter)
    if (t < nt - 1)
      asm volatile("s_waitcnt vmcnt(4)" ::: "memory");
    else
      asm volatile("s_waitcnt vmcnt(0)" ::: "memory");
    __builtin_amdgcn_s_barrier();          // tile t fully in LDS, all waves
    __builtin_amdgcn_sched_barrier(0);     // no hoisting across the barrier
    if (t + 2 < nt) {                      // issue tile t+2 into freed buffer
      stage(sb, (t + 2) * 32);
      if (++sb == 3) sb = 0;
    }
    bf16x8 af[4], bf[4];
#pragma unroll
    for (int m = 0; m < 4; ++m)
      af[m] = *(const bf16x8*)&As[cur][aoff[m]];
#pragma unroll
    for (int n = 0; n < 4; ++n)
      bf[n] = *(const bf16x8*)&Bs[cur][boff[n]];
    __builtin_amdgcn_s_setprio(1);
#pragma unroll
    for (int m = 0; m < 4; ++m)
#pragma unroll
      for (int n = 0; n < 4; ++n)
        acc[m][n] = __builtin_amdgcn_mfma_f32_16x16x32_bf16(af[m], bf[n], acc[m][n], 0, 0, 0);
    __builtin_amdgcn_s_setprio(0);
    if (++cur == 3) cur = 0;
  }

#pragma unroll
  for (int m = 0; m < 4; ++m) {
#pragma unroll
    for (int j = 0; j < 4; ++j) {
      int grow = bm + wr * 64 + m * 16 + lk * 4 + j;
      if (grow >= M) continue;
#pragma unroll
      for (int n = 0; n < 4; ++n) {
        int gcol = bn + wc * 64 + n * 16 + l16;
        if (gcol >= N) continue;
        float val = acc[m][n][j] + (bias ? bias[gcol] : 0.f);
        if (EPI == 0) {
          if (OUT == 0)
            Cf[(long long)grow * ldc + gcol] = val;
          else if (OUT == 1)
            Ch[(long long)grow * ldc + gcol] = f2bf(val);
          else
            C8[(long long)grow * ldc + gcol] = f2fp8(val);
        } else if (EPI == 1) {
          int h = gcol / EMB, c = gcol - h * EMB;
          Ch[((long long)h * QLEN + grow) * EMB + c] =
              f2bf(val + bf2f(extra[(long long)grow * EMB + c]));
        } else {
          int i2 = grow % QLEN, h = grow / QLEN;
          Cf[((long long)i2 * HNEED + h) * EMB + gcol] = val;
        }
      }
    }
  }
}

// ------------------------------------------------------ conversion / transpose
__global__ void f2bf_kernel(const float* __restrict__ in, u16* __restrict__ out, long long n)
{
  long long i = ((long long)blockIdx.x * 256 + threadIdx.x) * 4;
  if (i >= n) return;
  float4 v = *(const float4*)(in + i);
  ushort4 o;
  o.x = f2bf(v.x); o.y = f2bf(v.y); o.z = f2bf(v.z); o.w = f2bf(v.w);
  *(ushort4*)(out + i) = o;
}

// out z-slot = (z/G)*OG + z%G ; out[slot][c][r] = bf16(in[z][r][c])
__global__ __launch_bounds__(256) void transpose_bf(
    const float* __restrict__ in, u16* __restrict__ out, int R, int C, int G, int OG)
{
  __shared__ float t[32][33];
  const int z = blockIdx.z;
  in += (long long)z * R * C;
  out += (long long)((z / G) * OG + (z % G)) * R * C;
  const int c0 = blockIdx.x * 32, r0 = blockIdx.y * 32;
  const int tx = threadIdx.x & 31, ty = threadIdx.x >> 5;  // 32 x 8
  for (int i = 0; i < 32; i += 8) {
    int r = r0 + ty + i, c = c0 + tx;
    t[ty + i][tx] = (r < R && c < C) ? in[(long long)r * C + c] : 0.f;
  }
  __syncthreads();
  for (int i = 0; i < 32; i += 8) {
    int c = c0 + ty + i, r = r0 + tx;
    if (c < C && r < R) out[(long long)c * R + r] = f2bf(t[tx][ty + i]);
  }
}

// ---------------------------------------------------- small packing kernels
__global__ void pack_wct_kernel(const float* __restrict__ Wc, float* __restrict__ WcT)
{
  int idx = blockIdx.x * 256 + threadIdx.x;
  if (idx >= 7680) return;
  int j = idx / EMB, d = idx - j * EMB;
  WcT[idx] = Wc[d * 10 + j];
}

__global__ void pack_bias_kernel(const float* __restrict__ kb, const float* __restrict__ vb,
                                 const float* __restrict__ qb, float* __restrict__ o)
{
  int idx = blockIdx.x * 256 + threadIdx.x;
  if (idx >= 2 * 2304) return;
  int l = idx / 2304, c = idx - l * 2304;
  float v;
  if (c < 768) v = kb[(l * 2) * EMB + c];
  else if (c < 1536) v = vb[(l * 2) * EMB + c - 768];
  else v = qb[(l * 2) * EMB + c - 1536];
  o[idx] = v;
}

// --------------------------------------------- fused assign-softmax + centers
__global__ __launch_bounds__(512) void assign_center512(
    u16* __restrict__ qh_bf,
    const float* __restrict__ WcT, const float* __restrict__ bc,
    const float* __restrict__ centers)
{
  __shared__ float wc_s[7680];
  __shared__ float cen_s[7680];
  const int tid = threadIdx.x;
  for (int i = tid; i < 7680; i += 512) {
    wc_s[i] = WcT[i];
    cen_s[i] = centers[i];
  }
  __syncthreads();
  const int wave = tid >> 6, lane = tid & 63;
  const int row = blockIdx.x * 8 + wave;   // NQ = 30000 = 3750*8 exact
  const long long base = (long long)row * EMB;
  float x[12];
#pragma unroll
  for (int i = 0; i < 12; ++i) x[i] = bf2f(qh_bf[base + lane + 64 * i]);
  float part[10] = {};
#pragma unroll
  for (int i = 0; i < 12; ++i) {
    const float v = x[i];
    const int d = lane + 64 * i;
#pragma unroll
    for (int j = 0; j < 10; ++j) part[j] = fmaf(v, wc_s[j * EMB + d], part[j]);
  }
#pragma unroll
  for (int j = 0; j < 10; ++j)
#pragma unroll
    for (int off = 32; off; off >>= 1) part[j] += __shfl_xor(part[j], off);
  float mx = -1e30f;
#pragma unroll
  for (int j = 0; j < 10; ++j) { part[j] += bc[j]; mx = fmaxf(mx, part[j]); }
  float s = 0.f;
#pragma unroll
  for (int j = 0; j < 10; ++j) { part[j] = __expf(part[j] - mx); s += part[j]; }
  const float inv = 1.f / s;
#pragma unroll
  for (int i = 0; i < 12; ++i) {
    const int d = lane + 64 * i;
    float acc = 0.f;
#pragma unroll
    for (int j = 0; j < 10; ++j) acc = fmaf(part[j], cen_s[j * EMB + d], acc);
    qh_bf[base + d] = f2bf(x[i] + acc * inv);
  }
}

// ------------------------------------------------------------- CSR build
__global__ void hist_kernel(const int* __restrict__ dst, int* __restrict__ cnt, int E)
{
  int e = blockIdx.x * 256 + threadIdx.x;
  if (e < E) atomicAdd(&cnt[dst[e]], 1);
}

__global__ __launch_bounds__(1024) void scan_fill_kernel(
    const int* __restrict__ cnt, int* __restrict__ rowptr, int* __restrict__ cur, int n)
{
  __shared__ int buf[1024];
  const int tid = threadIdx.x;
  const int chunk = (n + 1023) >> 10;
  const int base = tid * chunk;
  int s = 0;
  for (int i = 0; i < chunk; ++i) {
    int idx = base + i;
    if (idx < n) s += cnt[idx];
  }
  buf[tid] = s;
  __syncthreads();
  for (int off = 1; off < 1024; off <<= 1) {
    int v = (tid >= off) ? buf[tid - off] : 0;
    __syncthreads();
    buf[tid] += v;
    __syncthreads();
  }
  int run = (tid == 0) ? 0 : buf[tid - 1];
  for (int i = 0; i < chunk; ++i) {
    int idx = base + i;
    if (idx < n) {
      rowptr[idx] = run;
      cur[idx] = run;
      run += cnt[idx];
    }
  }
  if (tid == 1023) rowptr[n] = buf[1023];
}

__global__ void fill_kernel(const int* __restrict__ src, const int* __restrict__ dst,
                            int* __restrict__ cur, int* __restrict__ adj, int E)
{
  int e = blockIdx.x * 256 + threadIdx.x;
  if (e < E) {
    int p = atomicAdd(&cur[dst[e]], 1);
    adj[p] = src[e];
  }
}

// ------------- give gather: one wave per dst, all 4 heads, fp8 K/V/Q, 3 copies
__global__ __launch_bounds__(256) void gather_give(
    const u8* __restrict__ q, const u8* __restrict__ kv,
    const int* __restrict__ rowptr, const int* __restrict__ adj,
    const float* __restrict__ rpri, u16* __restrict__ hq_bf)
{
  const int d = (blockIdx.x * 256 + threadIdx.x) >> 6;
  const int lane = threadIdx.x & 63;
  if (d >= QLEN) return;
  const int rs = rowptr[d], re = rowptr[d + 1];
  if (rs == re) return;  // no in-edges: rows keep residual
  const int h = lane >> 4, sub = lane & 15;
  const int off = h * DKH + sub * 12;
  const float pri = rpri[h] * SCALE;

  float qv[3][12];
#pragma unroll
  for (int c = 0; c < 3; ++c)
    decode12((const u32*)(q + (size_t)(c * QLEN + d) * EMB + off), qv[c]);

  float S[3] = {0.f, 0.f, 0.f};
  float A[3][12] = {};

  auto edge = [&](int sn) {
    float kf[12], vf[12];
    decode12((const u32*)(kv + (size_t)sn * 1536 + off), kf);
    decode12((const u32*)(kv + (size_t)sn * 1536 + 768 + off), vf);
    float dt[3] = {0.f, 0.f, 0.f};
#pragma unroll
    for (int t = 0; t < 12; ++t) {
#pragma unroll
      for (int c = 0; c < 3; ++c) dt[c] = fmaf(qv[c][t], kf[t], dt[c]);
    }
#pragma unroll
    for (int c = 0; c < 3; ++c) {
#pragma unroll
      for (int o2 = 8; o2; o2 >>= 1) dt[c] += __shfl_xor(dt[c], o2);
      const float e = __expf(dt[c] * pri);
      S[c] += e;
#pragma unroll
      for (int t = 0; t < 12; ++t) A[c][t] = fmaf(e, vf[t], A[c][t]);
    }
  };
  int i = rs;
  for (; i + 1 < re; i += 2) { edge(adj[i]); edge(adj[i + 1]); }
  if (i < re) edge(adj[i]);

#pragma unroll
  for (int c = 0; c < 3; ++c) {
    const float inv = 1.f / S[c];
    u32* o = (u32*)(hq_bf + (size_t)(c * QLEN + d) * EMB + off);
#pragma unroll
    for (int t = 0; t < 6; ++t) {
      f32x2 r = bfx2(o[t]);
      r[0] += A[c][2 * t] * inv;
      r[1] += A[c][2 * t + 1] * inv;
      o[t] = (u32)f2bf(r[0]) | ((u32)f2bf(r[1]) << 16);
    }
  }
}

// ---- merged inter gather: one wave per dst, all 4 heads, both relations
__global__ __launch_bounds__(256) void gather_inter(
    const u16* __restrict__ tag_kvq,   // bf16, q at col 1536
    const u8* __restrict__ kv1, const u8* __restrict__ kv2,
    const int* __restrict__ rp1, const int* __restrict__ adj1,
    const int* __restrict__ rp2, const int* __restrict__ adj2,
    const float* __restrict__ pri1, const float* __restrict__ pri2,
    u16* __restrict__ htag_bf)
{
  const int d = (blockIdx.x * 256 + threadIdx.x) >> 6;
  const int lane = threadIdx.x & 63;
  if (d >= TLEN) return;
  const int rs1 = rp1[d], re1 = rp1[d + 1];
  const int rs2 = rp2[d], re2 = rp2[d + 1];
  if (rs1 == re1 && rs2 == re2) return;
  const int h = lane >> 4, sub = lane & 15;
  const int off = h * DKH + sub * 12;
  float qv[12];
  {
    const u32* qp = (const u32*)(tag_kvq + (size_t)d * 2304 + 1536 + off);
#pragma unroll
    for (int t = 0; t < 6; ++t) {
      f32x2 r = bfx2(qp[t]);
      qv[2 * t] = r[0]; qv[2 * t + 1] = r[1];
    }
  }
  float R[12] = {};
#pragma unroll
  for (int rel = 0; rel < 2; ++rel) {
    const u8* kv = rel ? kv2 : kv1;
    const int rs = rel ? rs2 : rs1, re = rel ? re2 : re1;
    const int* adj = rel ? adj2 : adj1;
    if (rs == re) continue;
    const float pri = (rel ? pri2[h] : pri1[h]) * SCALE;
    float S = 0.f, A[12] = {};
    auto edge = [&](int sn) {
      float kf[12], vf[12];
      decode12((const u32*)(kv + (size_t)sn * 1536 + off), kf);
      decode12((const u32*)(kv + (size_t)sn * 1536 + 768 + off), vf);
      float dt = 0.f;
#pragma unroll
      for (int t = 0; t < 12; ++t) dt = fmaf(qv[t], kf[t], dt);
#pragma unroll
      for (int o2 = 8; o2; o2 >>= 1) dt += __shfl_xor(dt, o2);
      const float e = __expf(dt * pri);
      S += e;
#pragma unroll
      for (int t = 0; t < 12; ++t) A[t] = fmaf(e, vf[t], A[t]);
    };
    int i = rs;
    for (; i + 1 < re; i += 2) { edge(adj[i]); edge(adj[i + 1]); }
    if (i < re) edge(adj[i]);
    const float inv = 0.5f / S;
#pragma unroll
    for (int t = 0; t < 12; ++t) R[t] = fmaf(A[t], inv, R[t]);
  }
  u32* o = (u32*)(htag_bf + (size_t)d * EMB + off);
#pragma unroll
  for (int t = 0; t < 6; ++t) {
    f32x2 r = bfx2(o[t]);
    r[0] += R[2 * t];
    r[1] += R[2 * t + 1];
    o[t] = (u32)f2bf(r[0]) | ((u32)f2bf(r[1]) << 16);
  }
}

}  // namespace

extern "C" void kernel_launch(void* const* d_in, const int* in_sizes, int n_in,
                              void* d_out, int out_size, void* d_ws, size_t ws_size,
                              hipStream_t stream)
{
  const float* q_emb   = (const float*)d_in[0];
  const float* t_emb   = (const float*)d_in[1];
  const int*   give_src = (const int*)d_in[2];
  const int*   give_dst = (const int*)d_in[3];
  const int*   i1_src  = (const int*)d_in[4];
  const int*   i1_dst  = (const int*)d_in[5];
  const int*   i2_src  = (const int*)d_in[6];
  const int*   i2_dst  = (const int*)d_in[7];
  const float* Wq_enc  = (const float*)d_in[8];
  const float* bq_enc  = (const float*)d_in[9];
  const float* Wc      = (const float*)d_in[10];
  const float* bc      = (const float*)d_in[11];
  const float* centers = (const float*)d_in[12];
  const float* kW      = (const float*)d_in[13];
  const float* kb      = (const float*)d_in[14];
  const float* qW      = (const float*)d_in[15];
  const float* qb      = (const float*)d_in[16];
  const float* vW      = (const float*)d_in[17];
  const float* vb      = (const float*)d_in[18];
  const float* rel_att = (const float*)d_in[19];
  const float* rel_msg = (const float*)d_in[20];
  const float* rel_pri = (const float*)d_in[21];
  const float* Wout    = (const float*)d_in[22];
  const float* bout    = (const float*)d_in[23];
  float* out = (float*)d_out;

  const long long WS = (long long)EMB * EMB;   // 589824
  const long long RS = (long long)DKH * DKH;   // 36864

  // -------- workspace carve-up (bf16 node state, fp8 gather operands)
  float* p = (float*)d_ws;
  auto take = [&](size_t n) { float* r = p; p += ((n + 3) & ~(size_t)3); return r; };
  u16* h_q_bf    = (u16*)take((size_t)NQ * EMB / 2);
  u16* h_tag_bf  = (u16*)take((size_t)TLEN * EMB / 2);
  u16* q_emb_bf  = (u16*)take((size_t)QLEN * EMB / 2);
  u16* tag_kvq   = (u16*)take((size_t)TLEN * 2304 / 2);
  u8* kv_all     = (u8*)take((size_t)3 * TLEN * 1536 / 4);  // fp8: 3 x 4.6MB
  u8* kv_g = kv_all;
  u8* kv_1 = kv_all + (size_t)TLEN * 1536;
  u8* kv_2 = kv_all + (size_t)2 * TLEN * 1536;
  u16* WqT   = (u16*)take((size_t)EMB * EMB * HNEED / 2);
  u16* qWT   = (u16*)take((size_t)4 * WS / 2);
  u16* Wtag  = (u16*)take((size_t)2 * 3 * WS / 2);   // [l][2304][768]
  u16* WoutT = (u16*)take((size_t)WS / 2);
  u16* relWT = (u16*)take((size_t)48 * RS / 2);      // [l*3+r][8][192][192]
  float* WcT   = take(7680);
  float* b_kvq = take(2 * 2304);
  int* rp_g  = (int*)take(QLEN + 1);
  int* rp_1  = (int*)take(TLEN + 1);
  int* rp_2  = (int*)take(TLEN + 1);
  int* cur_g = (int*)take(QLEN);
  int* cur_1 = (int*)take(TLEN);
  int* cur_2 = (int*)take(TLEN);
  int* adj_g = (int*)take(EG);
  int* adj_1 = (int*)take(EI);
  int* adj_2 = (int*)take(EI);
  int* cnt   = (int*)take(QLEN);
  u8* q_que = (u8*)out;          // d_out as scratch (fp8, 23MB); overwritten at end

  auto gemmb = [&](int EPI, int OUT, const u16* A, int lda, long long sAz,
                   const u16* Bt, int ldb, long long sBz,
                   void* C, int ldc, long long sCz, long long sCz2, int relpack,
                   const float* bias, const u16* extra,
                   int M, int N, int K, int batch) {
    dim3 grid((N + 127) / 128, (M + 127) / 128, batch);
    if (EPI == 0 && OUT == 0)
      gemm_bf16<0, 0><<<grid, 256, 0, stream>>>(A, lda, sAz, Bt, ldb, sBz, C, ldc, sCz, sCz2, relpack, bias, extra, M, N, K);
    else if (EPI == 0 && OUT == 1)
      gemm_bf16<0, 1><<<grid, 256, 0, stream>>>(A, lda, sAz, Bt, ldb, sBz, C, ldc, sCz, sCz2, relpack, bias, extra, M, N, K);
    else if (EPI == 0 && OUT == 2)
      gemm_bf16<0, 2><<<grid, 256, 0, stream>>>(A, lda, sAz, Bt, ldb, sBz, C, ldc, sCz, sCz2, relpack, bias, extra, M, N, K);
    else if (EPI == 1)
      gemm_bf16<1, 1><<<grid, 256, 0, stream>>>(A, lda, sAz, Bt, ldb, sBz, C, ldc, sCz, sCz2, relpack, bias, extra, M, N, K);
    else
      gemm_bf16<2, 0><<<grid, 256, 0, stream>>>(A, lda, sAz, Bt, ldb, sBz, C, ldc, sCz, sCz2, relpack, bias, extra, M, N, K);
  };

  // -------- CSR builds (static graphs)
  auto build_csr = [&](const int* src, const int* dst, int E, int n,
                       int* rp, int* cu, int* adj) {
    hipMemsetAsync(cnt, 0, (size_t)n * sizeof(int), stream);
    hist_kernel<<<(E + 255) / 256, 256, 0, stream>>>(dst, cnt, E);
    scan_fill_kernel<<<1, 1024, 0, stream>>>(cnt, rp, cu, n);
    fill_kernel<<<(E + 255) / 256, 256, 0, stream>>>(src, dst, cu, adj, E);
  };
  build_csr(give_src, give_dst, EG, QLEN, rp_g, cur_g, adj_g);
  build_csr(i1_src, i1_dst, EI, TLEN, rp_1, cur_1, adj_1);
  build_csr(i2_src, i2_dst, EI, TLEN, rp_2, cur_2, adj_2);

  // -------- one-time packs / transposes
  pack_wct_kernel<<<30, 256, 0, stream>>>(Wc, WcT);
  pack_bias_kernel<<<18, 256, 0, stream>>>(kb, vb, qb, b_kvq);
  transpose_bf<<<dim3(EMB * HNEED / 32, EMB / 32, 1), 256, 0, stream>>>(Wq_enc, WqT, EMB, EMB * HNEED, 1, 1);
  transpose_bf<<<dim3(EMB / 32, EMB / 32, 4), 256, 0, stream>>>(qW, qWT, EMB, EMB, 1, 1);
  for (int l = 0; l < 2; ++l) {
    transpose_bf<<<dim3(EMB / 32, EMB / 32, 1), 256, 0, stream>>>(kW + (l * 2) * WS, Wtag + (l * 3 + 0) * WS, EMB, EMB, 1, 1);
    transpose_bf<<<dim3(EMB / 32, EMB / 32, 1), 256, 0, stream>>>(vW + (l * 2) * WS, Wtag + (l * 3 + 1) * WS, EMB, EMB, 1, 1);
    transpose_bf<<<dim3(EMB / 32, EMB / 32, 1), 256, 0, stream>>>(qW + (l * 2) * WS, Wtag + (l * 3 + 2) * WS, EMB, EMB, 1, 1);
  }
  transpose_bf<<<dim3(EMB / 32, EMB / 32, 1), 256, 0, stream>>>(Wout, WoutT, EMB, EMB, 1, 1);
  transpose_bf<<<dim3(DKH / 32, DKH / 32, 24), 256, 0, stream>>>(rel_att, relWT, DKH, DKH, 4, 8);
  transpose_bf<<<dim3(DKH / 32, DKH / 32, 24), 256, 0, stream>>>(rel_msg, relWT + 4 * RS, DKH, DKH, 4, 8);

  // -------- question encoder + clustering (bf16 state)
  f2bf_kernel<<<(QLEN * EMB / 4 + 255) / 256, 256, 0, stream>>>(q_emb, q_emb_bf, (long long)QLEN * EMB);
  gemmb(1, 1, q_emb_bf, EMB, 0, WqT, EMB, 0, h_q_bf, EMB, 0, 0, 0, bq_enc, q_emb_bf,
        QLEN, EMB * HNEED, EMB, 1);
  assign_center512<<<NQ / 8, 512, 0, stream>>>(h_q_bf, WcT, bc, centers);
  f2bf_kernel<<<(TLEN * EMB / 4 + 255) / 256, 256, 0, stream>>>(t_emb, h_tag_bf, (long long)TLEN * EMB);

  const long long KVZ = (long long)TLEN * 1536;   // fp8 bytes per kv buffer
  for (int l = 0; l < 2; ++l) {
    // fused K|V|Q tag projection: [3000][2304] bf16
    gemmb(0, 1, h_tag_bf, EMB, 0, Wtag + (long long)l * 3 * WS, EMB, 0,
          tag_kvq, 2304, 0, 0, 0, b_kvq + l * 2304, nullptr, TLEN, 2304, EMB, 1);
    // question Q projection -> fp8
    gemmb(0, 2, h_q_bf, EMB, 0, qWT + (l * 2 + 1) * WS, EMB, 0,
          q_que, EMB, 0, 0, 0, qb + (l * 2 + 1) * EMB, nullptr, NQ, EMB, EMB, 1);
    // all 3 relations' K/V transforms in one z=24 batch -> fp8
    gemmb(0, 2, tag_kvq, 2304, 192, relWT + (long long)(l * 3) * 8 * RS, DKH, RS,
          kv_g, 1536, 192, KVZ, 1, nullptr, nullptr, TLEN, DKH, DKH, 24);
    // gathers (bf16 RMW into node state)
    gather_give<<<(QLEN * 64 + 255) / 256, 256, 0, stream>>>(
        q_que, kv_g, rp_g, adj_g, rel_pri + (l * 3 + 0) * NHEADS, h_q_bf);
    gather_inter<<<(TLEN * 64 + 255) / 256, 256, 0, stream>>>(
        tag_kvq, kv_1, kv_2, rp_1, adj_1, rp_2, adj_2,
        rel_pri + (l * 3 + 1) * NHEADS, rel_pri + (l * 3 + 2) * NHEADS,
        h_tag_bf);
  }

  // -------- outputs
  gemmb(2, 0, h_q_bf, EMB, 0, WoutT, EMB, 0, out, EMB, 0, 0, 0, bout, nullptr,
        NQ, EMB, EMB, 1);
  gemmb(0, 0, h_tag_bf, EMB, 0, WoutT, EMB, 0, out + (size_t)NQ * EMB, EMB, 0, 0, 0,
        bout, nullptr, TLEN, EMB, EMB, 1);
}

// Round 10
// 807.909 us; speedup vs baseline: 8.2031x; 1.0866x over previous
//
#include <hip/hip_runtime.h>

#define QLEN 10000
#define TLEN 3000
#define EMB 768
#define HNEED 3
#define NQ (QLEN * HNEED)
#define EG 100000
#define EI 100000
#define DKH 192
#define NHEADS 4

namespace {

typedef unsigned short u16;
typedef unsigned char u8;
typedef unsigned int u32;
typedef __attribute__((ext_vector_type(8))) short bf16x8;
typedef __attribute__((ext_vector_type(4))) float f32x4;
typedef __attribute__((ext_vector_type(2))) float f32x2;

constexpr float SCALE = 0.07216878364870322f; // 1/sqrt(192)

__device__ inline u16 f2bf(float f) {
  unsigned u = __float_as_uint(f);
  unsigned r = (u + 0x7FFFu + ((u >> 16) & 1u)) >> 16;  // RNE
  return (u16)r;
}
__device__ inline float bf2f(u16 h) {
  return __uint_as_float((unsigned)h << 16);
}
__device__ inline u8 f2fp8(float f) {
  u32 pk = __builtin_amdgcn_cvt_pk_fp8_f32(f, f, 0, false);
  return (u8)(pk & 0xFF);
}
// decode 12 fp8 (3 dwords) -> 12 floats
__device__ inline void decode12(const u32* p, float* o) {
#pragma unroll
  for (int t = 0; t < 3; ++t) {
    u32 w = p[t];
    f32x2 lo = __builtin_amdgcn_cvt_pk_f32_fp8(w, false);
    f32x2 hi = __builtin_amdgcn_cvt_pk_f32_fp8(w, true);
    o[t * 4 + 0] = lo[0]; o[t * 4 + 1] = lo[1];
    o[t * 4 + 2] = hi[0]; o[t * 4 + 3] = hi[1];
  }
}
__device__ inline f32x2 bfx2(u32 w) {
  f32x2 r;
  r[0] = __uint_as_float(w << 16);
  r[1] = __uint_as_float(w & 0xFFFF0000u);
  return r;
}

__device__ inline void gload_lds16(const u16* g, u16* s) {
  __builtin_amdgcn_global_load_lds(
      (const __attribute__((address_space(1))) unsigned*)g,
      (__attribute__((address_space(3))) unsigned*)s, 16, 0, 0);
}

// ------------------------------------------------------------ bf16 MFMA GEMM
// A [M][K] bf16 row-major, Bt [N][K] bf16 row-major.
// 128x128 tile, BK=32, 3-stage pipelined LDS, counted vmcnt, XCD swizzle,
// LDS k-chunk swizzle, setprio around MFMA. OUT: 0=f32, 1=bf16, 2=fp8.
// EPI 0: C[m][n]
// EPI 1: encoder: C_bf[(n/768)*QLEN + m][n%768] = bf16(v + bf2f(extra[m][n%768]))
// EPI 2: merged output: grow<NQ -> Cf[((grow%QLEN)*3+grow/QLEN)*768+n];
//        else Cf[grow*768+n]   (tags region starts at NQ*768)
template <int EPI, int OUT>
__global__ __launch_bounds__(256) void gemm_bf16(
    const u16* __restrict__ A, int lda, long long sAz,
    const u16* __restrict__ Bt, int ldb, long long sBz,
    void* __restrict__ Cv, int ldc, long long sCz, long long sCz2, int relpack,
    const float* __restrict__ bias, const u16* __restrict__ extra,
    int M, int N, int K)
{
  __shared__ __align__(16) u16 As[3][4096];
  __shared__ __align__(16) u16 Bs[3][4096];
  const int z = blockIdx.z;
  float* Cf = (float*)Cv;
  u16* Ch = (u16*)Cv;
  u8* C8 = (u8*)Cv;
  if (relpack) {
    const int zr = z >> 3, zh = z & 7;
    A += (long long)zh * sAz;
    Bt += (long long)z * sBz;
    const long long co = (long long)zr * sCz2 + (long long)zh * sCz;
    Cf += co; Ch += co; C8 += co;
  } else {
    A += (long long)z * sAz;
    Bt += (long long)z * sBz;
    Cf += (long long)z * sCz;
    Ch += (long long)z * sCz;
    C8 += (long long)z * sCz;
  }
  // XCD-chunked bijective remap
  const int gx = gridDim.x;
  const int nwg = gx * gridDim.y;
  const int orig = blockIdx.y * gx + blockIdx.x;
  const int qq = nwg >> 3, rr = nwg & 7;
  const int xc = orig & 7, ix = orig >> 3;
  const int swz = (xc < rr ? xc * (qq + 1) : rr * (qq + 1) + (xc - rr) * qq) + ix;
  const int by = swz / gx, bx = swz - by * gx;
  const int bm = by * 128, bn = bx * 128;

  const int tid = threadIdx.x;
  const int w = tid >> 6, l = tid & 63;
  const int wr = w >> 1, wc = w & 1;
  const int l16 = l & 15, lk = l >> 4;
  const int srow = tid >> 2;
  const int scol = (((tid & 3) ^ ((srow >> 1) & 3))) * 8;
  const int rchunk = (lk ^ ((l16 >> 1) & 3));

  int r0 = bm + srow;      if (r0 > M - 1) r0 = M - 1;
  int r1 = bm + srow + 64; if (r1 > M - 1) r1 = M - 1;
  int c0 = bn + srow;      if (c0 > N - 1) c0 = N - 1;
  int c1 = bn + srow + 64; if (c1 > N - 1) c1 = N - 1;
  const u16* pa0 = A + (long long)r0 * lda + scol;
  const u16* pa1 = A + (long long)r1 * lda + scol;
  const u16* pb0 = Bt + (long long)c0 * ldb + scol;
  const u16* pb1 = Bt + (long long)c1 * ldb + scol;

  int aoff[4], boff[4];
#pragma unroll
  for (int m = 0; m < 4; ++m) {
    aoff[m] = (wr * 64 + m * 16 + l16) * 32 + rchunk * 8;
    boff[m] = (wc * 64 + m * 16 + l16) * 32 + rchunk * 8;
  }

  f32x4 acc[4][4] = {};
  const int nt = K / 32;

  auto stage = [&](int buf, int k0) {
    gload_lds16(pa0 + k0, &As[buf][w * 512]);
    gload_lds16(pa1 + k0, &As[buf][w * 512 + 2048]);
    gload_lds16(pb0 + k0, &Bs[buf][w * 512]);
    gload_lds16(pb1 + k0, &Bs[buf][w * 512 + 2048]);
  };

  stage(0, 0);
  stage(1, 32);
  int cur = 0, sb = 2;
  for (int t = 0; t < nt; ++t) {
    if (t < nt - 1)
      asm volatile("s_waitcnt vmcnt(4)" ::: "memory");
    else
      asm volatile("s_waitcnt vmcnt(0)" ::: "memory");
    __builtin_amdgcn_s_barrier();
    __builtin_amdgcn_sched_barrier(0);
    if (t + 2 < nt) {
      stage(sb, (t + 2) * 32);
      if (++sb == 3) sb = 0;
    }
    bf16x8 af[4], bf[4];
#pragma unroll
    for (int m = 0; m < 4; ++m)
      af[m] = *(const bf16x8*)&As[cur][aoff[m]];
#pragma unroll
    for (int n = 0; n < 4; ++n)
      bf[n] = *(const bf16x8*)&Bs[cur][boff[n]];
    __builtin_amdgcn_s_setprio(1);
#pragma unroll
    for (int m = 0; m < 4; ++m)
#pragma unroll
      for (int n = 0; n < 4; ++n)
        acc[m][n] = __builtin_amdgcn_mfma_f32_16x16x32_bf16(af[m], bf[n], acc[m][n], 0, 0, 0);
    __builtin_amdgcn_s_setprio(0);
    if (++cur == 3) cur = 0;
  }

#pragma unroll
  for (int m = 0; m < 4; ++m) {
#pragma unroll
    for (int j = 0; j < 4; ++j) {
      int grow = bm + wr * 64 + m * 16 + lk * 4 + j;
      if (grow >= M) continue;
#pragma unroll
      for (int n = 0; n < 4; ++n) {
        int gcol = bn + wc * 64 + n * 16 + l16;
        if (gcol >= N) continue;
        float val = acc[m][n][j] + (bias ? bias[gcol] : 0.f);
        if (EPI == 0) {
          if (OUT == 0)
            Cf[(long long)grow * ldc + gcol] = val;
          else if (OUT == 1)
            Ch[(long long)grow * ldc + gcol] = f2bf(val);
          else
            C8[(long long)grow * ldc + gcol] = f2fp8(val);
        } else if (EPI == 1) {
          int h = gcol / EMB, c = gcol - h * EMB;
          Ch[((long long)h * QLEN + grow) * EMB + c] =
              f2bf(val + bf2f(extra[(long long)grow * EMB + c]));
        } else {
          if (grow < NQ) {
            int i2 = grow % QLEN, h = grow / QLEN;
            Cf[((long long)i2 * HNEED + h) * EMB + gcol] = val;
          } else {
            Cf[(long long)grow * EMB + gcol] = val;
          }
        }
      }
    }
  }
}

// ------------------------------------------------------ conversion kernels
__global__ void f2bf_kernel(const float* __restrict__ in, u16* __restrict__ out, long long n)
{
  long long i = ((long long)blockIdx.x * 256 + threadIdx.x) * 4;
  if (i >= n) return;
  float4 v = *(const float4*)(in + i);
  ushort4 o;
  o.x = f2bf(v.x); o.y = f2bf(v.y); o.z = f2bf(v.z); o.w = f2bf(v.w);
  *(ushort4*)(out + i) = o;
}

// -------- batched 768x768 transposes (12 jobs, one launch) ----------------
struct T12 {
  const float* s[12];   // src (row 0, col 0 of a 768x768 region)
  u16* d[12];           // dst [768][768] bf16 row-major (transposed)
  int ld[12];           // src row stride
};

__global__ __launch_bounds__(256) void transpose768(T12 jobs)
{
  const int z = blockIdx.z;
  const float* in = jobs.s[z];
  const long long ld = jobs.ld[z];
  u16* out = jobs.d[z];
  __shared__ float t[32][33];
  const int c0 = blockIdx.x * 32, r0 = blockIdx.y * 32;
  const int tx = threadIdx.x & 31, ty = threadIdx.x >> 5;
#pragma unroll
  for (int i = 0; i < 32; i += 8)
    t[ty + i][tx] = in[(long long)(r0 + ty + i) * ld + c0 + tx];
  __syncthreads();
#pragma unroll
  for (int i = 0; i < 32; i += 8)
    out[(long long)(c0 + ty + i) * 768 + r0 + tx] = f2bf(t[tx][ty + i]);
}

// -------- rel weight transpose: z<24 att -> slot lr*8+h ; z>=24 msg -> +4
__global__ __launch_bounds__(256) void transpose_rel(
    const float* __restrict__ att, const float* __restrict__ msg,
    u16* __restrict__ relWT)
{
  const int z = blockIdx.z;
  const int isMsg = z >= 24;
  const int zz = isMsg ? z - 24 : z;
  const int lr = zz >> 2, h = zz & 3;
  const long long RS = (long long)DKH * DKH;
  const float* in = (isMsg ? msg : att) + (long long)zz * RS;
  u16* out = relWT + (long long)(lr * 8 + isMsg * 4 + h) * RS;
  __shared__ float t[32][33];
  const int c0 = blockIdx.x * 32, r0 = blockIdx.y * 32;
  const int tx = threadIdx.x & 31, ty = threadIdx.x >> 5;
#pragma unroll
  for (int i = 0; i < 32; i += 8)
    t[ty + i][tx] = in[(long long)(r0 + ty + i) * DKH + c0 + tx];
  __syncthreads();
#pragma unroll
  for (int i = 0; i < 32; i += 8)
    out[(long long)(c0 + ty + i) * DKH + r0 + tx] = f2bf(t[tx][ty + i]);
}

// -------- misc packing: WcT (7680) + fused kvq bias (2*2304) --------------
__global__ void pack_misc(const float* __restrict__ Wc, const float* __restrict__ kb,
                          const float* __restrict__ vb, const float* __restrict__ qb,
                          float* __restrict__ WcT, float* __restrict__ b_kvq)
{
  int idx = blockIdx.x * 256 + threadIdx.x;
  if (idx < 7680) {
    int j = idx / EMB, d = idx - j * EMB;
    WcT[idx] = Wc[d * 10 + j];
  } else if (idx < 7680 + 2 * 2304) {
    int k = idx - 7680;
    int l = k / 2304, c = k - l * 2304;
    float v;
    if (c < 768) v = kb[(l * 2) * EMB + c];
    else if (c < 1536) v = vb[(l * 2) * EMB + c - 768];
    else v = qb[(l * 2) * EMB + c - 1536];
    b_kvq[k] = v;
  }
}

// --------------------------------------------- fused assign-softmax + centers
__global__ __launch_bounds__(512) void assign_center512(
    u16* __restrict__ qh_bf,
    const float* __restrict__ WcT, const float* __restrict__ bc,
    const float* __restrict__ centers)
{
  __shared__ float wc_s[7680];
  __shared__ float cen_s[7680];
  const int tid = threadIdx.x;
  for (int i = tid; i < 7680; i += 512) {
    wc_s[i] = WcT[i];
    cen_s[i] = centers[i];
  }
  __syncthreads();
  const int wave = tid >> 6, lane = tid & 63;
  const int row = blockIdx.x * 8 + wave;   // NQ = 30000 = 3750*8 exact
  const long long base = (long long)row * EMB;
  float x[12];
#pragma unroll
  for (int i = 0; i < 12; ++i) x[i] = bf2f(qh_bf[base + lane + 64 * i]);
  float part[10] = {};
#pragma unroll
  for (int i = 0; i < 12; ++i) {
    const float v = x[i];
    const int d = lane + 64 * i;
#pragma unroll
    for (int j = 0; j < 10; ++j) part[j] = fmaf(v, wc_s[j * EMB + d], part[j]);
  }
#pragma unroll
  for (int j = 0; j < 10; ++j)
#pragma unroll
    for (int off = 32; off; off >>= 1) part[j] += __shfl_xor(part[j], off);
  float mx = -1e30f;
#pragma unroll
  for (int j = 0; j < 10; ++j) { part[j] += bc[j]; mx = fmaxf(mx, part[j]); }
  float s = 0.f;
#pragma unroll
  for (int j = 0; j < 10; ++j) { part[j] = __expf(part[j] - mx); s += part[j]; }
  const float inv = 1.f / s;
#pragma unroll
  for (int i = 0; i < 12; ++i) {
    const int d = lane + 64 * i;
    float acc = 0.f;
#pragma unroll
    for (int j = 0; j < 10; ++j) acc = fmaf(part[j], cen_s[j * EMB + d], acc);
    qh_bf[base + d] = f2bf(x[i] + acc * inv);
  }
}

// ------------------------------------------------------------- CSR build
// cnt/cur layout: [0,QLEN) give | [QLEN,QLEN+TLEN) i1 | [QLEN+TLEN,+TLEN) i2
// adj layout: [0,EG) give | [EG,EG+EI) i1 | [EG+EI,EG+2EI) i2 (graph-local p)
__global__ void hist_all(const int* __restrict__ gd, const int* __restrict__ d1,
                         const int* __restrict__ d2, int* __restrict__ cnt)
{
  int e = blockIdx.x * 256 + threadIdx.x;
  if (e < EG) atomicAdd(&cnt[gd[e]], 1);
  else if (e < EG + EI) atomicAdd(&cnt[QLEN + d1[e - EG]], 1);
  else if (e < EG + 2 * EI) atomicAdd(&cnt[QLEN + TLEN + d2[e - EG - EI]], 1);
}

__global__ __launch_bounds__(1024) void scan3(
    const int* __restrict__ cnt_all, int* __restrict__ rp_g,
    int* __restrict__ rp_1, int* __restrict__ rp_2, int* __restrict__ cur_all)
{
  __shared__ int buf[1024];
  const int b = blockIdx.x;
  const int n = (b == 0) ? QLEN : TLEN;
  const int seg = (b == 0) ? 0 : (b == 1) ? QLEN : QLEN + TLEN;
  const int* cnt = cnt_all + seg;
  int* cur = cur_all + seg;
  int* rowptr = (b == 0) ? rp_g : (b == 1) ? rp_1 : rp_2;
  const int tid = threadIdx.x;
  const int chunk = (n + 1023) >> 10;
  const int base = tid * chunk;
  int s = 0;
  for (int i = 0; i < chunk; ++i) {
    int idx = base + i;
    if (idx < n) s += cnt[idx];
  }
  buf[tid] = s;
  __syncthreads();
  for (int off = 1; off < 1024; off <<= 1) {
    int v = (tid >= off) ? buf[tid - off] : 0;
    __syncthreads();
    buf[tid] += v;
    __syncthreads();
  }
  int run = (tid == 0) ? 0 : buf[tid - 1];
  for (int i = 0; i < chunk; ++i) {
    int idx = base + i;
    if (idx < n) {
      rowptr[idx] = run;
      cur[idx] = run;
      run += cnt[idx];
    }
  }
  if (tid == 1023) rowptr[n] = buf[1023];
}

__global__ void fill_all(const int* __restrict__ gs, const int* __restrict__ gd,
                         const int* __restrict__ s1, const int* __restrict__ d1,
                         const int* __restrict__ s2, const int* __restrict__ d2,
                         int* __restrict__ cur_all, int* __restrict__ adj_all)
{
  int e = blockIdx.x * 256 + threadIdx.x;
  if (e < EG) {
    int p = atomicAdd(&cur_all[gd[e]], 1);
    adj_all[p] = gs[e];
  } else if (e < EG + EI) {
    int p = atomicAdd(&cur_all[QLEN + d1[e - EG]], 1);
    adj_all[EG + p] = s1[e - EG];
  } else if (e < EG + 2 * EI) {
    int p = atomicAdd(&cur_all[QLEN + TLEN + d2[e - EG - EI]], 1);
    adj_all[EG + EI + p] = s2[e - EG - EI];
  }
}

// ------------- give gather: one wave per dst, all 4 heads, fp8 K/V/Q, 3 copies
__global__ __launch_bounds__(256) void gather_give(
    const u8* __restrict__ q, const u8* __restrict__ kv,
    const int* __restrict__ rowptr, const int* __restrict__ adj,
    const float* __restrict__ rpri, u16* __restrict__ hq_bf)
{
  const int d = (blockIdx.x * 256 + threadIdx.x) >> 6;
  const int lane = threadIdx.x & 63;
  if (d >= QLEN) return;
  const int rs = rowptr[d], re = rowptr[d + 1];
  if (rs == re) return;
  const int h = lane >> 4, sub = lane & 15;
  const int off = h * DKH + sub * 12;
  const float pri = rpri[h] * SCALE;

  float qv[3][12];
#pragma unroll
  for (int c = 0; c < 3; ++c)
    decode12((const u32*)(q + (size_t)(c * QLEN + d) * EMB + off), qv[c]);

  float S[3] = {0.f, 0.f, 0.f};
  float A[3][12] = {};

  auto edge = [&](int sn) {
    float kf[12], vf[12];
    decode12((const u32*)(kv + (size_t)sn * 1536 + off), kf);
    decode12((const u32*)(kv + (size_t)sn * 1536 + 768 + off), vf);
    float dt[3] = {0.f, 0.f, 0.f};
#pragma unroll
    for (int t = 0; t < 12; ++t) {
#pragma unroll
      for (int c = 0; c < 3; ++c) dt[c] = fmaf(qv[c][t], kf[t], dt[c]);
    }
#pragma unroll
    for (int c = 0; c < 3; ++c) {
#pragma unroll
      for (int o2 = 8; o2; o2 >>= 1) dt[c] += __shfl_xor(dt[c], o2);
      const float e = __expf(dt[c] * pri);
      S[c] += e;
#pragma unroll
      for (int t = 0; t < 12; ++t) A[c][t] = fmaf(e, vf[t], A[c][t]);
    }
  };
  int i = rs;
  for (; i + 1 < re; i += 2) { edge(adj[i]); edge(adj[i + 1]); }
  if (i < re) edge(adj[i]);

#pragma unroll
  for (int c = 0; c < 3; ++c) {
    const float inv = 1.f / S[c];
    u32* o = (u32*)(hq_bf + (size_t)(c * QLEN + d) * EMB + off);
#pragma unroll
    for (int t = 0; t < 6; ++t) {
      f32x2 r = bfx2(o[t]);
      r[0] += A[c][2 * t] * inv;
      r[1] += A[c][2 * t + 1] * inv;
      o[t] = (u32)f2bf(r[0]) | ((u32)f2bf(r[1]) << 16);
    }
  }
}

// ---- merged inter gather: one wave per dst, all 4 heads, both relations
__global__ __launch_bounds__(256) void gather_inter(
    const u16* __restrict__ tag_kvq,   // bf16, q at col 1536
    const u8* __restrict__ kv1, const u8* __restrict__ kv2,
    const int* __restrict__ rp1, const int* __restrict__ adj1,
    const int* __restrict__ rp2, const int* __restrict__ adj2,
    const float* __restrict__ pri1, const float* __restrict__ pri2,
    u16* __restrict__ htag_bf)
{
  const int d = (blockIdx.x * 256 + threadIdx.x) >> 6;
  const int lane = threadIdx.x & 63;
  if (d >= TLEN) return;
  const int rs1 = rp1[d], re1 = rp1[d + 1];
  const int rs2 = rp2[d], re2 = rp2[d + 1];
  if (rs1 == re1 && rs2 == re2) return;
  const int h = lane >> 4, sub = lane & 15;
  const int off = h * DKH + sub * 12;
  float qv[12];
  {
    const u32* qp = (const u32*)(tag_kvq + (size_t)d * 2304 + 1536 + off);
#pragma unroll
    for (int t = 0; t < 6; ++t) {
      f32x2 r = bfx2(qp[t]);
      qv[2 * t] = r[0]; qv[2 * t + 1] = r[1];
    }
  }
  float R[12] = {};
#pragma unroll
  for (int rel = 0; rel < 2; ++rel) {
    const u8* kv = rel ? kv2 : kv1;
    const int rs = rel ? rs2 : rs1, re = rel ? re2 : re1;
    const int* adj = rel ? adj2 : adj1;
    if (rs == re) continue;
    const float pri = (rel ? pri2[h] : pri1[h]) * SCALE;
    float S = 0.f, A[12] = {};
    auto edge = [&](int sn) {
      float kf[12], vf[12];
      decode12((const u32*)(kv + (size_t)sn * 1536 + off), kf);
      decode12((const u32*)(kv + (size_t)sn * 1536 + 768 + off), vf);
      float dt = 0.f;
#pragma unroll
      for (int t = 0; t < 12; ++t) dt = fmaf(qv[t], kf[t], dt);
#pragma unroll
      for (int o2 = 8; o2; o2 >>= 1) dt += __shfl_xor(dt, o2);
      const float e = __expf(dt * pri);
      S += e;
#pragma unroll
      for (int t = 0; t < 12; ++t) A[t] = fmaf(e, vf[t], A[t]);
    };
    int i = rs;
    for (; i + 1 < re; i += 2) { edge(adj[i]); edge(adj[i + 1]); }
    if (i < re) edge(adj[i]);
    const float inv = 0.5f / S;
#pragma unroll
    for (int t = 0; t < 12; ++t) R[t] = fmaf(A[t], inv, R[t]);
  }
  u32* o = (u32*)(htag_bf + (size_t)d * EMB + off);
#pragma unroll
  for (int t = 0; t < 6; ++t) {
    f32x2 r = bfx2(o[t]);
    r[0] += R[2 * t];
    r[1] += R[2 * t + 1];
    o[t] = (u32)f2bf(r[0]) | ((u32)f2bf(r[1]) << 16);
  }
}

}  // namespace

extern "C" void kernel_launch(void* const* d_in, const int* in_sizes, int n_in,
                              void* d_out, int out_size, void* d_ws, size_t ws_size,
                              hipStream_t stream)
{
  const float* q_emb   = (const float*)d_in[0];
  const float* t_emb   = (const float*)d_in[1];
  const int*   give_src = (const int*)d_in[2];
  const int*   give_dst = (const int*)d_in[3];
  const int*   i1_src  = (const int*)d_in[4];
  const int*   i1_dst  = (const int*)d_in[5];
  const int*   i2_src  = (const int*)d_in[6];
  const int*   i2_dst  = (const int*)d_in[7];
  const float* Wq_enc  = (const float*)d_in[8];
  const float* bq_enc  = (const float*)d_in[9];
  const float* Wc      = (const float*)d_in[10];
  const float* bc      = (const float*)d_in[11];
  const float* centers = (const float*)d_in[12];
  const float* kW      = (const float*)d_in[13];
  const float* kb      = (const float*)d_in[14];
  const float* qW      = (const float*)d_in[15];
  const float* qb      = (const float*)d_in[16];
  const float* vW      = (const float*)d_in[17];
  const float* vb      = (const float*)d_in[18];
  const float* rel_att = (const float*)d_in[19];
  const float* rel_msg = (const float*)d_in[20];
  const float* rel_pri = (const float*)d_in[21];
  const float* Wout    = (const float*)d_in[22];
  const float* bout    = (const float*)d_in[23];
  float* out = (float*)d_out;

  const long long WS = (long long)EMB * EMB;   // 589824
  const long long RS = (long long)DKH * DKH;   // 36864

  // -------- workspace carve-up (bf16 node state, fp8 gather operands)
  float* p = (float*)d_ws;
  auto take = [&](size_t n) { float* r = p; p += ((n + 3) & ~(size_t)3); return r; };
  u16* h_q_bf    = (u16*)take((size_t)NQ * EMB / 2);     // contiguous with h_tag_bf
  u16* h_tag_bf  = (u16*)take((size_t)TLEN * EMB / 2);
  u16* q_emb_bf  = (u16*)take((size_t)QLEN * EMB / 2);
  u16* tag_kvq   = (u16*)take((size_t)TLEN * 2304 / 2);
  u8* kv_all     = (u8*)take((size_t)3 * TLEN * 1536 / 4);
  u8* kv_g = kv_all;
  u8* kv_1 = kv_all + (size_t)TLEN * 1536;
  u8* kv_2 = kv_all + (size_t)2 * TLEN * 1536;
  u16* WqT   = (u16*)take((size_t)3 * WS / 2);           // [2304][768]
  u16* qWT   = (u16*)take((size_t)2 * WS / 2);           // slots: l0 q_que, l1 q_que
  u16* Wtag  = (u16*)take((size_t)2 * 3 * WS / 2);       // [l][2304][768]
  u16* WoutT = (u16*)take((size_t)WS / 2);
  u16* relWT = (u16*)take((size_t)48 * RS / 2);          // [lr][8][192][192]
  float* WcT   = take(7680);
  float* b_kvq = take(2 * 2304);
  int* rp_g  = (int*)take(QLEN + 1);
  int* rp_1  = (int*)take(TLEN + 1);
  int* rp_2  = (int*)take(TLEN + 1);
  int* cur_all = (int*)take(QLEN + 2 * TLEN);
  int* cnt_all = (int*)take(QLEN + 2 * TLEN);
  int* adj_all = (int*)take(EG + 2 * EI);
  int* adj_g = adj_all;
  int* adj_1 = adj_all + EG;
  int* adj_2 = adj_all + EG + EI;
  u8* q_que = (u8*)out;          // d_out as scratch (fp8); overwritten at end

  auto gemmb = [&](int EPI, int OUT, const u16* A, int lda, long long sAz,
                   const u16* Bt, int ldb, long long sBz,
                   void* C, int ldc, long long sCz, long long sCz2, int relpack,
                   const float* bias, const u16* extra,
                   int M, int N, int K, int batch) {
    dim3 grid((N + 127) / 128, (M + 127) / 128, batch);
    if (EPI == 0 && OUT == 1)
      gemm_bf16<0, 1><<<grid, 256, 0, stream>>>(A, lda, sAz, Bt, ldb, sBz, C, ldc, sCz, sCz2, relpack, bias, extra, M, N, K);
    else if (EPI == 0 && OUT == 2)
      gemm_bf16<0, 2><<<grid, 256, 0, stream>>>(A, lda, sAz, Bt, ldb, sBz, C, ldc, sCz, sCz2, relpack, bias, extra, M, N, K);
    else if (EPI == 1)
      gemm_bf16<1, 1><<<grid, 256, 0, stream>>>(A, lda, sAz, Bt, ldb, sBz, C, ldc, sCz, sCz2, relpack, bias, extra, M, N, K);
    else
      gemm_bf16<2, 0><<<grid, 256, 0, stream>>>(A, lda, sAz, Bt, ldb, sBz, C, ldc, sCz, sCz2, relpack, bias, extra, M, N, K);
  };

  // -------- CSR builds: 4 launches for all 3 graphs
  hipMemsetAsync(cnt_all, 0, (size_t)(QLEN + 2 * TLEN) * sizeof(int), stream);
  hist_all<<<(EG + 2 * EI + 255) / 256, 256, 0, stream>>>(give_dst, i1_dst, i2_dst, cnt_all);
  scan3<<<3, 1024, 0, stream>>>(cnt_all, rp_g, rp_1, rp_2, cur_all);
  fill_all<<<(EG + 2 * EI + 255) / 256, 256, 0, stream>>>(
      give_src, give_dst, i1_src, i1_dst, i2_src, i2_dst, cur_all, adj_all);

  // -------- one-time packs / transposes (3 launches)
  pack_misc<<<48, 256, 0, stream>>>(Wc, kb, vb, qb, WcT, b_kvq);
  {
    T12 jobs;
    // Wq_enc [768][2304] -> WqT [2304][768] in 3 column-chunks
    for (int j = 0; j < 3; ++j) { jobs.s[j] = Wq_enc + j * 768; jobs.d[j] = WqT + (long long)j * WS; jobs.ld[j] = 2304; }
    // q_que weights (layer slots 1 and 3)
    jobs.s[3] = qW + 1 * WS; jobs.d[3] = qWT;           jobs.ld[3] = 768;
    jobs.s[4] = qW + 3 * WS; jobs.d[4] = qWT + WS;      jobs.ld[4] = 768;
    // fused tag weights: [l][k|v|q]
    for (int l = 0; l < 2; ++l) {
      jobs.s[5 + l * 3] = kW + (l * 2) * WS; jobs.d[5 + l * 3] = Wtag + (long long)(l * 3 + 0) * WS; jobs.ld[5 + l * 3] = 768;
      jobs.s[6 + l * 3] = vW + (l * 2) * WS; jobs.d[6 + l * 3] = Wtag + (long long)(l * 3 + 1) * WS; jobs.ld[6 + l * 3] = 768;
      jobs.s[7 + l * 3] = qW + (l * 2) * WS; jobs.d[7 + l * 3] = Wtag + (long long)(l * 3 + 2) * WS; jobs.ld[7 + l * 3] = 768;
    }
    jobs.s[11] = Wout; jobs.d[11] = WoutT; jobs.ld[11] = 768;
    transpose768<<<dim3(24, 24, 12), 256, 0, stream>>>(jobs);
  }
  transpose_rel<<<dim3(6, 6, 48), 256, 0, stream>>>(rel_att, rel_msg, relWT);

  // -------- question encoder + clustering (bf16 state)
  f2bf_kernel<<<(QLEN * EMB / 4 + 255) / 256, 256, 0, stream>>>(q_emb, q_emb_bf, (long long)QLEN * EMB);
  gemmb(1, 1, q_emb_bf, EMB, 0, WqT, EMB, 0, h_q_bf, EMB, 0, 0, 0, bq_enc, q_emb_bf,
        QLEN, EMB * HNEED, EMB, 1);
  assign_center512<<<NQ / 8, 512, 0, stream>>>(h_q_bf, WcT, bc, centers);
  f2bf_kernel<<<(TLEN * EMB / 4 + 255) / 256, 256, 0, stream>>>(t_emb, h_tag_bf, (long long)TLEN * EMB);

  const long long KVZ = (long long)TLEN * 1536;   // fp8 bytes per kv buffer
  for (int l = 0; l < 2; ++l) {
    // fused K|V|Q tag projection: [3000][2304] bf16
    gemmb(0, 1, h_tag_bf, EMB, 0, Wtag + (long long)l * 3 * WS, EMB, 0,
          tag_kvq, 2304, 0, 0, 0, b_kvq + l * 2304, nullptr, TLEN, 2304, EMB, 1);
    // question Q projection -> fp8
    gemmb(0, 2, h_q_bf, EMB, 0, qWT + (long long)l * WS, EMB, 0,
          q_que, EMB, 0, 0, 0, qb + (l * 2 + 1) * EMB, nullptr, NQ, EMB, EMB, 1);
    // all 3 relations' K/V transforms in one z=24 batch -> fp8
    gemmb(0, 2, tag_kvq, 2304, 192, relWT + (long long)(l * 3) * 8 * RS, DKH, RS,
          kv_g, 1536, 192, KVZ, 1, nullptr, nullptr, TLEN, DKH, DKH, 24);
    // gathers (bf16 RMW into node state)
    gather_give<<<(QLEN * 64 + 255) / 256, 256, 0, stream>>>(
        q_que, kv_g, rp_g, adj_g, rel_pri + (l * 3 + 0) * NHEADS, h_q_bf);
    gather_inter<<<(TLEN * 64 + 255) / 256, 256, 0, stream>>>(
        tag_kvq, kv_1, kv_2, rp_1, adj_1, rp_2, adj_2,
        rel_pri + (l * 3 + 1) * NHEADS, rel_pri + (l * 3 + 2) * NHEADS,
        h_tag_bf);
  }

  // -------- merged output GEMM: rows [0,NQ) ques-scatter, [NQ,NQ+TLEN) tags
  gemmb(2, 0, h_q_bf, EMB, 0, WoutT, EMB, 0, out, EMB, 0, 0, 0, bout, nullptr,
        NQ + TLEN, EMB, EMB, 1);
}

// Round 11
// 761.300 us; speedup vs baseline: 8.7054x; 1.0612x over previous
//
#include <hip/hip_runtime.h>

#define QLEN 10000
#define TLEN 3000
#define EMB 768
#define HNEED 3
#define NQ (QLEN * HNEED)
#define EG 100000
#define EI 100000
#define DKH 192
#define NHEADS 4

namespace {

typedef unsigned short u16;
typedef unsigned char u8;
typedef unsigned int u32;
typedef __attribute__((ext_vector_type(8))) short bf16x8;
typedef __attribute__((ext_vector_type(4))) float f32x4;
typedef __attribute__((ext_vector_type(2))) float f32x2;

constexpr float SCALE = 0.07216878364870322f; // 1/sqrt(192)
constexpr long long WS = (long long)EMB * EMB;   // 589824
constexpr long long RS = (long long)DKH * DKH;   // 36864

__device__ inline u16 f2bf(float f) {
  unsigned u = __float_as_uint(f);
  unsigned r = (u + 0x7FFFu + ((u >> 16) & 1u)) >> 16;  // RNE
  return (u16)r;
}
__device__ inline float bf2f(u16 h) {
  return __uint_as_float((unsigned)h << 16);
}
__device__ inline u8 f2fp8(float f) {
  u32 pk = __builtin_amdgcn_cvt_pk_fp8_f32(f, f, 0, false);
  return (u8)(pk & 0xFF);
}
__device__ inline void decode12(const u32* p, float* o) {
#pragma unroll
  for (int t = 0; t < 3; ++t) {
    u32 w = p[t];
    f32x2 lo = __builtin_amdgcn_cvt_pk_f32_fp8(w, false);
    f32x2 hi = __builtin_amdgcn_cvt_pk_f32_fp8(w, true);
    o[t * 4 + 0] = lo[0]; o[t * 4 + 1] = lo[1];
    o[t * 4 + 2] = hi[0]; o[t * 4 + 3] = hi[1];
  }
}
__device__ inline f32x2 bfx2(u32 w) {
  f32x2 r;
  r[0] = __uint_as_float(w << 16);
  r[1] = __uint_as_float(w & 0xFFFF0000u);
  return r;
}

__device__ inline void gload_lds16(const u16* g, u16* s) {
  __builtin_amdgcn_global_load_lds(
      (const __attribute__((address_space(1))) unsigned*)g,
      (__attribute__((address_space(3))) unsigned*)s, 16, 0, 0);
}

// ------------------------------------------------------------ bf16 MFMA GEMM
// 128x128 tile, BK=32, 3-stage pipelined LDS, counted vmcnt, XCD swizzle,
// LDS k-chunk swizzle, setprio. OUT: 0=f32, 1=bf16, 2=fp8.
// EPI 0: C[m][n]
// EPI 1: encoder: C_bf[(n/768)*QLEN + m][n%768] = bf16(v + bf2f(extra[m][n%768]))
// EPI 2: merged out: grow<NQ -> Cf[((grow%QLEN)*3+grow/QLEN)*768+n] else direct
// MODE 0: standard z-batch. MODE 1: combine-weights addressing:
//   z = lr*8 + kv*4 + h; A = relWT + z*RS (A[n'][e]); Bt = (kv?vWbf:kWbf)
//   + (l*2)*WS + h*192 (ldb 768); C = Wcomb + lr*1536*768 + (kv*768+h*192)*768.
template <int EPI, int OUT, int MODE>
__global__ __launch_bounds__(256) void gemm_bf16(
    const u16* __restrict__ A, int lda, long long sAz,
    const u16* __restrict__ Bt, int ldb, long long sBz,
    void* __restrict__ Cv, int ldc, long long sCz,
    const float* __restrict__ bias, const u16* __restrict__ extra,
    int M, int N, int K)
{
  __shared__ __align__(16) u16 As[3][4096];
  __shared__ __align__(16) u16 Bs[3][4096];
  const int z = blockIdx.z;
  float* Cf = (float*)Cv;
  u16* Ch = (u16*)Cv;
  u8* C8 = (u8*)Cv;
  if (MODE == 1) {
    const int lr = z >> 3, kv = (z >> 2) & 1, h = z & 3;
    const int l = lr >= 3;
    A += (long long)z * RS;
    Bt = (kv ? extra : Bt) + (long long)(l * 2) * WS + h * 192;
    Ch = (u16*)Cv + (long long)lr * 1536 * 768 + (long long)(kv * 768 + h * 192) * 768;
  } else {
    A += (long long)z * sAz;
    Bt += (long long)z * sBz;
    Cf += (long long)z * sCz;
    Ch += (long long)z * sCz;
    C8 += (long long)z * sCz;
  }
  // XCD-chunked bijective remap
  const int gx = gridDim.x;
  const int nwg = gx * gridDim.y;
  const int orig = blockIdx.y * gx + blockIdx.x;
  const int qq = nwg >> 3, rr = nwg & 7;
  const int xc = orig & 7, ix = orig >> 3;
  const int swz = (xc < rr ? xc * (qq + 1) : rr * (qq + 1) + (xc - rr) * qq) + ix;
  const int by = swz / gx, bx = swz - by * gx;
  const int bm = by * 128, bn = bx * 128;

  const int tid = threadIdx.x;
  const int w = tid >> 6, l = tid & 63;
  const int wr = w >> 1, wc = w & 1;
  const int l16 = l & 15, lk = l >> 4;
  const int srow = tid >> 2;
  const int scol = (((tid & 3) ^ ((srow >> 1) & 3))) * 8;
  const int rchunk = (lk ^ ((l16 >> 1) & 3));

  int r0 = bm + srow;      if (r0 > M - 1) r0 = M - 1;
  int r1 = bm + srow + 64; if (r1 > M - 1) r1 = M - 1;
  int c0 = bn + srow;      if (c0 > N - 1) c0 = N - 1;
  int c1 = bn + srow + 64; if (c1 > N - 1) c1 = N - 1;
  const u16* pa0 = A + (long long)r0 * lda + scol;
  const u16* pa1 = A + (long long)r1 * lda + scol;
  const u16* pb0 = Bt + (long long)c0 * ldb + scol;
  const u16* pb1 = Bt + (long long)c1 * ldb + scol;

  int aoff[4], boff[4];
#pragma unroll
  for (int m = 0; m < 4; ++m) {
    aoff[m] = (wr * 64 + m * 16 + l16) * 32 + rchunk * 8;
    boff[m] = (wc * 64 + m * 16 + l16) * 32 + rchunk * 8;
  }

  f32x4 acc[4][4] = {};
  const int nt = K / 32;

  auto stage = [&](int buf, int k0) {
    gload_lds16(pa0 + k0, &As[buf][w * 512]);
    gload_lds16(pa1 + k0, &As[buf][w * 512 + 2048]);
    gload_lds16(pb0 + k0, &Bs[buf][w * 512]);
    gload_lds16(pb1 + k0, &Bs[buf][w * 512 + 2048]);
  };

  stage(0, 0);
  stage(1, 32);
  int cur = 0, sb = 2;
  for (int t = 0; t < nt; ++t) {
    if (t < nt - 1)
      asm volatile("s_waitcnt vmcnt(4)" ::: "memory");
    else
      asm volatile("s_waitcnt vmcnt(0)" ::: "memory");
    __builtin_amdgcn_s_barrier();
    __builtin_amdgcn_sched_barrier(0);
    if (t + 2 < nt) {
      stage(sb, (t + 2) * 32);
      if (++sb == 3) sb = 0;
    }
    bf16x8 af[4], bf[4];
#pragma unroll
    for (int m = 0; m < 4; ++m)
      af[m] = *(const bf16x8*)&As[cur][aoff[m]];
#pragma unroll
    for (int n = 0; n < 4; ++n)
      bf[n] = *(const bf16x8*)&Bs[cur][boff[n]];
    __builtin_amdgcn_s_setprio(1);
#pragma unroll
    for (int m = 0; m < 4; ++m)
#pragma unroll
      for (int n = 0; n < 4; ++n)
        acc[m][n] = __builtin_amdgcn_mfma_f32_16x16x32_bf16(af[m], bf[n], acc[m][n], 0, 0, 0);
    __builtin_amdgcn_s_setprio(0);
    if (++cur == 3) cur = 0;
  }

#pragma unroll
  for (int m = 0; m < 4; ++m) {
#pragma unroll
    for (int j = 0; j < 4; ++j) {
      int grow = bm + wr * 64 + m * 16 + lk * 4 + j;
      if (grow >= M) continue;
#pragma unroll
      for (int n = 0; n < 4; ++n) {
        int gcol = bn + wc * 64 + n * 16 + l16;
        if (gcol >= N) continue;
        float val = acc[m][n][j] + (bias ? bias[gcol] : 0.f);
        if (EPI == 0) {
          if (OUT == 0)
            Cf[(long long)grow * ldc + gcol] = val;
          else if (OUT == 1)
            Ch[(long long)grow * ldc + gcol] = f2bf(val);
          else
            C8[(long long)grow * ldc + gcol] = f2fp8(val);
        } else if (EPI == 1) {
          int h = gcol / EMB, c = gcol - h * EMB;
          Ch[((long long)h * QLEN + grow) * EMB + c] =
              f2bf(val + bf2f(extra[(long long)grow * EMB + c]));
        } else {
          if (grow < NQ) {
            int i2 = grow % QLEN, h = grow / QLEN;
            Cf[((long long)i2 * HNEED + h) * EMB + gcol] = val;
          } else {
            Cf[(long long)grow * EMB + gcol] = val;
          }
        }
      }
    }
  }
}

// ------------------------------------------------- grouped per-layer GEMM pack
// All jobs: K=768, lda=ldb=768, N multiple of 128. out: 1=bf16, 2=fp8.
struct PackJobs {
  const u16* A[5];
  const u16* Bt[5];
  void* C[5];
  const float* bias[5];
  int M[5];
  int nx[5];     // N/128
  int ldc[5];
  int out[5];
  int start[6];
};

__global__ __launch_bounds__(256) void gemm_pack(PackJobs Jb)
{
  const int nwg = Jb.start[5];
  const int orig = blockIdx.x;
  const int qq = nwg >> 3, rr = nwg & 7;
  const int xc = orig & 7, ix = orig >> 3;
  const int swz = (xc < rr ? xc * (qq + 1) : rr * (qq + 1) + (xc - rr) * qq) + ix;
  int j = 0;
  while (swz >= Jb.start[j + 1]) ++j;
  const int local = swz - Jb.start[j];
  const int nx = Jb.nx[j];
  const int by = local / nx, bx = local - by * nx;
  const int bm = by * 128, bn = bx * 128;
  const int M = Jb.M[j];
  const int ldc = Jb.ldc[j];
  const int outk = Jb.out[j];
  const u16* A = Jb.A[j];
  const u16* Bt = Jb.Bt[j];
  const float* bias = Jb.bias[j];
  u16* Ch = (u16*)Jb.C[j];
  u8* C8 = (u8*)Jb.C[j];

  __shared__ __align__(16) u16 As[3][4096];
  __shared__ __align__(16) u16 Bs[3][4096];

  const int tid = threadIdx.x;
  const int w = tid >> 6, l = tid & 63;
  const int wr = w >> 1, wc = w & 1;
  const int l16 = l & 15, lk = l >> 4;
  const int srow = tid >> 2;
  const int scol = (((tid & 3) ^ ((srow >> 1) & 3))) * 8;
  const int rchunk = (lk ^ ((l16 >> 1) & 3));

  int r0 = bm + srow;      if (r0 > M - 1) r0 = M - 1;
  int r1 = bm + srow + 64; if (r1 > M - 1) r1 = M - 1;
  const int c0 = bn + srow;
  const int c1 = bn + srow + 64;
  const u16* pa0 = A + (long long)r0 * 768 + scol;
  const u16* pa1 = A + (long long)r1 * 768 + scol;
  const u16* pb0 = Bt + (long long)c0 * 768 + scol;
  const u16* pb1 = Bt + (long long)c1 * 768 + scol;

  int aoff[4], boff[4];
#pragma unroll
  for (int m = 0; m < 4; ++m) {
    aoff[m] = (wr * 64 + m * 16 + l16) * 32 + rchunk * 8;
    boff[m] = (wc * 64 + m * 16 + l16) * 32 + rchunk * 8;
  }

  f32x4 acc[4][4] = {};
  const int nt = 24;   // K = 768

  auto stage = [&](int buf, int k0) {
    gload_lds16(pa0 + k0, &As[buf][w * 512]);
    gload_lds16(pa1 + k0, &As[buf][w * 512 + 2048]);
    gload_lds16(pb0 + k0, &Bs[buf][w * 512]);
    gload_lds16(pb1 + k0, &Bs[buf][w * 512 + 2048]);
  };

  stage(0, 0);
  stage(1, 32);
  int cur = 0, sb = 2;
  for (int t = 0; t < nt; ++t) {
    if (t < nt - 1)
      asm volatile("s_waitcnt vmcnt(4)" ::: "memory");
    else
      asm volatile("s_waitcnt vmcnt(0)" ::: "memory");
    __builtin_amdgcn_s_barrier();
    __builtin_amdgcn_sched_barrier(0);
    if (t + 2 < nt) {
      stage(sb, (t + 2) * 32);
      if (++sb == 3) sb = 0;
    }
    bf16x8 af[4], bf[4];
#pragma unroll
    for (int m = 0; m < 4; ++m)
      af[m] = *(const bf16x8*)&As[cur][aoff[m]];
#pragma unroll
    for (int n = 0; n < 4; ++n)
      bf[n] = *(const bf16x8*)&Bs[cur][boff[n]];
    __builtin_amdgcn_s_setprio(1);
#pragma unroll
    for (int m = 0; m < 4; ++m)
#pragma unroll
      for (int n = 0; n < 4; ++n)
        acc[m][n] = __builtin_amdgcn_mfma_f32_16x16x32_bf16(af[m], bf[n], acc[m][n], 0, 0, 0);
    __builtin_amdgcn_s_setprio(0);
    if (++cur == 3) cur = 0;
  }

#pragma unroll
  for (int m = 0; m < 4; ++m) {
#pragma unroll
    for (int j2 = 0; j2 < 4; ++j2) {
      int grow = bm + wr * 64 + m * 16 + lk * 4 + j2;
      if (grow >= M) continue;
#pragma unroll
      for (int n = 0; n < 4; ++n) {
        int gcol = bn + wc * 64 + n * 16 + l16;
        float val = acc[m][n][j2] + bias[gcol];
        if (outk == 1)
          Ch[(long long)grow * ldc + gcol] = f2bf(val);
        else
          C8[(long long)grow * ldc + gcol] = f2fp8(val);
      }
    }
  }
}

// ------------------------------------------------------ conversion kernels
__global__ void f2bf_kernel(const float* __restrict__ in, u16* __restrict__ out, long long n)
{
  long long i = ((long long)blockIdx.x * 256 + threadIdx.x) * 4;
  if (i >= n) return;
  float4 v = *(const float4*)(in + i);
  ushort4 o;
  o.x = f2bf(v.x); o.y = f2bf(v.y); o.z = f2bf(v.z); o.w = f2bf(v.w);
  *(ushort4*)(out + i) = o;
}

// -------- batched 768x768 transposes ----------------
struct T12 {
  const float* s[12];
  u16* d[12];
  int ld[12];
};

__global__ __launch_bounds__(256) void transpose768(T12 jobs)
{
  const int z = blockIdx.z;
  const float* in = jobs.s[z];
  const long long ld = jobs.ld[z];
  u16* out = jobs.d[z];
  __shared__ float t[32][33];
  const int c0 = blockIdx.x * 32, r0 = blockIdx.y * 32;
  const int tx = threadIdx.x & 31, ty = threadIdx.x >> 5;
#pragma unroll
  for (int i = 0; i < 32; i += 8)
    t[ty + i][tx] = in[(long long)(r0 + ty + i) * ld + c0 + tx];
  __syncthreads();
#pragma unroll
  for (int i = 0; i < 32; i += 8)
    out[(long long)(c0 + ty + i) * 768 + r0 + tx] = f2bf(t[tx][ty + i]);
}

// -------- rel weight transpose: z<24 att -> slot lr*8+h ; z>=24 msg -> +4
__global__ __launch_bounds__(256) void transpose_rel(
    const float* __restrict__ att, const float* __restrict__ msg,
    u16* __restrict__ relWT)
{
  const int z = blockIdx.z;
  const int isMsg = z >= 24;
  const int zz = isMsg ? z - 24 : z;
  const int lr = zz >> 2, h = zz & 3;
  const float* in = (isMsg ? msg : att) + (long long)zz * RS;
  u16* out = relWT + (long long)(lr * 8 + isMsg * 4 + h) * RS;
  __shared__ float t[32][33];
  const int c0 = blockIdx.x * 32, r0 = blockIdx.y * 32;
  const int tx = threadIdx.x & 31, ty = threadIdx.x >> 5;
#pragma unroll
  for (int i = 0; i < 32; i += 8)
    t[ty + i][tx] = in[(long long)(r0 + ty + i) * DKH + c0 + tx];
  __syncthreads();
#pragma unroll
  for (int i = 0; i < 32; i += 8)
    out[(long long)(c0 + ty + i) * DKH + r0 + tx] = f2bf(t[tx][ty + i]);
}

// -------- WcT pack --------------------------------------------------------
__global__ void pack_wct(const float* __restrict__ Wc, float* __restrict__ WcT)
{
  int idx = blockIdx.x * 256 + threadIdx.x;
  if (idx >= 7680) return;
  int j = idx / EMB, d = idx - j * EMB;
  WcT[idx] = Wc[d * 10 + j];
}

// -------- bias fold: bcomb[lr][kv*768 + h*192 + j] = sum_e b[e] rel[lr,h,e,j]
__global__ void bcomb_kernel(const float* __restrict__ kb, const float* __restrict__ vb,
                             const float* __restrict__ att, const float* __restrict__ msg,
                             float* __restrict__ bcomb)
{
  int idx = blockIdx.x * 256 + threadIdx.x;
  if (idx >= 6 * 1536) return;
  int lr = idx / 1536, n = idx - lr * 1536;
  int kv = n / 768, n2 = n - kv * 768;
  int h = n2 / 192, j = n2 - h * 192;
  int l = lr / 3;
  const float* bsrc = (kv ? vb : kb) + (l * 2) * EMB + h * 192;
  const float* rl = (kv ? msg : att) + ((long long)lr * 4 + h) * RS + j;
  float s = 0.f;
  for (int e = 0; e < 192; ++e) s = fmaf(bsrc[e], rl[(long long)e * 192], s);
  bcomb[idx] = s;
}

// --------------------------------------------- fused assign-softmax + centers
__global__ __launch_bounds__(512) void assign_center512(
    u16* __restrict__ qh_bf,
    const float* __restrict__ WcT, const float* __restrict__ bc,
    const float* __restrict__ centers)
{
  __shared__ float wc_s[7680];
  __shared__ float cen_s[7680];
  const int tid = threadIdx.x;
  for (int i = tid; i < 7680; i += 512) {
    wc_s[i] = WcT[i];
    cen_s[i] = centers[i];
  }
  __syncthreads();
  const int wave = tid >> 6, lane = tid & 63;
  const int row = blockIdx.x * 8 + wave;
  const long long base = (long long)row * EMB;
  float x[12];
#pragma unroll
  for (int i = 0; i < 12; ++i) x[i] = bf2f(qh_bf[base + lane + 64 * i]);
  float part[10] = {};
#pragma unroll
  for (int i = 0; i < 12; ++i) {
    const float v = x[i];
    const int d = lane + 64 * i;
#pragma unroll
    for (int j = 0; j < 10; ++j) part[j] = fmaf(v, wc_s[j * EMB + d], part[j]);
  }
#pragma unroll
  for (int j = 0; j < 10; ++j)
#pragma unroll
    for (int off = 32; off; off >>= 1) part[j] += __shfl_xor(part[j], off);
  float mx = -1e30f;
#pragma unroll
  for (int j = 0; j < 10; ++j) { part[j] += bc[j]; mx = fmaxf(mx, part[j]); }
  float s = 0.f;
#pragma unroll
  for (int j = 0; j < 10; ++j) { part[j] = __expf(part[j] - mx); s += part[j]; }
  const float inv = 1.f / s;
#pragma unroll
  for (int i = 0; i < 12; ++i) {
    const int d = lane + 64 * i;
    float acc = 0.f;
#pragma unroll
    for (int j = 0; j < 10; ++j) acc = fmaf(part[j], cen_s[j * EMB + d], acc);
    qh_bf[base + d] = f2bf(x[i] + acc * inv);
  }
}

// ------------------------------------------------------------- CSR build
__global__ void hist_all(const int* __restrict__ gd, const int* __restrict__ d1,
                         const int* __restrict__ d2, int* __restrict__ cnt)
{
  int e = blockIdx.x * 256 + threadIdx.x;
  if (e < EG) atomicAdd(&cnt[gd[e]], 1);
  else if (e < EG + EI) atomicAdd(&cnt[QLEN + d1[e - EG]], 1);
  else if (e < EG + 2 * EI) atomicAdd(&cnt[QLEN + TLEN + d2[e - EG - EI]], 1);
}

__global__ __launch_bounds__(1024) void scan3(
    const int* __restrict__ cnt_all, int* __restrict__ rp_g,
    int* __restrict__ rp_1, int* __restrict__ rp_2, int* __restrict__ cur_all)
{
  __shared__ int buf[1024];
  const int b = blockIdx.x;
  const int n = (b == 0) ? QLEN : TLEN;
  const int seg = (b == 0) ? 0 : (b == 1) ? QLEN : QLEN + TLEN;
  const int* cnt = cnt_all + seg;
  int* cur = cur_all + seg;
  int* rowptr = (b == 0) ? rp_g : (b == 1) ? rp_1 : rp_2;
  const int tid = threadIdx.x;
  const int chunk = (n + 1023) >> 10;
  const int base = tid * chunk;
  int s = 0;
  for (int i = 0; i < chunk; ++i) {
    int idx = base + i;
    if (idx < n) s += cnt[idx];
  }
  buf[tid] = s;
  __syncthreads();
  for (int off = 1; off < 1024; off <<= 1) {
    int v = (tid >= off) ? buf[tid - off] : 0;
    __syncthreads();
    buf[tid] += v;
    __syncthreads();
  }
  int run = (tid == 0) ? 0 : buf[tid - 1];
  for (int i = 0; i < chunk; ++i) {
    int idx = base + i;
    if (idx < n) {
      rowptr[idx] = run;
      cur[idx] = run;
      run += cnt[idx];
    }
  }
  if (tid == 1023) rowptr[n] = buf[1023];
}

__global__ void fill_all(const int* __restrict__ gs, const int* __restrict__ gd,
                         const int* __restrict__ s1, const int* __restrict__ d1,
                         const int* __restrict__ s2, const int* __restrict__ d2,
                         int* __restrict__ cur_all, int* __restrict__ adj_all)
{
  int e = blockIdx.x * 256 + threadIdx.x;
  if (e < EG) {
    int p = atomicAdd(&cur_all[gd[e]], 1);
    adj_all[p] = gs[e];
  } else if (e < EG + EI) {
    int p = atomicAdd(&cur_all[QLEN + d1[e - EG]], 1);
    adj_all[EG + p] = s1[e - EG];
  } else if (e < EG + 2 * EI) {
    int p = atomicAdd(&cur_all[QLEN + TLEN + d2[e - EG - EI]], 1);
    adj_all[EG + EI + p] = s2[e - EG - EI];
  }
}

// --------------------- fused gathers: waves [0,QLEN) give, [QLEN,+TLEN) inter
__global__ __launch_bounds__(256) void gather_all(
    const u8* __restrict__ q, const u8* __restrict__ kv_g,
    const int* __restrict__ rp_g, const int* __restrict__ adj_g,
    const float* __restrict__ pri_g, u16* __restrict__ hq_bf,
    const u16* __restrict__ q_tag, const u8* __restrict__ kv1,
    const u8* __restrict__ kv2,
    const int* __restrict__ rp1, const int* __restrict__ adj1,
    const int* __restrict__ rp2, const int* __restrict__ adj2,
    const float* __restrict__ pri1, const float* __restrict__ pri2,
    u16* __restrict__ htag_bf)
{
  const int wid = blockIdx.x * 4 + (threadIdx.x >> 6);
  const int lane = threadIdx.x & 63;
  const int h = lane >> 4, sub = lane & 15;
  const int off = h * DKH + sub * 12;

  if (wid < QLEN) {
    const int d = wid;
    const int rs = rp_g[d], re = rp_g[d + 1];
    if (rs == re) return;
    const float pri = pri_g[h] * SCALE;
    float qv[3][12];
#pragma unroll
    for (int c = 0; c < 3; ++c)
      decode12((const u32*)(q + (size_t)(c * QLEN + d) * EMB + off), qv[c]);
    float S[3] = {0.f, 0.f, 0.f};
    float A[3][12] = {};
    auto edge = [&](int sn) {
      float kf[12], vf[12];
      decode12((const u32*)(kv_g + (size_t)sn * 1536 + off), kf);
      decode12((const u32*)(kv_g + (size_t)sn * 1536 + 768 + off), vf);
      float dt[3] = {0.f, 0.f, 0.f};
#pragma unroll
      for (int t = 0; t < 12; ++t) {
#pragma unroll
        for (int c = 0; c < 3; ++c) dt[c] = fmaf(qv[c][t], kf[t], dt[c]);
      }
#pragma unroll
      for (int c = 0; c < 3; ++c) {
#pragma unroll
        for (int o2 = 8; o2; o2 >>= 1) dt[c] += __shfl_xor(dt[c], o2);
        const float e = __expf(dt[c] * pri);
        S[c] += e;
#pragma unroll
        for (int t = 0; t < 12; ++t) A[c][t] = fmaf(e, vf[t], A[c][t]);
      }
    };
    int i = rs;
    for (; i + 1 < re; i += 2) { edge(adj_g[i]); edge(adj_g[i + 1]); }
    if (i < re) edge(adj_g[i]);
#pragma unroll
    for (int c = 0; c < 3; ++c) {
      const float inv = 1.f / S[c];
      u32* o = (u32*)(hq_bf + (size_t)(c * QLEN + d) * EMB + off);
#pragma unroll
      for (int t = 0; t < 6; ++t) {
        f32x2 r = bfx2(o[t]);
        r[0] += A[c][2 * t] * inv;
        r[1] += A[c][2 * t + 1] * inv;
        o[t] = (u32)f2bf(r[0]) | ((u32)f2bf(r[1]) << 16);
      }
    }
  } else {
    const int d = wid - QLEN;
    if (d >= TLEN) return;
    const int rs1 = rp1[d], re1 = rp1[d + 1];
    const int rs2 = rp2[d], re2 = rp2[d + 1];
    if (rs1 == re1 && rs2 == re2) return;
    float qv[12];
    {
      const u32* qp = (const u32*)(q_tag + (size_t)d * EMB + off);
#pragma unroll
      for (int t = 0; t < 6; ++t) {
        f32x2 r = bfx2(qp[t]);
        qv[2 * t] = r[0]; qv[2 * t + 1] = r[1];
      }
    }
    float R[12] = {};
#pragma unroll
    for (int rel = 0; rel < 2; ++rel) {
      const u8* kv = rel ? kv2 : kv1;
      const int rs = rel ? rs2 : rs1, re = rel ? re2 : re1;
      const int* adj = rel ? adj2 : adj1;
      if (rs == re) continue;
      const float pri = (rel ? pri2[h] : pri1[h]) * SCALE;
      float S = 0.f, A[12] = {};
      auto edge = [&](int sn) {
        float kf[12], vf[12];
        decode12((const u32*)(kv + (size_t)sn * 1536 + off), kf);
        decode12((const u32*)(kv + (size_t)sn * 1536 + 768 + off), vf);
        float dt = 0.f;
#pragma unroll
        for (int t = 0; t < 12; ++t) dt = fmaf(qv[t], kf[t], dt);
#pragma unroll
        for (int o2 = 8; o2; o2 >>= 1) dt += __shfl_xor(dt, o2);
        const float e = __expf(dt * pri);
        S += e;
#pragma unroll
        for (int t = 0; t < 12; ++t) A[t] = fmaf(e, vf[t], A[t]);
      };
      int i = rs;
      for (; i + 1 < re; i += 2) { edge(adj[i]); edge(adj[i + 1]); }
      if (i < re) edge(adj[i]);
      const float inv = 0.5f / S;
#pragma unroll
      for (int t = 0; t < 12; ++t) R[t] = fmaf(A[t], inv, R[t]);
    }
    u32* o = (u32*)(htag_bf + (size_t)d * EMB + off);
#pragma unroll
    for (int t = 0; t < 6; ++t) {
      f32x2 r = bfx2(o[t]);
      r[0] += R[2 * t];
      r[1] += R[2 * t + 1];
      o[t] = (u32)f2bf(r[0]) | ((u32)f2bf(r[1]) << 16);
    }
  }
}

}  // namespace

extern "C" void kernel_launch(void* const* d_in, const int* in_sizes, int n_in,
                              void* d_out, int out_size, void* d_ws, size_t ws_size,
                              hipStream_t stream)
{
  const float* q_emb   = (const float*)d_in[0];
  const float* t_emb   = (const float*)d_in[1];
  const int*   give_src = (const int*)d_in[2];
  const int*   give_dst = (const int*)d_in[3];
  const int*   i1_src  = (const int*)d_in[4];
  const int*   i1_dst  = (const int*)d_in[5];
  const int*   i2_src  = (const int*)d_in[6];
  const int*   i2_dst  = (const int*)d_in[7];
  const float* Wq_enc  = (const float*)d_in[8];
  const float* bq_enc  = (const float*)d_in[9];
  const float* Wc      = (const float*)d_in[10];
  const float* bc      = (const float*)d_in[11];
  const float* centers = (const float*)d_in[12];
  const float* kW      = (const float*)d_in[13];
  const float* kb      = (const float*)d_in[14];
  const float* qW      = (const float*)d_in[15];
  const float* qb      = (const float*)d_in[16];
  const float* vW      = (const float*)d_in[17];
  const float* vb      = (const float*)d_in[18];
  const float* rel_att = (const float*)d_in[19];
  const float* rel_msg = (const float*)d_in[20];
  const float* rel_pri = (const float*)d_in[21];
  const float* Wout    = (const float*)d_in[22];
  const float* bout    = (const float*)d_in[23];
  float* out = (float*)d_out;

  // -------- workspace carve-up
  float* p = (float*)d_ws;
  auto take = [&](size_t n) { float* r = p; p += ((n + 3) & ~(size_t)3); return r; };
  u16* h_q_bf    = (u16*)take((size_t)NQ * EMB / 2);
  u16* h_tag_bf  = (u16*)take((size_t)TLEN * EMB / 2);
  u16* q_emb_bf  = (u16*)take((size_t)QLEN * EMB / 2);
  u16* q_tag_bf  = (u16*)take((size_t)TLEN * EMB / 2);
  u8* kv_all     = (u8*)take((size_t)3 * TLEN * 1536 / 4);
  u8* kv_g = kv_all;
  u8* kv_1 = kv_all + (size_t)TLEN * 1536;
  u8* kv_2 = kv_all + (size_t)2 * TLEN * 1536;
  u16* WqT   = (u16*)take((size_t)3 * WS / 2);
  u16* qWT   = (u16*)take((size_t)4 * WS / 2);
  u16* WoutT = (u16*)take((size_t)WS / 2);
  u16* relWT = (u16*)take((size_t)48 * RS / 2);
  u16* kWbf  = (u16*)take((size_t)4 * WS / 2);
  u16* vWbf  = (u16*)take((size_t)4 * WS / 2);
  u16* Wcomb = (u16*)take((size_t)6 * 1536 * 768 / 2);
  float* bcomb = take(6 * 1536);
  float* WcT   = take(7680);
  int* rp_g  = (int*)take(QLEN + 1);
  int* rp_1  = (int*)take(TLEN + 1);
  int* rp_2  = (int*)take(TLEN + 1);
  int* cur_all = (int*)take(QLEN + 2 * TLEN);
  int* cnt_all = (int*)take(QLEN + 2 * TLEN);
  int* adj_all = (int*)take(EG + 2 * EI);
  int* adj_g = adj_all;
  int* adj_1 = adj_all + EG;
  int* adj_2 = adj_all + EG + EI;
  u8* q_que = (u8*)out;   // d_out as scratch (fp8); fully overwritten at end

  // -------- CSR builds
  hipMemsetAsync(cnt_all, 0, (size_t)(QLEN + 2 * TLEN) * sizeof(int), stream);
  hist_all<<<(EG + 2 * EI + 255) / 256, 256, 0, stream>>>(give_dst, i1_dst, i2_dst, cnt_all);
  scan3<<<3, 1024, 0, stream>>>(cnt_all, rp_g, rp_1, rp_2, cur_all);
  fill_all<<<(EG + 2 * EI + 255) / 256, 256, 0, stream>>>(
      give_src, give_dst, i1_src, i1_dst, i2_src, i2_dst, cur_all, adj_all);

  // -------- weight prep
  pack_wct<<<30, 256, 0, stream>>>(Wc, WcT);
  {
    T12 jobs;
    for (int j = 0; j < 3; ++j) { jobs.s[j] = Wq_enc + j * 768; jobs.d[j] = WqT + (long long)j * WS; jobs.ld[j] = 2304; }
    for (int s = 0; s < 4; ++s) { jobs.s[3 + s] = qW + (long long)s * WS; jobs.d[3 + s] = qWT + (long long)s * WS; jobs.ld[3 + s] = 768; }
    jobs.s[7] = Wout; jobs.d[7] = WoutT; jobs.ld[7] = 768;
    for (int j = 8; j < 12; ++j) { jobs.s[j] = Wout; jobs.d[j] = WoutT; jobs.ld[j] = 768; }  // unused slots
    transpose768<<<dim3(24, 24, 8), 256, 0, stream>>>(jobs);
  }
  transpose_rel<<<dim3(6, 6, 48), 256, 0, stream>>>(rel_att, rel_msg, relWT);
  f2bf_kernel<<<(int)((4 * WS / 4 + 255) / 256), 256, 0, stream>>>(kW, kWbf, 4 * WS);
  f2bf_kernel<<<(int)((4 * WS / 4 + 255) / 256), 256, 0, stream>>>(vW, vWbf, 4 * WS);
  // combined relation weights: Wcomb[lr][kv*768+h*192+n'][d] (bf16)
  gemm_bf16<0, 1, 1><<<dim3(6, 2, 48), 256, 0, stream>>>(
      relWT, DKH, 0, kWbf, EMB, 0, Wcomb, EMB, 0, nullptr, vWbf, DKH, EMB, DKH);
  bcomb_kernel<<<36, 256, 0, stream>>>(kb, vb, rel_att, rel_msg, bcomb);

  // -------- question encoder + clustering
  f2bf_kernel<<<(QLEN * EMB / 4 + 255) / 256, 256, 0, stream>>>(q_emb, q_emb_bf, (long long)QLEN * EMB);
  gemm_bf16<1, 1, 0><<<dim3(18, 79, 1), 256, 0, stream>>>(
      q_emb_bf, EMB, 0, WqT, EMB, 0, h_q_bf, EMB, 0, bq_enc, q_emb_bf,
      QLEN, EMB * HNEED, EMB);
  assign_center512<<<NQ / 8, 512, 0, stream>>>(h_q_bf, WcT, bc, centers);
  f2bf_kernel<<<(TLEN * EMB / 4 + 255) / 256, 256, 0, stream>>>(t_emb, h_tag_bf, (long long)TLEN * EMB);

  for (int l = 0; l < 2; ++l) {
    PackJobs J;
    // job 0: q_tag  (3000 x 768, bf16)
    J.A[0] = h_tag_bf; J.Bt[0] = qWT + (long long)(l * 2) * WS; J.C[0] = q_tag_bf;
    J.bias[0] = qb + (l * 2) * EMB; J.M[0] = TLEN; J.nx[0] = 6; J.ldc[0] = 768; J.out[0] = 1;
    // job 1: q_que  (30000 x 768, fp8 -> d_out scratch)
    J.A[1] = h_q_bf; J.Bt[1] = qWT + (long long)(l * 2 + 1) * WS; J.C[1] = q_que;
    J.bias[1] = qb + (l * 2 + 1) * EMB; J.M[1] = NQ; J.nx[1] = 6; J.ldc[1] = 768; J.out[1] = 2;
    // jobs 2-4: kv_r (3000 x 1536, fp8) via combined weights
    for (int r = 0; r < 3; ++r) {
      J.A[2 + r] = h_tag_bf;
      J.Bt[2 + r] = Wcomb + (long long)(l * 3 + r) * 1536 * 768;
      J.C[2 + r] = kv_all + (size_t)r * TLEN * 1536;
      J.bias[2 + r] = bcomb + (l * 3 + r) * 1536;
      J.M[2 + r] = TLEN; J.nx[2 + r] = 12; J.ldc[2 + r] = 1536; J.out[2 + r] = 2;
    }
    J.start[0] = 0;
    J.start[1] = 144;            // q_tag: 24 x 6
    J.start[2] = 144 + 1410;     // q_que: 235 x 6
    J.start[3] = 1554 + 288;     // kv: 24 x 12 each
    J.start[4] = 1842 + 288;
    J.start[5] = 2130 + 288;     // = 2418
    gemm_pack<<<2418, 256, 0, stream>>>(J);

    gather_all<<<(QLEN + TLEN) / 4 + 1, 256, 0, stream>>>(
        q_que, kv_g, rp_g, adj_g, rel_pri + (l * 3 + 0) * NHEADS, h_q_bf,
        q_tag_bf, kv_1, kv_2, rp_1, adj_1, rp_2, adj_2,
        rel_pri + (l * 3 + 1) * NHEADS, rel_pri + (l * 3 + 2) * NHEADS,
        h_tag_bf);
  }

  // -------- merged output GEMM: rows [0,NQ) ques-scatter, [NQ,NQ+TLEN) tags
  gemm_bf16<2, 0, 0><<<dim3(6, 258, 1), 256, 0, stream>>>(
      h_q_bf, EMB, 0, WoutT, EMB, 0, out, EMB, 0, bout, nullptr,
      NQ + TLEN, EMB, EMB);
}